// Round 1
// baseline (1513.750 us; speedup 1.0000x reference)
//
#include <hip/hip_runtime.h>
#include <math.h>

// Problem constants
static constexpr int kB = 256;
static constexpr int kL = 256;
static constexpr int kD = 100;
static constexpr int kLIN = 512;
static constexpr int SZ_E = kB * kL * kD;   // 6,553,600 floats
static constexpr int SZ_A = kB * kL * kL;   // 16,777,216 floats
// Workspace budget (floats): 4*SZ_E (e1,e2,f1,f2) + 2*SZ_A (A,At; o1/o2 reuse A)
// + 6*kB*kL (sq/v/w) + kB*600 (xcat) = 60,315,648 floats = 241.3 MB. Assumes ws_size >= 242MB.

// ---------------------------------------------------------------- embed
__global__ __launch_bounds__(256) void embed_kernel(const int* __restrict__ q1,
                                                    const int* __restrict__ q2,
                                                    const float* __restrict__ emb,
                                                    float* __restrict__ e1,
                                                    float* __restrict__ e2) {
    int idx = blockIdx.x * 256 + threadIdx.x;           // grid covers 2*SZ_E exactly
    int which = idx >= SZ_E;
    int off = which ? idx - SZ_E : idx;
    int row = off / kD;
    int d = off - row * kD;
    int q = which ? q2[row] : q1[row];
    float v = emb[q * kD + d];
    if (which) e2[off] = v; else e1[off] = v;
}

__global__ __launch_bounds__(256) void valid_kernel(const int* __restrict__ q1,
                                                    const int* __restrict__ q2,
                                                    float* __restrict__ v1,
                                                    float* __restrict__ v2) {
    int idx = blockIdx.x * 256 + threadIdx.x;           // 2*kB*kL total
    if (idx < kB * kL) v1[idx] = q1[idx] != 0 ? 1.f : 0.f;
    else { int j = idx - kB * kL; v2[j] = q2[j] != 0 ? 1.f : 0.f; }
}

// ------------------------------------------------------------- row sum-of-squares (masked)
__global__ __launch_bounds__(256) void rowsq_kernel(const float* __restrict__ S,
                                                    const float* __restrict__ v,
                                                    float* __restrict__ sq) {
    int tid = threadIdx.x;
    int row = blockIdx.x * 4 + (tid >> 6);
    int lane = tid & 63;
    const float* p = S + (size_t)row * kD;
    float a = p[lane];
    float s = a * a;
    if (lane < kD - 64) { float c = p[64 + lane]; s += c * c; }
#pragma unroll
    for (int m = 32; m >= 1; m >>= 1) s += __shfl_xor(s, m, 64);
    if (lane == 0) sq[row] = s * v[row];                // (e*v)^2 summed == v * sum(e^2), v in {0,1}
}

// ------------------------------------------------------------- mean over L (for res1[0]/res2[0])
__global__ __launch_bounds__(256) void mean_kernel(const float* __restrict__ S,
                                                   float* __restrict__ xcat, int off) {
    int g = blockIdx.x * 256 + threadIdx.x;
    if (g >= kB * kD) return;
    int b = g / kD, d = g - b * kD;
    const float* p = S + (size_t)b * kL * kD + d;
    float s = 0.f;
    for (int l = 0; l < kL; ++l) s += p[l * kD];
    xcat[b * 600 + off + d] = s * (1.0f / kL);
}

// ------------------------------------------------------------- match score
// mode 0: write A[b,i,j] and At[b,j,i].  mode 1: accumulate row sums -> w1, col sums -> w2.
__global__ __launch_bounds__(256) void match_kernel(const float* __restrict__ S1,
                                                    const float* __restrict__ S2,
                                                    const float* __restrict__ v1,
                                                    const float* __restrict__ v2,
                                                    const float* __restrict__ sq1,
                                                    const float* __restrict__ sq2,
                                                    int mode,
                                                    float* __restrict__ A,
                                                    float* __restrict__ At,
                                                    float* __restrict__ w1,
                                                    float* __restrict__ w2) {
    __shared__ float lA[kD][68];   // [k][row], stride 68 keeps float4 reads 16B-aligned
    __shared__ float lB[kD][68];
    __shared__ float red[64][16];
    int tid = threadIdx.x;
    int b = blockIdx.z;
    int i0 = blockIdx.y * 64, j0 = blockIdx.x * 64;

    for (int t = tid; t < 64 * kD; t += 256) {
        int r = t & 63, k = t >> 6;
        int ri = b * kL + i0 + r, rj = b * kL + j0 + r;
        lA[k][r] = S1[(size_t)ri * kD + k] * v1[ri];
        lB[k][r] = S2[(size_t)rj * kD + k] * v2[rj];
    }
    __syncthreads();

    int tx = tid & 15, ty = tid >> 4;
    float acc[4][4] = {};
    for (int k = 0; k < kD; ++k) {
        float4 av = *(const float4*)&lA[k][ty * 4];
        float4 bv = *(const float4*)&lB[k][tx * 4];
        float am[4] = {av.x, av.y, av.z, av.w};
        float bn[4] = {bv.x, bv.y, bv.z, bv.w};
#pragma unroll
        for (int m = 0; m < 4; ++m)
#pragma unroll
            for (int n = 0; n < 4; ++n) acc[m][n] += am[m] * bn[n];
    }

    float s1v[4], s2v[4];
#pragma unroll
    for (int m = 0; m < 4; ++m) s1v[m] = sq1[b * kL + i0 + ty * 4 + m];
#pragma unroll
    for (int n = 0; n < 4; ++n) s2v[n] = sq2[b * kL + j0 + tx * 4 + n];
    float aval[4][4];
#pragma unroll
    for (int m = 0; m < 4; ++m)
#pragma unroll
        for (int n = 0; n < 4; ++n) {
            float d2 = fmaxf(s1v[m] + s2v[n] - 2.f * acc[m][n], 0.f);
            aval[m][n] = 1.f / (1.f + sqrtf(d2));
        }

    if (mode == 0) {
#pragma unroll
        for (int m = 0; m < 4; ++m) {
            float4 st = {aval[m][0], aval[m][1], aval[m][2], aval[m][3]};
            *(float4*)&A[(size_t)(b * kL + i0 + ty * 4 + m) * kL + j0 + tx * 4] = st;
        }
#pragma unroll
        for (int n = 0; n < 4; ++n) {
            float4 st = {aval[0][n], aval[1][n], aval[2][n], aval[3][n]};
            *(float4*)&At[(size_t)(b * kL + j0 + tx * 4 + n) * kL + i0 + ty * 4] = st;
        }
    } else {
        float rs[4] = {}, cs[4] = {};
#pragma unroll
        for (int m = 0; m < 4; ++m)
#pragma unroll
            for (int n = 0; n < 4; ++n) { rs[m] += aval[m][n]; cs[n] += aval[m][n]; }
#pragma unroll
        for (int m = 0; m < 4; ++m) red[ty * 4 + m][tx] = rs[m];
        __syncthreads();
        if (tid < 64) {
            float s = 0.f;
#pragma unroll
            for (int t = 0; t < 16; ++t) s += red[tid][t];
            atomicAdd(&w1[b * kL + i0 + tid], s);
        }
        __syncthreads();
#pragma unroll
        for (int n = 0; n < 4; ++n) red[tx * 4 + n][ty] = cs[n];
        __syncthreads();
        if (tid < 64) {
            float s = 0.f;
#pragma unroll
            for (int t = 0; t < 16; ++t) s += red[tid][t];
            atomicAdd(&w2[b * kL + j0 + tid], s);
        }
    }
}

// ------------------------------------------------------------- f = A_rows @ W  (131072 x 256 @ 256 x 100)
__global__ __launch_bounds__(256) void fgemm_kernel(const float* __restrict__ Aall,
                                                    const float* __restrict__ W,
                                                    float* __restrict__ out) {
    __shared__ float lW[128 * kD + 64];   // 128 K-rows of W, padded
    int tid = threadIdx.x;
    int lane = tid & 63;
    int wave = tid >> 6;
    int row0 = __builtin_amdgcn_readfirstlane(blockIdx.x * 32 + wave * 8);
    float acc[8][2] = {};
    for (int kk = 0; kk < kL; kk += 128) {
        __syncthreads();
        for (int t = tid; t < 128 * kD; t += 256) lW[t] = W[kk * kD + t];
        __syncthreads();
        for (int j = 0; j < 128; j += 4) {
            float wA[4], wB[4];
#pragma unroll
            for (int q = 0; q < 4; ++q) {
                wA[q] = lW[(j + q) * kD + lane];
                wB[q] = (lane < kD - 64) ? lW[(j + q) * kD + 64 + lane] : 0.f;
            }
#pragma unroll
            for (int r = 0; r < 8; ++r) {
                const float4 a4 = *(const float4*)&Aall[(size_t)(row0 + r) * kL + kk + j];
                acc[r][0] += a4.x * wA[0] + a4.y * wA[1] + a4.z * wA[2] + a4.w * wA[3];
                acc[r][1] += a4.x * wB[0] + a4.y * wB[1] + a4.z * wB[2] + a4.w * wB[3];
            }
        }
    }
#pragma unroll
    for (int r = 0; r < 8; ++r) {
        float* orow = out + (size_t)(row0 + r) * kD;
        orow[lane] = acc[r][0];
        if (lane < kD - 64) orow[64 + lane] = acc[r][1];
    }
}

// ------------------------------------------------------------- conv(3x3, 2ch) + tanh + fused mean(1)
__global__ __launch_bounds__(256) void conv_kernel(const float* __restrict__ e,
                                                   const float* __restrict__ f,
                                                   const float* __restrict__ ck,
                                                   const float* __restrict__ cb,
                                                   float* __restrict__ o,
                                                   float* __restrict__ res, int res_off) {
    __shared__ float le[18][kD];
    __shared__ float lf[18][kD];
    __shared__ float ksh[19];
    __shared__ float macc[kD];
    int tid = threadIdx.x;
    int b = blockIdx.y;
    int l0 = blockIdx.x * 16;
    if (tid < 19) ksh[tid] = (tid < 18) ? ck[tid] : cb[0];
    if (tid < kD) macc[tid] = 0.f;
    for (int t = tid; t < 18 * kD; t += 256) {
        int r = t / kD, d = t - r * kD;
        int l = l0 - 1 + r;
        bool ok = (l >= 0 && l < kL);
        int lc = l < 0 ? 0 : (l >= kL ? kL - 1 : l);
        size_t g = ((size_t)b * kL + lc) * kD + d;
        float ev = e[g], fv = f[g];
        le[r][d] = ok ? ev : 0.f;
        lf[r][d] = ok ? fv : 0.f;
    }
    __syncthreads();
    for (int t = tid; t < 16 * kD; t += 256) {
        int r = t / kD, d = t - r * kD;
        float acc = ksh[18];
#pragma unroll
        for (int c = 0; c < 2; ++c) {
            const float* kkp = &ksh[c * 9];
#pragma unroll
            for (int ky = 0; ky < 3; ++ky) {
                const float* rowp = c ? lf[r + ky] : le[r + ky];
                if (d > 0)      acc += kkp[ky * 3 + 0] * rowp[d - 1];
                                acc += kkp[ky * 3 + 1] * rowp[d];
                if (d < kD - 1) acc += kkp[ky * 3 + 2] * rowp[d + 1];
            }
        }
        float ov = tanhf(acc);
        o[((size_t)b * kL + l0 + r) * kD + d] = ov;
        atomicAdd(&macc[d], ov);
    }
    __syncthreads();
    if (tid < kD) atomicAdd(&res[b * 600 + res_off + tid], macc[tid] * (1.0f / kL));
}

// ------------------------------------------------------------- e += avg_pool3(o * w)
__global__ __launch_bounds__(256) void pool_kernel(const float* __restrict__ o,
                                                   const float* __restrict__ w,
                                                   float* __restrict__ e) {
    int g = blockIdx.x * 256 + threadIdx.x;             // grid covers SZ_E exactly
    int row = g / kD;                                   // b*kL + l
    int l = row & (kL - 1);
    float p1 = o[g] * w[row];
    float p0 = (l > 0) ? o[g - kD] * w[row - 1] : 0.f;
    float p2 = (l < kL - 1) ? o[g + kD] * w[row + 1] : 0.f;
    e[g] += (p0 + p1 + p2) * (1.f / 3.f);
}

// ------------------------------------------------------------- head: fc1 + LN + relu + fc2
__device__ __forceinline__ float block_sum(float v, float* red, int tid) {
#pragma unroll
    for (int m = 32; m >= 1; m >>= 1) v += __shfl_xor(v, m, 64);
    __syncthreads();
    if ((tid & 63) == 0) red[tid >> 6] = v;
    __syncthreads();
    return red[0] + red[1] + red[2] + red[3];
}

__global__ __launch_bounds__(256) void head_kernel(const float* __restrict__ xcat,
                                                   const float* __restrict__ fc1w,
                                                   const float* __restrict__ fc1b,
                                                   const float* __restrict__ lng,
                                                   const float* __restrict__ lnb,
                                                   const float* __restrict__ fc2w,
                                                   const float* __restrict__ fc2b,
                                                   float* __restrict__ out) {
    __shared__ float xr[600];
    __shared__ float red[4];
    int b = blockIdx.x, tid = threadIdx.x;
    for (int t = tid; t < 600; t += 256) xr[t] = xcat[b * 600 + t];
    __syncthreads();
    float h0 = fc1b[tid], h1 = fc1b[tid + 256];
    for (int k = 0; k < 600; ++k) {
        float xv = xr[k];
        h0 = fmaf(xv, fc1w[k * kLIN + tid], h0);
        h1 = fmaf(xv, fc1w[k * kLIN + tid + 256], h1);
    }
    float mu = block_sum(h0 + h1, red, tid) * (1.0f / kLIN);
    float d0 = h0 - mu, d1 = h1 - mu;
    float var = block_sum(d0 * d0 + d1 * d1, red, tid) * (1.0f / kLIN);
    float rstd = rsqrtf(var + 1e-5f);
    float n0 = d0 * rstd * lng[tid] + lnb[tid];
    float n1 = d1 * rstd * lng[tid + 256] + lnb[tid + 256];
    float r0 = fmaxf(n0, 0.f), r1 = fmaxf(n1, 0.f);
    float p0 = r0 * fc2w[tid * 2 + 0] + r1 * fc2w[(tid + 256) * 2 + 0];
    float p1 = r0 * fc2w[tid * 2 + 1] + r1 * fc2w[(tid + 256) * 2 + 1];
    float o0 = block_sum(p0, red, tid);
    float o1 = block_sum(p1, red, tid);
    if (tid == 0) { out[b * 2 + 0] = o0 + fc2b[0]; out[b * 2 + 1] = o1 + fc2b[1]; }
}

// ----------------------------------------------------------------------------
extern "C" void kernel_launch(void* const* d_in, const int* in_sizes, int n_in,
                              void* d_out, int out_size, void* d_ws, size_t ws_size,
                              hipStream_t stream) {
    const int*   q1   = (const int*)d_in[0];
    const int*   q2   = (const int*)d_in[1];
    const float* emb  = (const float*)d_in[2];
    const float* Ws   = (const float*)d_in[3];
    const float* ck   = (const float*)d_in[4];
    const float* cb   = (const float*)d_in[5];
    const float* fc1w = (const float*)d_in[6];
    const float* fc1b = (const float*)d_in[7];
    const float* lng  = (const float*)d_in[8];
    const float* lnb  = (const float*)d_in[9];
    const float* fc2w = (const float*)d_in[10];
    const float* fc2b = (const float*)d_in[11];
    float* out = (float*)d_out;
    float* ws  = (float*)d_ws;

    float* e1  = ws;
    float* e2  = e1 + SZ_E;
    float* f1  = e2 + SZ_E;
    float* f2  = f1 + SZ_E;
    float* Am  = f2 + SZ_E;
    float* At  = Am + SZ_A;
    float* o1  = Am;            // reuse: A dead once f1/f2 computed
    float* o2  = Am + SZ_E;
    float* sq1 = At + SZ_A;
    float* sq2 = sq1 + kB * kL;
    float* v1  = sq2 + kB * kL;
    float* v2  = v1 + kB * kL;
    float* w1  = v2 + kB * kL;
    float* w2  = w1 + kB * kL;
    float* xcat = w2 + kB * kL;

    hipMemsetAsync(xcat, 0, kB * 600 * sizeof(float), stream);
    embed_kernel<<<2 * SZ_E / 256, 256, 0, stream>>>(q1, q2, emb, e1, e2);
    valid_kernel<<<2 * kB * kL / 256, 256, 0, stream>>>(q1, q2, v1, v2);
    mean_kernel<<<(kB * kD + 255) / 256, 256, 0, stream>>>(e1, xcat, 0);
    mean_kernel<<<(kB * kD + 255) / 256, 256, 0, stream>>>(e2, xcat, 300);

    for (int layer = 0; layer < 2; ++layer) {
        const float* Wl  = Ws + layer * kL * kD;
        const float* ckl = ck + layer * 18;
        const float* cbl = cb + layer;
        rowsq_kernel<<<kB * kL / 4, 256, 0, stream>>>(e1, v1, sq1);
        rowsq_kernel<<<kB * kL / 4, 256, 0, stream>>>(e2, v2, sq2);
        match_kernel<<<dim3(4, 4, kB), 256, 0, stream>>>(e1, e2, v1, v2, sq1, sq2,
                                                         0, Am, At, nullptr, nullptr);
        fgemm_kernel<<<2 * kB * kL / 32, 256, 0, stream>>>(Am, Wl, f1);  // A|At -> f1|f2
        conv_kernel<<<dim3(kL / 16, kB), 256, 0, stream>>>(e1, f1, ckl, cbl, o1, xcat, 100 + layer * 100);
        conv_kernel<<<dim3(kL / 16, kB), 256, 0, stream>>>(e2, f2, ckl, cbl, o2, xcat, 400 + layer * 100);
        rowsq_kernel<<<kB * kL / 4, 256, 0, stream>>>(o1, v1, sq1);
        rowsq_kernel<<<kB * kL / 4, 256, 0, stream>>>(o2, v2, sq2);
        hipMemsetAsync(w1, 0, 2 * kB * kL * sizeof(float), stream);
        match_kernel<<<dim3(4, 4, kB), 256, 0, stream>>>(o1, o2, v1, v2, sq1, sq2,
                                                         1, nullptr, nullptr, w1, w2);
        pool_kernel<<<SZ_E / 256, 256, 0, stream>>>(o1, w1, e1);
        pool_kernel<<<SZ_E / 256, 256, 0, stream>>>(o2, w2, e2);
    }
    head_kernel<<<kB, 256, 0, stream>>>(xcat, fc1w, fc1b, lng, lnb, fc2w, fc2b, out);
}

// Round 2
// 1057.315 us; speedup vs baseline: 1.4317x; 1.4317x over previous
//
#include <hip/hip_runtime.h>
#include <hip/hip_bf16.h>
#include <math.h>

// Problem constants
static constexpr int kB = 256;
static constexpr int kL = 256;
static constexpr int kD = 100;
static constexpr int kLIN = 512;
static constexpr int SZ_E = kB * kL * kD;   // 6,553,600 floats
static constexpr int SZ_A = kB * kL * kL;   // 16,777,216 elems (per matrix)
static constexpr int W_FRAG = 7 * 8 * 64 * 8; // 28672 bf16 per layer (N=112 pad, K=256)

typedef short  s8_t  __attribute__((ext_vector_type(8)));
typedef float  f4_t  __attribute__((ext_vector_type(4)));

__device__ __forceinline__ unsigned short f2bf(float x) {
    __hip_bfloat16 h = __float2bfloat16(x);
    return *(unsigned short*)&h;
}

// ---------------------------------------------------------------- embed
__global__ __launch_bounds__(256) void embed_kernel(const int* __restrict__ q1,
                                                    const int* __restrict__ q2,
                                                    const float* __restrict__ emb,
                                                    float* __restrict__ e1,
                                                    float* __restrict__ e2) {
    int idx = blockIdx.x * 256 + threadIdx.x;
    int which = idx >= SZ_E;
    int off = which ? idx - SZ_E : idx;
    int row = off / kD;
    int d = off - row * kD;
    int q = which ? q2[row] : q1[row];
    float v = emb[q * kD + d];
    if (which) e2[off] = v; else e1[off] = v;
}

__global__ __launch_bounds__(256) void valid_kernel(const int* __restrict__ q1,
                                                    const int* __restrict__ q2,
                                                    float* __restrict__ v1,
                                                    float* __restrict__ v2) {
    int idx = blockIdx.x * 256 + threadIdx.x;
    if (idx < kB * kL) v1[idx] = q1[idx] != 0 ? 1.f : 0.f;
    else { int j = idx - kB * kL; v2[j] = q2[j] != 0 ? 1.f : 0.f; }
}

// ------------------------------------------------------------- row sum-of-squares (masked)
__global__ __launch_bounds__(256) void rowsq_kernel(const float* __restrict__ S,
                                                    const float* __restrict__ v,
                                                    float* __restrict__ sq) {
    int tid = threadIdx.x;
    int row = blockIdx.x * 4 + (tid >> 6);
    int lane = tid & 63;
    const float* p = S + (size_t)row * kD;
    float a = p[lane];
    float s = a * a;
    if (lane < kD - 64) { float c = p[64 + lane]; s += c * c; }
#pragma unroll
    for (int m = 32; m >= 1; m >>= 1) s += __shfl_xor(s, m, 64);
    if (lane == 0) sq[row] = s * v[row];
}

// ------------------------------------------------------------- mean over L
__global__ __launch_bounds__(256) void mean_kernel(const float* __restrict__ S,
                                                   float* __restrict__ xcat, int off) {
    int g = blockIdx.x * 256 + threadIdx.x;
    if (g >= kB * kD) return;
    int b = g / kD, d = g - b * kD;
    const float* p = S + (size_t)b * kL * kD + d;
    float s = 0.f;
    for (int l = 0; l < kL; ++l) s += p[l * kD];
    xcat[b * 600 + off + d] = s * (1.0f / kL);
}

// ------------------------------------------------------------- match score
// mode 0: write bf16 A[b,i,j] and At[b,j,i].  mode 1: row sums -> w1, col sums -> w2.
__global__ __launch_bounds__(256) void match_kernel(const float* __restrict__ S1,
                                                    const float* __restrict__ S2,
                                                    const float* __restrict__ v1,
                                                    const float* __restrict__ v2,
                                                    const float* __restrict__ sq1,
                                                    const float* __restrict__ sq2,
                                                    int mode,
                                                    unsigned short* __restrict__ A,
                                                    unsigned short* __restrict__ At,
                                                    float* __restrict__ w1,
                                                    float* __restrict__ w2) {
    __shared__ float lA[kD][68];
    __shared__ float lB[kD][68];
    __shared__ float red[64][16];
    int tid = threadIdx.x;
    int b = blockIdx.z;
    int i0 = blockIdx.y * 64, j0 = blockIdx.x * 64;

    for (int t = tid; t < 64 * kD; t += 256) {
        int r = t & 63, k = t >> 6;
        int ri = b * kL + i0 + r, rj = b * kL + j0 + r;
        lA[k][r] = S1[(size_t)ri * kD + k] * v1[ri];
        lB[k][r] = S2[(size_t)rj * kD + k] * v2[rj];
    }
    __syncthreads();

    int tx = tid & 15, ty = tid >> 4;
    float acc[4][4] = {};
    for (int k = 0; k < kD; ++k) {
        float4 av = *(const float4*)&lA[k][ty * 4];
        float4 bv = *(const float4*)&lB[k][tx * 4];
        float am[4] = {av.x, av.y, av.z, av.w};
        float bn[4] = {bv.x, bv.y, bv.z, bv.w};
#pragma unroll
        for (int m = 0; m < 4; ++m)
#pragma unroll
            for (int n = 0; n < 4; ++n) acc[m][n] += am[m] * bn[n];
    }

    float s1v[4], s2v[4];
#pragma unroll
    for (int m = 0; m < 4; ++m) s1v[m] = sq1[b * kL + i0 + ty * 4 + m];
#pragma unroll
    for (int n = 0; n < 4; ++n) s2v[n] = sq2[b * kL + j0 + tx * 4 + n];
    float aval[4][4];
#pragma unroll
    for (int m = 0; m < 4; ++m)
#pragma unroll
        for (int n = 0; n < 4; ++n) {
            float d2 = fmaxf(s1v[m] + s2v[n] - 2.f * acc[m][n], 0.f);
            aval[m][n] = 1.f / (1.f + sqrtf(d2));
        }

    if (mode == 0) {
#pragma unroll
        for (int m = 0; m < 4; ++m) {
            ushort4 st = {f2bf(aval[m][0]), f2bf(aval[m][1]), f2bf(aval[m][2]), f2bf(aval[m][3])};
            *(ushort4*)&A[(size_t)(b * kL + i0 + ty * 4 + m) * kL + j0 + tx * 4] = st;
        }
#pragma unroll
        for (int n = 0; n < 4; ++n) {
            ushort4 st = {f2bf(aval[0][n]), f2bf(aval[1][n]), f2bf(aval[2][n]), f2bf(aval[3][n])};
            *(ushort4*)&At[(size_t)(b * kL + j0 + tx * 4 + n) * kL + i0 + ty * 4] = st;
        }
    } else {
        float rs[4] = {}, cs[4] = {};
#pragma unroll
        for (int m = 0; m < 4; ++m)
#pragma unroll
            for (int n = 0; n < 4; ++n) { rs[m] += aval[m][n]; cs[n] += aval[m][n]; }
#pragma unroll
        for (int m = 0; m < 4; ++m) red[ty * 4 + m][tx] = rs[m];
        __syncthreads();
        if (tid < 64) {
            float s = 0.f;
#pragma unroll
            for (int t = 0; t < 16; ++t) s += red[tid][t];
            atomicAdd(&w1[b * kL + i0 + tid], s);
        }
        __syncthreads();
#pragma unroll
        for (int n = 0; n < 4; ++n) red[tx * 4 + n][ty] = cs[n];
        __syncthreads();
        if (tid < 64) {
            float s = 0.f;
#pragma unroll
            for (int t = 0; t < 16; ++t) s += red[tid][t];
            atomicAdd(&w2[b * kL + j0 + tid], s);
        }
    }
}

// ------------------------------------------------------------- W -> B-fragment layout (bf16)
// Wfrag flat index: ((nt*8 + kt)*64 + lane)*8 + j  holds  W[kt*32 + (lane>>4)*8 + j][nt*16 + (lane&15)]
__global__ __launch_bounds__(256) void wprep_kernel(const float* __restrict__ Ws,
                                                    unsigned short* __restrict__ Wf) {
    int layer = blockIdx.x;
    const float* W = Ws + layer * kL * kD;
    unsigned short* o = Wf + layer * W_FRAG;
    for (int t = threadIdx.x; t < W_FRAG; t += 256) {
        int j = t & 7, lane = (t >> 3) & 63, kt = (t >> 9) & 7, nt = t >> 12;
        int k = kt * 32 + (lane >> 4) * 8 + j;
        int n = nt * 16 + (lane & 15);
        float v = (n < kD) ? W[k * kD + n] : 0.f;
        o[t] = f2bf(v);
    }
}

// ------------------------------------------------------------- f = A @ W via MFMA bf16
// M=131072 rows (A then At), K=256, N=100 (pad 112). Block=4 waves, 128 rows; wave: 32 rows x 112 cols.
__global__ __launch_bounds__(256) void fgemm_mfma(const unsigned short* __restrict__ Abf,
                                                  const unsigned short* __restrict__ Wf,
                                                  float* __restrict__ out) {
    int tid = threadIdx.x;
    int lane = tid & 63, wave = tid >> 6;
    int quad = lane >> 4, l15 = lane & 15;
    size_t m0 = (size_t)blockIdx.x * 128 + wave * 32;
    f4_t acc[2][7] = {};
    const unsigned short* arow = Abf + (m0 + l15) * kL + quad * 8;
#pragma unroll
    for (int kt = 0; kt < 8; ++kt) {
        s8_t a0 = *(const s8_t*)(arow + kt * 32);
        s8_t a1 = *(const s8_t*)(arow + 16 * kL + kt * 32);
        const unsigned short* bp = Wf + (size_t)(kt * 64 + lane) * 8;
#pragma unroll
        for (int nt = 0; nt < 7; ++nt) {
            s8_t b = *(const s8_t*)(bp + (size_t)nt * 8 * 64 * 8);
            acc[0][nt] = __builtin_amdgcn_mfma_f32_16x16x32_bf16(a0, b, acc[0][nt], 0, 0, 0);
            acc[1][nt] = __builtin_amdgcn_mfma_f32_16x16x32_bf16(a1, b, acc[1][nt], 0, 0, 0);
        }
    }
#pragma unroll
    for (int mt = 0; mt < 2; ++mt)
#pragma unroll
        for (int nt = 0; nt < 7; ++nt) {
            int col = nt * 16 + l15;
            if (col < kD) {
#pragma unroll
                for (int r = 0; r < 4; ++r) {
                    size_t row = m0 + mt * 16 + quad * 4 + r;
                    out[row * kD + col] = acc[mt][nt][r];
                }
            }
        }
}

// ------------------------------------------------------------- conv(3x3, 2ch) + tanh + fused mean(1)
__global__ __launch_bounds__(256) void conv_kernel(const float* __restrict__ e,
                                                   const float* __restrict__ f,
                                                   const float* __restrict__ ck,
                                                   const float* __restrict__ cb,
                                                   float* __restrict__ o,
                                                   float* __restrict__ res, int res_off) {
    __shared__ float le[18][kD];
    __shared__ float lf[18][kD];
    __shared__ float ksh[19];
    __shared__ float macc[kD];
    int tid = threadIdx.x;
    int b = blockIdx.y;
    int l0 = blockIdx.x * 16;
    if (tid < 19) ksh[tid] = (tid < 18) ? ck[tid] : cb[0];
    if (tid < kD) macc[tid] = 0.f;
    for (int t = tid; t < 18 * kD; t += 256) {
        int r = t / kD, d = t - r * kD;
        int l = l0 - 1 + r;
        bool ok = (l >= 0 && l < kL);
        int lc = l < 0 ? 0 : (l >= kL ? kL - 1 : l);
        size_t g = ((size_t)b * kL + lc) * kD + d;
        float ev = e[g], fv = f[g];
        le[r][d] = ok ? ev : 0.f;
        lf[r][d] = ok ? fv : 0.f;
    }
    __syncthreads();
    for (int t = tid; t < 16 * kD; t += 256) {
        int r = t / kD, d = t - r * kD;
        float acc = ksh[18];
#pragma unroll
        for (int c = 0; c < 2; ++c) {
            const float* kkp = &ksh[c * 9];
#pragma unroll
            for (int ky = 0; ky < 3; ++ky) {
                const float* rowp = c ? lf[r + ky] : le[r + ky];
                if (d > 0)      acc += kkp[ky * 3 + 0] * rowp[d - 1];
                                acc += kkp[ky * 3 + 1] * rowp[d];
                if (d < kD - 1) acc += kkp[ky * 3 + 2] * rowp[d + 1];
            }
        }
        float ov = tanhf(acc);
        o[((size_t)b * kL + l0 + r) * kD + d] = ov;
        atomicAdd(&macc[d], ov);
    }
    __syncthreads();
    if (tid < kD) atomicAdd(&res[b * 600 + res_off + tid], macc[tid] * (1.0f / kL));
}

// ------------------------------------------------------------- e += avg_pool3(o * w)
__global__ __launch_bounds__(256) void pool_kernel(const float* __restrict__ o,
                                                   const float* __restrict__ w,
                                                   float* __restrict__ e) {
    int g = blockIdx.x * 256 + threadIdx.x;
    int row = g / kD;
    int l = row & (kL - 1);
    float p1 = o[g] * w[row];
    float p0 = (l > 0) ? o[g - kD] * w[row - 1] : 0.f;
    float p2 = (l < kL - 1) ? o[g + kD] * w[row + 1] : 0.f;
    e[g] += (p0 + p1 + p2) * (1.f / 3.f);
}

// ------------------------------------------------------------- head
__device__ __forceinline__ float block_sum(float v, float* red, int tid) {
#pragma unroll
    for (int m = 32; m >= 1; m >>= 1) v += __shfl_xor(v, m, 64);
    __syncthreads();
    if ((tid & 63) == 0) red[tid >> 6] = v;
    __syncthreads();
    return red[0] + red[1] + red[2] + red[3];
}

__global__ __launch_bounds__(256) void head_kernel(const float* __restrict__ xcat,
                                                   const float* __restrict__ fc1w,
                                                   const float* __restrict__ fc1b,
                                                   const float* __restrict__ lng,
                                                   const float* __restrict__ lnb,
                                                   const float* __restrict__ fc2w,
                                                   const float* __restrict__ fc2b,
                                                   float* __restrict__ out) {
    __shared__ float xr[600];
    __shared__ float red[4];
    int b = blockIdx.x, tid = threadIdx.x;
    for (int t = tid; t < 600; t += 256) xr[t] = xcat[b * 600 + t];
    __syncthreads();
    float h0 = fc1b[tid], h1 = fc1b[tid + 256];
    for (int k = 0; k < 600; ++k) {
        float xv = xr[k];
        h0 = fmaf(xv, fc1w[k * kLIN + tid], h0);
        h1 = fmaf(xv, fc1w[k * kLIN + tid + 256], h1);
    }
    float mu = block_sum(h0 + h1, red, tid) * (1.0f / kLIN);
    float d0 = h0 - mu, d1 = h1 - mu;
    float var = block_sum(d0 * d0 + d1 * d1, red, tid) * (1.0f / kLIN);
    float rstd = rsqrtf(var + 1e-5f);
    float n0 = d0 * rstd * lng[tid] + lnb[tid];
    float n1 = d1 * rstd * lng[tid + 256] + lnb[tid + 256];
    float r0 = fmaxf(n0, 0.f), r1 = fmaxf(n1, 0.f);
    float p0 = r0 * fc2w[tid * 2 + 0] + r1 * fc2w[(tid + 256) * 2 + 0];
    float p1 = r0 * fc2w[tid * 2 + 1] + r1 * fc2w[(tid + 256) * 2 + 1];
    float o0 = block_sum(p0, red, tid);
    float o1 = block_sum(p1, red, tid);
    if (tid == 0) { out[b * 2 + 0] = o0 + fc2b[0]; out[b * 2 + 1] = o1 + fc2b[1]; }
}

// ----------------------------------------------------------------------------
extern "C" void kernel_launch(void* const* d_in, const int* in_sizes, int n_in,
                              void* d_out, int out_size, void* d_ws, size_t ws_size,
                              hipStream_t stream) {
    const int*   q1   = (const int*)d_in[0];
    const int*   q2   = (const int*)d_in[1];
    const float* emb  = (const float*)d_in[2];
    const float* Ws   = (const float*)d_in[3];
    const float* ck   = (const float*)d_in[4];
    const float* cb   = (const float*)d_in[5];
    const float* fc1w = (const float*)d_in[6];
    const float* fc1b = (const float*)d_in[7];
    const float* lng  = (const float*)d_in[8];
    const float* lnb  = (const float*)d_in[9];
    const float* fc2w = (const float*)d_in[10];
    const float* fc2b = (const float*)d_in[11];
    float* out = (float*)d_out;
    float* ws  = (float*)d_ws;

    float* e1  = ws;
    float* e2  = e1 + SZ_E;
    float* f1  = e2 + SZ_E;
    float* f2  = f1 + SZ_E;
    unsigned short* Abf = (unsigned short*)(f2 + SZ_E);   // 2*SZ_A bf16 = SZ_A floats
    unsigned short* Atb = Abf + SZ_A;
    float* o1  = (float*)Abf;            // alias: A dead once f1/f2 computed, o dead before next match-0
    float* o2  = o1 + SZ_E;
    float* after = (float*)Abf + SZ_A;
    unsigned short* Wfrag = (unsigned short*)after;       // 2*W_FRAG bf16 = W_FRAG floats
    float* sq1 = after + W_FRAG;
    float* sq2 = sq1 + kB * kL;
    float* v1  = sq2 + kB * kL;
    float* v2  = v1 + kB * kL;
    float* w1  = v2 + kB * kL;
    float* w2  = w1 + kB * kL;
    float* xcat = w2 + kB * kL;

    hipMemsetAsync(xcat, 0, kB * 600 * sizeof(float), stream);
    embed_kernel<<<2 * SZ_E / 256, 256, 0, stream>>>(q1, q2, emb, e1, e2);
    valid_kernel<<<2 * kB * kL / 256, 256, 0, stream>>>(q1, q2, v1, v2);
    wprep_kernel<<<2, 256, 0, stream>>>(Ws, Wfrag);
    mean_kernel<<<(kB * kD + 255) / 256, 256, 0, stream>>>(e1, xcat, 0);
    mean_kernel<<<(kB * kD + 255) / 256, 256, 0, stream>>>(e2, xcat, 300);

    for (int layer = 0; layer < 2; ++layer) {
        const float* ckl = ck + layer * 18;
        const float* cbl = cb + layer;
        rowsq_kernel<<<kB * kL / 4, 256, 0, stream>>>(e1, v1, sq1);
        rowsq_kernel<<<kB * kL / 4, 256, 0, stream>>>(e2, v2, sq2);
        match_kernel<<<dim3(4, 4, kB), 256, 0, stream>>>(e1, e2, v1, v2, sq1, sq2,
                                                         0, Abf, Atb, nullptr, nullptr);
        fgemm_mfma<<<2 * kB * kL / 128, 256, 0, stream>>>(Abf, Wfrag + layer * W_FRAG, f1);
        conv_kernel<<<dim3(kL / 16, kB), 256, 0, stream>>>(e1, f1, ckl, cbl, o1, xcat, 100 + layer * 100);
        conv_kernel<<<dim3(kL / 16, kB), 256, 0, stream>>>(e2, f2, ckl, cbl, o2, xcat, 400 + layer * 100);
        rowsq_kernel<<<kB * kL / 4, 256, 0, stream>>>(o1, v1, sq1);
        rowsq_kernel<<<kB * kL / 4, 256, 0, stream>>>(o2, v2, sq2);
        hipMemsetAsync(w1, 0, 2 * kB * kL * sizeof(float), stream);
        match_kernel<<<dim3(4, 4, kB), 256, 0, stream>>>(o1, o2, v1, v2, sq1, sq2,
                                                         1, nullptr, nullptr, w1, w2);
        pool_kernel<<<SZ_E / 256, 256, 0, stream>>>(o1, w1, e1);
        pool_kernel<<<SZ_E / 256, 256, 0, stream>>>(o2, w2, e2);
    }
    head_kernel<<<kB, 256, 0, stream>>>(xcat, fc1w, fc1b, lng, lnb, fc2w, fc2b, out);
}

// Round 3
// 906.120 us; speedup vs baseline: 1.6706x; 1.1669x over previous
//
#include <hip/hip_runtime.h>
#include <hip/hip_bf16.h>
#include <math.h>

// Problem constants
static constexpr int kB = 256;
static constexpr int kL = 256;
static constexpr int kD = 100;
static constexpr int kLIN = 512;
static constexpr int SZ_E = kB * kL * kD;     // 6,553,600 floats
static constexpr int SZ_A = kB * kL * kL;     // 16,777,216 elems
static constexpr int W_FRAG = 7 * 8 * 64 * 8; // 28672 bf16 per layer

typedef short  s8_t  __attribute__((ext_vector_type(8)));
typedef float  f4_t  __attribute__((ext_vector_type(4)));

__device__ __forceinline__ unsigned short f2bf(float x) {
    __hip_bfloat16 h = __float2bfloat16(x);
    return *(unsigned short*)&h;
}
__device__ __forceinline__ float bf2f(unsigned short u) {
    unsigned int w = ((unsigned int)u) << 16;
    return *(float*)&w;
}

// ---------------------------------------------------------------- embed
__global__ __launch_bounds__(256) void embed_kernel(const int* __restrict__ q1,
                                                    const int* __restrict__ q2,
                                                    const float* __restrict__ emb,
                                                    float* __restrict__ e1,
                                                    float* __restrict__ e2) {
    int idx = blockIdx.x * 256 + threadIdx.x;
    int which = idx >= SZ_E;
    int off = which ? idx - SZ_E : idx;
    int row = off / kD;
    int d = off - row * kD;
    int q = which ? q2[row] : q1[row];
    float v = emb[q * kD + d];
    if (which) e2[off] = v; else e1[off] = v;
}

// ------------------------------------------------------------- mean over L (both sides)
__global__ __launch_bounds__(256) void mean_kernel(const float* __restrict__ e1,
                                                   const float* __restrict__ e2,
                                                   float* __restrict__ xcat) {
    int g = blockIdx.x * 256 + threadIdx.x;
    int side = blockIdx.y;
    if (g >= kB * kD) return;
    int b = g / kD, d = g - b * kD;
    const float* p = (side ? e2 : e1) + (size_t)b * kL * kD + d;
    float s = 0.f;
    for (int l = 0; l < kL; ++l) s += p[l * kD];
    xcat[b * 600 + side * 300 + d] = s * (1.0f / kL);
}

// ------------------------------------------------------------- bf16 hi/lo prep + sq + zero w
// Output row layout (256 bf16): [0..99]=hi, [100..127]=0, [128..227]=lo, [228..255]=0
__global__ __launch_bounds__(256) void bfprep_kernel(const float* __restrict__ S1,
                                                     const float* __restrict__ S2,
                                                     const int* __restrict__ q1,
                                                     const int* __restrict__ q2,
                                                     unsigned short* __restrict__ sbf1,
                                                     unsigned short* __restrict__ sbf2,
                                                     float* __restrict__ sq1,
                                                     float* __restrict__ sq2,
                                                     float* __restrict__ w1,
                                                     float* __restrict__ w2) {
    int side = blockIdx.y;
    const float* S = side ? S2 : S1;
    const int* q = side ? q2 : q1;
    unsigned short* sb = side ? sbf2 : sbf1;
    float* sq = side ? sq2 : sq1;
    float* w = side ? w2 : w1;
    int tid = threadIdx.x;
    int row = blockIdx.x * 4 + (tid >> 6);
    int l = tid & 63;
    const float* p = S + (size_t)row * kD;
    float v = q[row] != 0 ? 1.f : 0.f;
    float xa = p[l];
    float xb = (l < kD - 64) ? p[64 + l] : 0.f;
    float s = xa * xa + xb * xb;
#pragma unroll
    for (int m = 32; m >= 1; m >>= 1) s += __shfl_xor(s, m, 64);
    if (l == 0) { sq[row] = s * v; w[row] = 0.f; }

    bool is_hi = l < 25;
    bool is_lo = (l >= 32 && l < 57);
    float4 hv = {0.f, 0.f, 0.f, 0.f};
    if (is_hi) hv = *(const float4*)(p + 4 * l);
    else if (is_lo) hv = *(const float4*)(p + 4 * (l - 32));
    float arr[4] = {hv.x, hv.y, hv.z, hv.w};
    unsigned short us[4];
#pragma unroll
    for (int i = 0; i < 4; ++i) {
        float x = arr[i] * v;
        unsigned short h = f2bf(x);
        if (is_hi) us[i] = h;
        else if (is_lo) us[i] = f2bf(x - bf2f(h));
        else us[i] = 0;
    }
    ushort4 st = {us[0], us[1], us[2], us[3]};
    *(ushort4*)(sb + (size_t)row * 256 + 4 * l) = st;
}

// ------------------------------------------------------------- match via MFMA (hi/lo split)
// MODE 0: write bf16 A[b,i,j] and At[b,j,i] (dual-orientation MFMA, no transpose needed)
// MODE 1: row sums -> w1, col sums -> w2 (atomics)
template<int MODE>
__global__ __launch_bounds__(256) void match_core(const unsigned short* __restrict__ sbf1,
                                                  const unsigned short* __restrict__ sbf2,
                                                  const float* __restrict__ sq1,
                                                  const float* __restrict__ sq2,
                                                  unsigned short* __restrict__ A,
                                                  unsigned short* __restrict__ At,
                                                  float* __restrict__ w1,
                                                  float* __restrict__ w2) {
    int tid = threadIdx.x;
    int lane = tid & 63, wave = tid >> 6;
    int quad = lane >> 4, l15 = lane & 15;
    int b = blockIdx.z;
    int i0 = blockIdx.y * 128, j0 = blockIdx.x * 128;
    int iw = i0 + wave * 32;

    const unsigned short* s1p = sbf1 + ((size_t)(b * kL + iw + l15)) * 256 + quad * 8;
    const unsigned short* s2p = sbf2 + ((size_t)(b * kL + j0 + l15)) * 256 + quad * 8;
    const float* sq1p = sq1 + b * kL + iw;
    const float* sq2p = sq2 + b * kL + j0;

    float s1v[2][4];
#pragma unroll
    for (int mt = 0; mt < 2; ++mt)
#pragma unroll
        for (int r = 0; r < 4; ++r) s1v[mt][r] = sq1p[mt * 16 + quad * 4 + r];
    float s1c[2];
    if (MODE == 0) { s1c[0] = sq1p[l15]; s1c[1] = sq1p[16 + l15]; }

    float rs_acc[2][4] = {{0.f,0.f,0.f,0.f},{0.f,0.f,0.f,0.f}};

    for (int half = 0; half < 2; ++half) {
        f4_t D[2][4] = {};
        f4_t Dp[4][2] = {};
#pragma unroll
        for (int kt = 0; kt < 4; ++kt) {
            s8_t a1h[2], a1l[2], b2h[4], b2l[4];
#pragma unroll
            for (int mt = 0; mt < 2; ++mt) {
                const unsigned short* ap = s1p + mt * 16 * 256 + kt * 32;
                a1h[mt] = *(const s8_t*)ap;
                a1l[mt] = *(const s8_t*)(ap + 128);
            }
#pragma unroll
            for (int n = 0; n < 4; ++n) {
                const unsigned short* bp = s2p + (size_t)(half * 64 + n * 16) * 256 + kt * 32;
                b2h[n] = *(const s8_t*)bp;
                b2l[n] = *(const s8_t*)(bp + 128);
            }
#pragma unroll
            for (int mt = 0; mt < 2; ++mt)
#pragma unroll
                for (int n = 0; n < 4; ++n) {
                    D[mt][n] = __builtin_amdgcn_mfma_f32_16x16x32_bf16(a1h[mt], b2h[n], D[mt][n], 0, 0, 0);
                    D[mt][n] = __builtin_amdgcn_mfma_f32_16x16x32_bf16(a1h[mt], b2l[n], D[mt][n], 0, 0, 0);
                    D[mt][n] = __builtin_amdgcn_mfma_f32_16x16x32_bf16(a1l[mt], b2h[n], D[mt][n], 0, 0, 0);
                    if (MODE == 0) {
                        Dp[n][mt] = __builtin_amdgcn_mfma_f32_16x16x32_bf16(b2h[n], a1h[mt], Dp[n][mt], 0, 0, 0);
                        Dp[n][mt] = __builtin_amdgcn_mfma_f32_16x16x32_bf16(b2l[n], a1h[mt], Dp[n][mt], 0, 0, 0);
                        Dp[n][mt] = __builtin_amdgcn_mfma_f32_16x16x32_bf16(b2h[n], a1l[mt], Dp[n][mt], 0, 0, 0);
                    }
                }
        }
        // ---------------- epilogue: D tiles (rows=i, col=j per l15)
#pragma unroll
        for (int n = 0; n < 4; ++n) {
            float s2vn = sq2p[half * 64 + n * 16 + l15];
            float cs = 0.f;
#pragma unroll
            for (int mt = 0; mt < 2; ++mt) {
                float av[4];
#pragma unroll
                for (int r = 0; r < 4; ++r) {
                    float d2 = fmaxf(s1v[mt][r] + s2vn - 2.f * D[mt][n][r], 0.f);
                    av[r] = __builtin_amdgcn_rcpf(1.f + __builtin_amdgcn_sqrtf(d2));
                }
                if (MODE == 0) {
                    int j = j0 + half * 64 + n * 16 + l15;
                    ushort4 st = {f2bf(av[0]), f2bf(av[1]), f2bf(av[2]), f2bf(av[3])};
                    *(ushort4*)&At[((size_t)(b * kL + j)) * kL + iw + mt * 16 + quad * 4] = st;
                } else {
#pragma unroll
                    for (int r = 0; r < 4; ++r) { rs_acc[mt][r] += av[r]; cs += av[r]; }
                }
            }
            if (MODE == 1) {
                cs += __shfl_xor(cs, 16, 64);
                cs += __shfl_xor(cs, 32, 64);
                if (lane < 16) atomicAdd(&w2[b * kL + j0 + half * 64 + n * 16 + lane], cs);
            }
        }
        // ---------------- epilogue: Dp tiles (rows=j, col=i per l15) -> natural A stores
        if (MODE == 0) {
#pragma unroll
            for (int n = 0; n < 4; ++n) {
                float s2q[4];
#pragma unroll
                for (int r = 0; r < 4; ++r) s2q[r] = sq2p[half * 64 + n * 16 + quad * 4 + r];
#pragma unroll
                for (int mt = 0; mt < 2; ++mt) {
                    float av[4];
#pragma unroll
                    for (int r = 0; r < 4; ++r) {
                        float d2 = fmaxf(s2q[r] + s1c[mt] - 2.f * Dp[n][mt][r], 0.f);
                        av[r] = __builtin_amdgcn_rcpf(1.f + __builtin_amdgcn_sqrtf(d2));
                    }
                    int i = iw + mt * 16 + l15;
                    ushort4 st = {f2bf(av[0]), f2bf(av[1]), f2bf(av[2]), f2bf(av[3])};
                    *(ushort4*)&A[((size_t)(b * kL + i)) * kL + j0 + half * 64 + n * 16 + quad * 4] = st;
                }
            }
        }
    }
    if (MODE == 1) {
#pragma unroll
        for (int mt = 0; mt < 2; ++mt)
#pragma unroll
            for (int r = 0; r < 4; ++r) {
                float v = rs_acc[mt][r];
                v += __shfl_xor(v, 1, 64);
                v += __shfl_xor(v, 2, 64);
                v += __shfl_xor(v, 4, 64);
                v += __shfl_xor(v, 8, 64);
                if (l15 == 0) atomicAdd(&w1[b * kL + iw + mt * 16 + quad * 4 + r], v);
            }
    }
}

// ------------------------------------------------------------- W -> B-fragment layout (bf16)
__global__ __launch_bounds__(256) void wprep_kernel(const float* __restrict__ Ws,
                                                    unsigned short* __restrict__ Wf) {
    int layer = blockIdx.x;
    const float* W = Ws + layer * kL * kD;
    unsigned short* o = Wf + layer * W_FRAG;
    for (int t = threadIdx.x; t < W_FRAG; t += 256) {
        int j = t & 7, lane = (t >> 3) & 63, kt = (t >> 9) & 7, nt = t >> 12;
        int k = kt * 32 + (lane >> 4) * 8 + j;
        int n = nt * 16 + (lane & 15);
        float v = (n < kD) ? W[k * kD + n] : 0.f;
        o[t] = f2bf(v);
    }
}

// ------------------------------------------------------------- f = A @ W via MFMA bf16
__global__ __launch_bounds__(256) void fgemm_mfma(const unsigned short* __restrict__ Abf,
                                                  const unsigned short* __restrict__ Wf,
                                                  float* __restrict__ out) {
    int tid = threadIdx.x;
    int lane = tid & 63, wave = tid >> 6;
    int quad = lane >> 4, l15 = lane & 15;
    size_t m0 = (size_t)blockIdx.x * 128 + wave * 32;
    f4_t acc[2][7] = {};
    const unsigned short* arow = Abf + (m0 + l15) * kL + quad * 8;
#pragma unroll
    for (int kt = 0; kt < 8; ++kt) {
        s8_t a0 = *(const s8_t*)(arow + kt * 32);
        s8_t a1 = *(const s8_t*)(arow + 16 * kL + kt * 32);
        const unsigned short* bp = Wf + (size_t)(kt * 64 + lane) * 8;
#pragma unroll
        for (int nt = 0; nt < 7; ++nt) {
            s8_t b = *(const s8_t*)(bp + (size_t)nt * 8 * 64 * 8);
            acc[0][nt] = __builtin_amdgcn_mfma_f32_16x16x32_bf16(a0, b, acc[0][nt], 0, 0, 0);
            acc[1][nt] = __builtin_amdgcn_mfma_f32_16x16x32_bf16(a1, b, acc[1][nt], 0, 0, 0);
        }
    }
#pragma unroll
    for (int mt = 0; mt < 2; ++mt)
#pragma unroll
        for (int nt = 0; nt < 7; ++nt) {
            int col = nt * 16 + l15;
            if (col < kD) {
#pragma unroll
                for (int r = 0; r < 4; ++r) {
                    size_t row = m0 + mt * 16 + quad * 4 + r;
                    out[row * kD + col] = acc[mt][nt][r];
                }
            }
        }
}

// ------------------------------------------------------------- conv(3x3, 2ch) + tanh + fused mean(1), both sides
__global__ __launch_bounds__(256) void conv_kernel(const float* __restrict__ e1,
                                                   const float* __restrict__ e2,
                                                   const float* __restrict__ f1,
                                                   const float* __restrict__ f2,
                                                   const float* __restrict__ ck,
                                                   const float* __restrict__ cb,
                                                   float* __restrict__ o1,
                                                   float* __restrict__ o2,
                                                   float* __restrict__ res,
                                                   int ro1, int ro2) {
    __shared__ float le[18][kD];
    __shared__ float lf[18][kD];
    __shared__ float ksh[19];
    __shared__ float macc[kD];
    int tid = threadIdx.x;
    int b = blockIdx.y;
    int l0 = blockIdx.x * 16;
    int side = blockIdx.z;
    const float* e = side ? e2 : e1;
    const float* f = side ? f2 : f1;
    float* o = side ? o2 : o1;
    int res_off = side ? ro2 : ro1;
    if (tid < 19) ksh[tid] = (tid < 18) ? ck[tid] : cb[0];
    if (tid < kD) macc[tid] = 0.f;
    for (int t = tid; t < 18 * kD; t += 256) {
        int r = t / kD, d = t - r * kD;
        int l = l0 - 1 + r;
        bool ok = (l >= 0 && l < kL);
        int lc = l < 0 ? 0 : (l >= kL ? kL - 1 : l);
        size_t g = ((size_t)b * kL + lc) * kD + d;
        float ev = e[g], fv = f[g];
        le[r][d] = ok ? ev : 0.f;
        lf[r][d] = ok ? fv : 0.f;
    }
    __syncthreads();
    for (int t = tid; t < 16 * kD; t += 256) {
        int r = t / kD, d = t - r * kD;
        float acc = ksh[18];
#pragma unroll
        for (int c = 0; c < 2; ++c) {
            const float* kkp = &ksh[c * 9];
#pragma unroll
            for (int ky = 0; ky < 3; ++ky) {
                const float* rowp = c ? lf[r + ky] : le[r + ky];
                if (d > 0)      acc += kkp[ky * 3 + 0] * rowp[d - 1];
                                acc += kkp[ky * 3 + 1] * rowp[d];
                if (d < kD - 1) acc += kkp[ky * 3 + 2] * rowp[d + 1];
            }
        }
        float ov = tanhf(acc);
        o[((size_t)b * kL + l0 + r) * kD + d] = ov;
        atomicAdd(&macc[d], ov);
    }
    __syncthreads();
    if (tid < kD) atomicAdd(&res[b * 600 + res_off + tid], macc[tid] * (1.0f / kL));
}

// ------------------------------------------------------------- e += avg_pool3(o * w), both sides
__global__ __launch_bounds__(256) void pool_kernel(const float* __restrict__ o1,
                                                   const float* __restrict__ o2,
                                                   const float* __restrict__ w1,
                                                   const float* __restrict__ w2,
                                                   float* __restrict__ e1,
                                                   float* __restrict__ e2) {
    int g = blockIdx.x * 256 + threadIdx.x;
    int side = blockIdx.y;
    const float* o = side ? o2 : o1;
    const float* w = side ? w2 : w1;
    float* e = side ? e2 : e1;
    int row = g / kD;
    int l = row & (kL - 1);
    float p1 = o[g] * w[row];
    float p0 = (l > 0) ? o[g - kD] * w[row - 1] : 0.f;
    float p2 = (l < kL - 1) ? o[g + kD] * w[row + 1] : 0.f;
    e[g] += (p0 + p1 + p2) * (1.f / 3.f);
}

// ------------------------------------------------------------- head
__device__ __forceinline__ float block_sum(float v, float* red, int tid) {
#pragma unroll
    for (int m = 32; m >= 1; m >>= 1) v += __shfl_xor(v, m, 64);
    __syncthreads();
    if ((tid & 63) == 0) red[tid >> 6] = v;
    __syncthreads();
    return red[0] + red[1] + red[2] + red[3];
}

__global__ __launch_bounds__(256) void head_kernel(const float* __restrict__ xcat,
                                                   const float* __restrict__ fc1w,
                                                   const float* __restrict__ fc1b,
                                                   const float* __restrict__ lng,
                                                   const float* __restrict__ lnb,
                                                   const float* __restrict__ fc2w,
                                                   const float* __restrict__ fc2b,
                                                   float* __restrict__ out) {
    __shared__ float xr[600];
    __shared__ float red[4];
    int b = blockIdx.x, tid = threadIdx.x;
    for (int t = tid; t < 600; t += 256) xr[t] = xcat[b * 600 + t];
    __syncthreads();
    float h0 = fc1b[tid], h1 = fc1b[tid + 256];
    for (int k = 0; k < 600; ++k) {
        float xv = xr[k];
        h0 = fmaf(xv, fc1w[k * kLIN + tid], h0);
        h1 = fmaf(xv, fc1w[k * kLIN + tid + 256], h1);
    }
    float mu = block_sum(h0 + h1, red, tid) * (1.0f / kLIN);
    float d0 = h0 - mu, d1 = h1 - mu;
    float var = block_sum(d0 * d0 + d1 * d1, red, tid) * (1.0f / kLIN);
    float rstd = rsqrtf(var + 1e-5f);
    float n0 = d0 * rstd * lng[tid] + lnb[tid];
    float n1 = d1 * rstd * lng[tid + 256] + lnb[tid + 256];
    float r0 = fmaxf(n0, 0.f), r1 = fmaxf(n1, 0.f);
    float p0 = r0 * fc2w[tid * 2 + 0] + r1 * fc2w[(tid + 256) * 2 + 0];
    float p1 = r0 * fc2w[tid * 2 + 1] + r1 * fc2w[(tid + 256) * 2 + 1];
    float o0 = block_sum(p0, red, tid);
    float o1 = block_sum(p1, red, tid);
    if (tid == 0) { out[b * 2 + 0] = o0 + fc2b[0]; out[b * 2 + 1] = o1 + fc2b[1]; }
}

// ----------------------------------------------------------------------------
extern "C" void kernel_launch(void* const* d_in, const int* in_sizes, int n_in,
                              void* d_out, int out_size, void* d_ws, size_t ws_size,
                              hipStream_t stream) {
    const int*   q1   = (const int*)d_in[0];
    const int*   q2   = (const int*)d_in[1];
    const float* emb  = (const float*)d_in[2];
    const float* Ws   = (const float*)d_in[3];
    const float* ck   = (const float*)d_in[4];
    const float* cb   = (const float*)d_in[5];
    const float* fc1w = (const float*)d_in[6];
    const float* fc1b = (const float*)d_in[7];
    const float* lng  = (const float*)d_in[8];
    const float* lnb  = (const float*)d_in[9];
    const float* fc2w = (const float*)d_in[10];
    const float* fc2b = (const float*)d_in[11];
    float* out = (float*)d_out;
    float* ws  = (float*)d_ws;

    float* e1  = ws;
    float* e2  = e1 + SZ_E;
    float* f1  = e2 + SZ_E;
    float* f2  = f1 + SZ_E;
    unsigned short* Abf = (unsigned short*)(f2 + SZ_E);   // A+At bf16 = SZ_A floats
    unsigned short* Atb = Abf + SZ_A;
    float* o1  = (float*)Abf;                             // alias: A dead once f computed
    float* o2  = o1 + SZ_E;
    unsigned short* sbf1 = (unsigned short*)((float*)Abf + SZ_A);  // 2x [65536][256] bf16 = SZ_A floats
    unsigned short* sbf2 = sbf1 + kB * kL * 256;
    float* after = (float*)sbf1 + SZ_A;
    unsigned short* Wfrag = (unsigned short*)after;       // 2 layers * W_FRAG bf16
    float* sq1 = after + W_FRAG;
    float* sq2 = sq1 + kB * kL;
    float* w1  = sq2 + kB * kL;
    float* w2  = w1 + kB * kL;
    float* xcat = w2 + kB * kL;

    hipMemsetAsync(xcat, 0, kB * 600 * sizeof(float), stream);
    embed_kernel<<<2 * SZ_E / 256, 256, 0, stream>>>(q1, q2, emb, e1, e2);
    wprep_kernel<<<2, 256, 0, stream>>>(Ws, Wfrag);
    mean_kernel<<<dim3((kB * kD + 255) / 256, 2), 256, 0, stream>>>(e1, e2, xcat);

    for (int layer = 0; layer < 2; ++layer) {
        const float* ckl = ck + layer * 18;
        const float* cbl = cb + layer;
        bfprep_kernel<<<dim3(kB * kL / 4, 2), 256, 0, stream>>>(e1, e2, q1, q2,
                                                                sbf1, sbf2, sq1, sq2, w1, w2);
        match_core<0><<<dim3(2, 2, kB), 256, 0, stream>>>(sbf1, sbf2, sq1, sq2,
                                                          Abf, Atb, nullptr, nullptr);
        fgemm_mfma<<<2 * kB * kL / 128, 256, 0, stream>>>(Abf, Wfrag + layer * W_FRAG, f1);
        conv_kernel<<<dim3(kL / 16, kB, 2), 256, 0, stream>>>(e1, e2, f1, f2, ckl, cbl,
                                                              o1, o2, xcat,
                                                              100 + layer * 100, 400 + layer * 100);
        bfprep_kernel<<<dim3(kB * kL / 4, 2), 256, 0, stream>>>(o1, o2, q1, q2,
                                                                sbf1, sbf2, sq1, sq2, w1, w2);
        match_core<1><<<dim3(2, 2, kB), 256, 0, stream>>>(sbf1, sbf2, sq1, sq2,
                                                          nullptr, nullptr, w1, w2);
        pool_kernel<<<dim3(SZ_E / 256, 2), 256, 0, stream>>>(o1, o2, w1, w2, e1, e2);
    }
    head_kernel<<<kB, 256, 0, stream>>>(xcat, fc1w, fc1b, lng, lnb, fc2w, fc2b, out);
}

// Round 4
// 609.994 us; speedup vs baseline: 2.4816x; 1.4855x over previous
//
#include <hip/hip_runtime.h>
#include <hip/hip_bf16.h>
#include <math.h>

// Problem constants
static constexpr int kB = 256;
static constexpr int kL = 256;
static constexpr int kD = 100;
static constexpr int kLIN = 512;
static constexpr int SZ_E = kB * kL * kD;     // 6,553,600
static constexpr int SZ_A = kB * kL * kL;     // 16,777,216
static constexpr int W_FRAG = 7 * 8 * 64 * 8; // 28672 bf16 per layer

typedef short  s8_t  __attribute__((ext_vector_type(8)));
typedef float  f4_t  __attribute__((ext_vector_type(4)));

__device__ __forceinline__ unsigned short f2bf(float x) {
    __hip_bfloat16 h = __float2bfloat16(x);
    return *(unsigned short*)&h;
}
__device__ __forceinline__ float bf2f(unsigned short u) {
    unsigned int w = ((unsigned int)u) << 16;
    return *(float*)&w;
}
__device__ __forceinline__ float ftanh(float x) {
    float ax = fabsf(x);
    float t = __expf(-2.f * ax);
    float r = 1.f - 2.f * t / (1.f + t);
    return copysignf(r, x);
}

// ---------------------------------------------------------------- embed
__global__ __launch_bounds__(256) void embed_kernel(const int* __restrict__ q1,
                                                    const int* __restrict__ q2,
                                                    const float* __restrict__ emb,
                                                    float* __restrict__ e1,
                                                    float* __restrict__ e2) {
    int idx = blockIdx.x * 256 + threadIdx.x;
    int which = idx >= SZ_E;
    int off = which ? idx - SZ_E : idx;
    int row = off / kD;
    int d = off - row * kD;
    int q = which ? q2[row] : q1[row];
    float v = emb[q * kD + d];
    if (which) e2[off] = v; else e1[off] = v;
}

// ------------------------------------------------------------- mean over L (both sides)
__global__ __launch_bounds__(256) void mean_kernel(const float* __restrict__ e1,
                                                   const float* __restrict__ e2,
                                                   float* __restrict__ xcat) {
    int g = blockIdx.x * 256 + threadIdx.x;
    int side = blockIdx.y;
    if (g >= kB * kD) return;
    int b = g / kD, d = g - b * kD;
    const float* p = (side ? e2 : e1) + (size_t)b * kL * kD + d;
    float s = 0.f;
    for (int l = 0; l < kL; ++l) s += p[l * kD];
    xcat[b * 600 + side * 300 + d] = s * (1.0f / kL);
}

// ------------------------------------------------------------- bf16 hi/lo prep + sq + zero w
// Row layout (256 bf16): [0..99]=hi, [100..127]=0, [128..227]=lo, [228..255]=0
__global__ __launch_bounds__(256) void bfprep_kernel(const float* __restrict__ S1,
                                                     const float* __restrict__ S2,
                                                     const int* __restrict__ q1,
                                                     const int* __restrict__ q2,
                                                     unsigned short* __restrict__ sbf1,
                                                     unsigned short* __restrict__ sbf2,
                                                     float* __restrict__ sq1,
                                                     float* __restrict__ sq2,
                                                     float* __restrict__ w1,
                                                     float* __restrict__ w2) {
    int side = blockIdx.y;
    const float* S = side ? S2 : S1;
    const int* q = side ? q2 : q1;
    unsigned short* sb = side ? sbf2 : sbf1;
    float* sq = side ? sq2 : sq1;
    float* w = side ? w2 : w1;
    int tid = threadIdx.x;
    int row = blockIdx.x * 4 + (tid >> 6);
    int l = tid & 63;
    const float* p = S + (size_t)row * kD;
    float v = q[row] != 0 ? 1.f : 0.f;
    float xa = p[l];
    float xb = (l < kD - 64) ? p[64 + l] : 0.f;
    float s = xa * xa + xb * xb;
#pragma unroll
    for (int m = 32; m >= 1; m >>= 1) s += __shfl_xor(s, m, 64);
    if (l == 0) { sq[row] = s * v; w[row] = 0.f; }

    bool is_hi = l < 25;
    bool is_lo = (l >= 32 && l < 57);
    float4 hv = {0.f, 0.f, 0.f, 0.f};
    if (is_hi) hv = *(const float4*)(p + 4 * l);
    else if (is_lo) hv = *(const float4*)(p + 4 * (l - 32));
    float arr[4] = {hv.x, hv.y, hv.z, hv.w};
    unsigned short us[4];
#pragma unroll
    for (int i = 0; i < 4; ++i) {
        float x = arr[i] * v;
        unsigned short h = f2bf(x);
        if (is_hi) us[i] = h;
        else if (is_lo) us[i] = f2bf(x - bf2f(h));
        else us[i] = 0;
    }
    ushort4 st = {us[0], us[1], us[2], us[3]};
    *(ushort4*)(sb + (size_t)row * 256 + 4 * l) = st;
}

// ------------------------------------------------------------- match via MFMA (hi/lo split)
template<int MODE>
__global__ __launch_bounds__(256) void match_core(const unsigned short* __restrict__ sbf1,
                                                  const unsigned short* __restrict__ sbf2,
                                                  const float* __restrict__ sq1,
                                                  const float* __restrict__ sq2,
                                                  unsigned short* __restrict__ A,
                                                  unsigned short* __restrict__ At,
                                                  float* __restrict__ w1,
                                                  float* __restrict__ w2) {
    int tid = threadIdx.x;
    int lane = tid & 63, wave = tid >> 6;
    int quad = lane >> 4, l15 = lane & 15;
    int b = blockIdx.z;
    int i0 = blockIdx.y * 128, j0 = blockIdx.x * 128;
    int iw = i0 + wave * 32;

    const unsigned short* s1p = sbf1 + ((size_t)(b * kL + iw + l15)) * 256 + quad * 8;
    const unsigned short* s2p = sbf2 + ((size_t)(b * kL + j0 + l15)) * 256 + quad * 8;
    const float* sq1p = sq1 + b * kL + iw;
    const float* sq2p = sq2 + b * kL + j0;

    float s1v[2][4];
#pragma unroll
    for (int mt = 0; mt < 2; ++mt)
#pragma unroll
        for (int r = 0; r < 4; ++r) s1v[mt][r] = sq1p[mt * 16 + quad * 4 + r];
    float s1c[2];
    if (MODE == 0) { s1c[0] = sq1p[l15]; s1c[1] = sq1p[16 + l15]; }

    float rs_acc[2][4] = {{0.f,0.f,0.f,0.f},{0.f,0.f,0.f,0.f}};

    for (int half = 0; half < 2; ++half) {
        f4_t D[2][4] = {};
        f4_t Dp[4][2] = {};
#pragma unroll
        for (int kt = 0; kt < 4; ++kt) {
            s8_t a1h[2], a1l[2], b2h[4], b2l[4];
#pragma unroll
            for (int mt = 0; mt < 2; ++mt) {
                const unsigned short* ap = s1p + mt * 16 * 256 + kt * 32;
                a1h[mt] = *(const s8_t*)ap;
                a1l[mt] = *(const s8_t*)(ap + 128);
            }
#pragma unroll
            for (int n = 0; n < 4; ++n) {
                const unsigned short* bp = s2p + (size_t)(half * 64 + n * 16) * 256 + kt * 32;
                b2h[n] = *(const s8_t*)bp;
                b2l[n] = *(const s8_t*)(bp + 128);
            }
#pragma unroll
            for (int mt = 0; mt < 2; ++mt)
#pragma unroll
                for (int n = 0; n < 4; ++n) {
                    D[mt][n] = __builtin_amdgcn_mfma_f32_16x16x32_bf16(a1h[mt], b2h[n], D[mt][n], 0, 0, 0);
                    D[mt][n] = __builtin_amdgcn_mfma_f32_16x16x32_bf16(a1h[mt], b2l[n], D[mt][n], 0, 0, 0);
                    D[mt][n] = __builtin_amdgcn_mfma_f32_16x16x32_bf16(a1l[mt], b2h[n], D[mt][n], 0, 0, 0);
                    if (MODE == 0) {
                        Dp[n][mt] = __builtin_amdgcn_mfma_f32_16x16x32_bf16(b2h[n], a1h[mt], Dp[n][mt], 0, 0, 0);
                        Dp[n][mt] = __builtin_amdgcn_mfma_f32_16x16x32_bf16(b2l[n], a1h[mt], Dp[n][mt], 0, 0, 0);
                        Dp[n][mt] = __builtin_amdgcn_mfma_f32_16x16x32_bf16(b2h[n], a1l[mt], Dp[n][mt], 0, 0, 0);
                    }
                }
        }
#pragma unroll
        for (int n = 0; n < 4; ++n) {
            float s2vn = sq2p[half * 64 + n * 16 + l15];
            float cs = 0.f;
#pragma unroll
            for (int mt = 0; mt < 2; ++mt) {
                float av[4];
#pragma unroll
                for (int r = 0; r < 4; ++r) {
                    float d2 = fmaxf(s1v[mt][r] + s2vn - 2.f * D[mt][n][r], 0.f);
                    av[r] = __builtin_amdgcn_rcpf(1.f + __builtin_amdgcn_sqrtf(d2));
                }
                if (MODE == 0) {
                    int j = j0 + half * 64 + n * 16 + l15;
                    ushort4 st = {f2bf(av[0]), f2bf(av[1]), f2bf(av[2]), f2bf(av[3])};
                    *(ushort4*)&At[((size_t)(b * kL + j)) * kL + iw + mt * 16 + quad * 4] = st;
                } else {
#pragma unroll
                    for (int r = 0; r < 4; ++r) { rs_acc[mt][r] += av[r]; cs += av[r]; }
                }
            }
            if (MODE == 1) {
                cs += __shfl_xor(cs, 16, 64);
                cs += __shfl_xor(cs, 32, 64);
                if (lane < 16) atomicAdd(&w2[b * kL + j0 + half * 64 + n * 16 + lane], cs);
            }
        }
        if (MODE == 0) {
#pragma unroll
            for (int n = 0; n < 4; ++n) {
                float s2q[4];
#pragma unroll
                for (int r = 0; r < 4; ++r) s2q[r] = sq2p[half * 64 + n * 16 + quad * 4 + r];
#pragma unroll
                for (int mt = 0; mt < 2; ++mt) {
                    float av[4];
#pragma unroll
                    for (int r = 0; r < 4; ++r) {
                        float d2 = fmaxf(s2q[r] + s1c[mt] - 2.f * Dp[n][mt][r], 0.f);
                        av[r] = __builtin_amdgcn_rcpf(1.f + __builtin_amdgcn_sqrtf(d2));
                    }
                    int i = iw + mt * 16 + l15;
                    ushort4 st = {f2bf(av[0]), f2bf(av[1]), f2bf(av[2]), f2bf(av[3])};
                    *(ushort4*)&A[((size_t)(b * kL + i)) * kL + j0 + half * 64 + n * 16 + quad * 4] = st;
                }
            }
        }
    }
    if (MODE == 1) {
#pragma unroll
        for (int mt = 0; mt < 2; ++mt)
#pragma unroll
            for (int r = 0; r < 4; ++r) {
                float v = rs_acc[mt][r];
                v += __shfl_xor(v, 1, 64);
                v += __shfl_xor(v, 2, 64);
                v += __shfl_xor(v, 4, 64);
                v += __shfl_xor(v, 8, 64);
                if (l15 == 0) atomicAdd(&w1[b * kL + iw + mt * 16 + quad * 4 + r], v);
            }
    }
}

// ------------------------------------------------------------- W -> B-fragment layout (bf16)
__global__ __launch_bounds__(256) void wprep_kernel(const float* __restrict__ Ws,
                                                    unsigned short* __restrict__ Wf) {
    int layer = blockIdx.x;
    const float* W = Ws + layer * kL * kD;
    unsigned short* o = Wf + layer * W_FRAG;
    for (int t = threadIdx.x; t < W_FRAG; t += 256) {
        int j = t & 7, lane = (t >> 3) & 63, kt = (t >> 9) & 7, nt = t >> 12;
        int k = kt * 32 + (lane >> 4) * 8 + j;
        int n = nt * 16 + (lane & 15);
        float v = (n < kD) ? W[k * kD + n] : 0.f;
        o[t] = f2bf(v);
    }
}

// ------------------------------------------------------------- f = A @ W via MFMA bf16, bf16 out
__global__ __launch_bounds__(256) void fgemm_mfma(const unsigned short* __restrict__ Abf,
                                                  const unsigned short* __restrict__ Wf,
                                                  unsigned short* __restrict__ out) {
    int tid = threadIdx.x;
    int lane = tid & 63, wave = tid >> 6;
    int quad = lane >> 4, l15 = lane & 15;
    size_t m0 = (size_t)blockIdx.x * 128 + wave * 32;
    f4_t acc[2][7] = {};
    const unsigned short* arow = Abf + (m0 + l15) * kL + quad * 8;
#pragma unroll
    for (int kt = 0; kt < 8; ++kt) {
        s8_t a0 = *(const s8_t*)(arow + kt * 32);
        s8_t a1 = *(const s8_t*)(arow + 16 * kL + kt * 32);
        const unsigned short* bp = Wf + (size_t)(kt * 64 + lane) * 8;
#pragma unroll
        for (int nt = 0; nt < 7; ++nt) {
            s8_t b = *(const s8_t*)(bp + (size_t)nt * 8 * 64 * 8);
            acc[0][nt] = __builtin_amdgcn_mfma_f32_16x16x32_bf16(a0, b, acc[0][nt], 0, 0, 0);
            acc[1][nt] = __builtin_amdgcn_mfma_f32_16x16x32_bf16(a1, b, acc[1][nt], 0, 0, 0);
        }
    }
#pragma unroll
    for (int mt = 0; mt < 2; ++mt)
#pragma unroll
        for (int nt = 0; nt < 7; ++nt) {
            int col = nt * 16 + l15;
            if (col < kD) {
#pragma unroll
                for (int r = 0; r < 4; ++r) {
                    size_t row = m0 + mt * 16 + quad * 4 + r;
                    out[row * kD + col] = f2bf(acc[mt][nt][r]);
                }
            }
        }
}

// ------------------------------------------------------------- conv(3x3, 2ch) + tanh + fused mean(1)
// block: 256 thr; 16 l-rows x 100 d per block. Thread: rowgrp=tid>>5 (8 grps x 2 rows), 4 d-cols.
__global__ __launch_bounds__(256) void conv_kernel(const float* __restrict__ e1,
                                                   const float* __restrict__ e2,
                                                   const unsigned short* __restrict__ f1,
                                                   const unsigned short* __restrict__ f2,
                                                   const float* __restrict__ ck,
                                                   const float* __restrict__ cb,
                                                   float* __restrict__ o1,
                                                   float* __restrict__ o2,
                                                   float* __restrict__ res,
                                                   int ro1, int ro2) {
    __shared__ float le[18][104];   // [halo row][1+d], [0]=left zero, [101]=right zero
    __shared__ float lf[18][104];
    __shared__ float pm[8][104];
    __shared__ float ksh[19];
    int tid = threadIdx.x;
    int b = blockIdx.y;
    int l0 = blockIdx.x * 16;
    int side = blockIdx.z;
    const float* e = side ? e2 : e1;
    const unsigned short* f = side ? f2 : f1;
    float* o = side ? o2 : o1;
    int res_off = side ? ro2 : ro1;
    if (tid < 19) ksh[tid] = (tid < 18) ? ck[tid] : cb[0];
    if (tid < 18) { le[tid][0] = 0.f; lf[tid][0] = 0.f; le[tid][101] = 0.f; lf[tid][101] = 0.f; }
    for (int t = tid; t < 900; t += 256) {
        int a = t >= 450;
        int tt = a ? t - 450 : t;
        int r = tt / 25, c = tt - r * 25;
        int l = l0 - 1 + r;
        bool ok = (l >= 0 && l < kL);
        size_t base = ((size_t)b * kL + (ok ? l : 0)) * kD + c * 4;
        float vx = 0.f, vy = 0.f, vz = 0.f, vw = 0.f;
        if (!a) {
            if (ok) { float4 v = *(const float4*)(e + base); vx = v.x; vy = v.y; vz = v.z; vw = v.w; }
            le[r][1 + c * 4] = vx; le[r][2 + c * 4] = vy; le[r][3 + c * 4] = vz; le[r][4 + c * 4] = vw;
        } else {
            if (ok) { ushort4 u = *(const ushort4*)(f + base); vx = bf2f(u.x); vy = bf2f(u.y); vz = bf2f(u.z); vw = bf2f(u.w); }
            lf[r][1 + c * 4] = vx; lf[r][2 + c * 4] = vy; lf[r][3 + c * 4] = vz; lf[r][4 + c * 4] = vw;
        }
    }
    __syncthreads();
    int rg = tid >> 5, c4 = tid & 31;
    bool act = c4 < 25;
    int d0 = c4 * 4;
    float m4[4] = {0.f, 0.f, 0.f, 0.f};
#pragma unroll
    for (int rr = 0; rr < 2; ++rr) {
        int r = rg * 2 + rr;
        if (act) {
            float bias = ksh[18];
            float a0 = bias, a1 = bias, a2 = bias, a3 = bias;
#pragma unroll
            for (int ch = 0; ch < 2; ++ch) {
                const float (*L)[104] = ch ? lf : le;
                const float* kp = &ksh[ch * 9];
#pragma unroll
                for (int ky = 0; ky < 3; ++ky) {
                    const float* row = L[r + ky];
                    float4 v4 = *(const float4*)&row[d0];
                    float2 v2 = *(const float2*)&row[d0 + 4];
                    float k0 = kp[ky * 3], k1 = kp[ky * 3 + 1], k2 = kp[ky * 3 + 2];
                    a0 += k0 * v4.x + k1 * v4.y + k2 * v4.z;
                    a1 += k0 * v4.y + k1 * v4.z + k2 * v4.w;
                    a2 += k0 * v4.z + k1 * v4.w + k2 * v2.x;
                    a3 += k0 * v4.w + k1 * v2.x + k2 * v2.y;
                }
            }
            a0 = ftanh(a0); a1 = ftanh(a1); a2 = ftanh(a2); a3 = ftanh(a3);
            float4 st = {a0, a1, a2, a3};
            *(float4*)&o[((size_t)(b * kL) + l0 + r) * kD + d0] = st;
            m4[0] += a0; m4[1] += a1; m4[2] += a2; m4[3] += a3;
        }
    }
    if (act) { float4 st = {m4[0], m4[1], m4[2], m4[3]}; *(float4*)&pm[rg][d0] = st; }
    __syncthreads();
    if (tid < kD) {
        float s = 0.f;
#pragma unroll
        for (int g = 0; g < 8; ++g) s += pm[g][tid];
        atomicAdd(&res[b * 600 + res_off + tid], s * (1.0f / kL));
    }
}

// ------------------------------------------------------------- fused: e += avgpool3(o*w); then hi/lo prep for next layer
__global__ __launch_bounds__(256) void poolprep_kernel(const float* __restrict__ o1,
                                                       const float* __restrict__ o2,
                                                       const float* __restrict__ w1,
                                                       const float* __restrict__ w2,
                                                       const int* __restrict__ q1,
                                                       const int* __restrict__ q2,
                                                       float* __restrict__ e1,
                                                       float* __restrict__ e2,
                                                       unsigned short* __restrict__ sbf1,
                                                       unsigned short* __restrict__ sbf2,
                                                       float* __restrict__ sq1,
                                                       float* __restrict__ sq2) {
    int side = blockIdx.y;
    const float* o = side ? o2 : o1;
    const float* w = side ? w2 : w1;
    const int* q = side ? q2 : q1;
    float* e = side ? e2 : e1;
    unsigned short* sb = side ? sbf2 : sbf1;
    float* sq = side ? sq2 : sq1;
    int tid = threadIdx.x;
    int row = blockIdx.x * 4 + (tid >> 6);
    int lane = tid & 63;
    int l = row & (kL - 1);
    float v = q[row] != 0 ? 1.f : 0.f;
    float wm = w[row];
    float wp = (l > 0) ? w[row - 1] : 0.f;
    float wn = (l < kL - 1) ? w[row + 1] : 0.f;
    const float* po = o + (size_t)row * kD;
    float* pe = e + (size_t)row * kD;
    float x[2];
#pragma unroll
    for (int h = 0; h < 2; ++h) {
        int d = h * 64 + lane;
        bool okd = d < kD;
        float cur = okd ? po[d] : 0.f;
        float prv = (okd && l > 0) ? po[d - kD] : 0.f;
        float nxt = (okd && l < kL - 1) ? po[d + kD] : 0.f;
        float pooled = (prv * wp + cur * wm + nxt * wn) * (1.f / 3.f);
        float en = 0.f;
        if (okd) { en = pe[d] + pooled; pe[d] = en; }
        x[h] = en * v;
    }
    float s = x[0] * x[0] + x[1] * x[1];
#pragma unroll
    for (int m = 32; m >= 1; m >>= 1) s += __shfl_xor(s, m, 64);
    if (lane == 0) sq[row] = s;
    unsigned short* rowp = sb + (size_t)row * 256;
#pragma unroll
    for (int h = 0; h < 2; ++h) {
        int d = h * 64 + lane;
        unsigned short hi = f2bf(x[h]);
        unsigned short lo = f2bf(x[h] - bf2f(hi));
        rowp[d] = hi;
        rowp[128 + d] = lo;
    }
}

// ------------------------------------------------------------- head
__device__ __forceinline__ float block_sum(float v, float* red, int tid) {
#pragma unroll
    for (int m = 32; m >= 1; m >>= 1) v += __shfl_xor(v, m, 64);
    __syncthreads();
    if ((tid & 63) == 0) red[tid >> 6] = v;
    __syncthreads();
    return red[0] + red[1] + red[2] + red[3];
}

__global__ __launch_bounds__(256) void head_kernel(const float* __restrict__ xcat,
                                                   const float* __restrict__ fc1w,
                                                   const float* __restrict__ fc1b,
                                                   const float* __restrict__ lng,
                                                   const float* __restrict__ lnb,
                                                   const float* __restrict__ fc2w,
                                                   const float* __restrict__ fc2b,
                                                   float* __restrict__ out) {
    __shared__ float xr[600];
    __shared__ float red[4];
    int b = blockIdx.x, tid = threadIdx.x;
    for (int t = tid; t < 600; t += 256) xr[t] = xcat[b * 600 + t];
    __syncthreads();
    float h0 = fc1b[tid], h1 = fc1b[tid + 256];
    for (int k = 0; k < 600; ++k) {
        float xv = xr[k];
        h0 = fmaf(xv, fc1w[k * kLIN + tid], h0);
        h1 = fmaf(xv, fc1w[k * kLIN + tid + 256], h1);
    }
    float mu = block_sum(h0 + h1, red, tid) * (1.0f / kLIN);
    float d0 = h0 - mu, d1 = h1 - mu;
    float var = block_sum(d0 * d0 + d1 * d1, red, tid) * (1.0f / kLIN);
    float rstd = rsqrtf(var + 1e-5f);
    float n0 = d0 * rstd * lng[tid] + lnb[tid];
    float n1 = d1 * rstd * lng[tid + 256] + lnb[tid + 256];
    float r0 = fmaxf(n0, 0.f), r1 = fmaxf(n1, 0.f);
    float p0 = r0 * fc2w[tid * 2 + 0] + r1 * fc2w[(tid + 256) * 2 + 0];
    float p1 = r0 * fc2w[tid * 2 + 1] + r1 * fc2w[(tid + 256) * 2 + 1];
    float o0 = block_sum(p0, red, tid);
    float o1 = block_sum(p1, red, tid);
    if (tid == 0) { out[b * 2 + 0] = o0 + fc2b[0]; out[b * 2 + 1] = o1 + fc2b[1]; }
}

// ----------------------------------------------------------------------------
extern "C" void kernel_launch(void* const* d_in, const int* in_sizes, int n_in,
                              void* d_out, int out_size, void* d_ws, size_t ws_size,
                              hipStream_t stream) {
    const int*   q1   = (const int*)d_in[0];
    const int*   q2   = (const int*)d_in[1];
    const float* emb  = (const float*)d_in[2];
    const float* Ws   = (const float*)d_in[3];
    const float* ck   = (const float*)d_in[4];
    const float* cb   = (const float*)d_in[5];
    const float* fc1w = (const float*)d_in[6];
    const float* fc1b = (const float*)d_in[7];
    const float* lng  = (const float*)d_in[8];
    const float* lnb  = (const float*)d_in[9];
    const float* fc2w = (const float*)d_in[10];
    const float* fc2b = (const float*)d_in[11];
    float* out = (float*)d_out;
    float* ws  = (float*)d_ws;

    float* e1  = ws;
    float* e2  = e1 + SZ_E;
    unsigned short* fb1 = (unsigned short*)(e2 + SZ_E);   // f1|f2 bf16 = SZ_E floats total
    unsigned short* fb2 = fb1 + SZ_E;
    unsigned short* Abf = (unsigned short*)((float*)fb1 + SZ_E);  // A|At bf16 = SZ_A floats
    unsigned short* Atb = Abf + SZ_A;
    float* o1  = (float*)Abf;             // alias: A dead once f computed; o dead once A rewritten
    float* o2  = o1 + SZ_E;
    unsigned short* sbf1 = (unsigned short*)((float*)Abf + SZ_A); // 2x[65536][256] bf16 = SZ_A floats
    unsigned short* sbf2 = sbf1 + kB * kL * 256;
    float* after = (float*)sbf1 + SZ_A;
    unsigned short* Wfrag = (unsigned short*)after;       // 2 layers * W_FRAG bf16
    float* sq1 = after + W_FRAG;
    float* sq2 = sq1 + kB * kL;
    float* w1  = sq2 + kB * kL;
    float* w2  = w1 + kB * kL;
    float* xcat = w2 + kB * kL;

    hipMemsetAsync(xcat, 0, kB * 600 * sizeof(float), stream);
    embed_kernel<<<2 * SZ_E / 256, 256, 0, stream>>>(q1, q2, emb, e1, e2);
    wprep_kernel<<<2, 256, 0, stream>>>(Ws, Wfrag);
    mean_kernel<<<dim3(kB * kD / 256, 2), 256, 0, stream>>>(e1, e2, xcat);

    // ---- layer 0
    bfprep_kernel<<<dim3(kB * kL / 4, 2), 256, 0, stream>>>(e1, e2, q1, q2,
                                                            sbf1, sbf2, sq1, sq2, w1, w2);
    match_core<0><<<dim3(2, 2, kB), 256, 0, stream>>>(sbf1, sbf2, sq1, sq2,
                                                      Abf, Atb, nullptr, nullptr);
    fgemm_mfma<<<2 * kB * kL / 128, 256, 0, stream>>>(Abf, Wfrag, fb1);
    conv_kernel<<<dim3(kL / 16, kB, 2), 256, 0, stream>>>(e1, e2, fb1, fb2, ck, cb,
                                                          o1, o2, xcat, 100, 400);
    bfprep_kernel<<<dim3(kB * kL / 4, 2), 256, 0, stream>>>(o1, o2, q1, q2,
                                                            sbf1, sbf2, sq1, sq2, w1, w2);
    match_core<1><<<dim3(2, 2, kB), 256, 0, stream>>>(sbf1, sbf2, sq1, sq2,
                                                      nullptr, nullptr, w1, w2);
    poolprep_kernel<<<dim3(kB * kL / 4, 2), 256, 0, stream>>>(o1, o2, w1, w2, q1, q2,
                                                              e1, e2, sbf1, sbf2, sq1, sq2);
    // ---- layer 1 (match1/pool are dead: e unused afterwards)
    match_core<0><<<dim3(2, 2, kB), 256, 0, stream>>>(sbf1, sbf2, sq1, sq2,
                                                      Abf, Atb, nullptr, nullptr);
    fgemm_mfma<<<2 * kB * kL / 128, 256, 0, stream>>>(Abf, Wfrag + W_FRAG, fb1);
    conv_kernel<<<dim3(kL / 16, kB, 2), 256, 0, stream>>>(e1, e2, fb1, fb2, ck + 18, cb + 1,
                                                          o1, o2, xcat, 200, 500);

    head_kernel<<<kB, 256, 0, stream>>>(xcat, fc1w, fc1b, lng, lnb, fc2w, fc2b, out);
}

// Round 5
// 604.726 us; speedup vs baseline: 2.5032x; 1.0087x over previous
//
#include <hip/hip_runtime.h>
#include <hip/hip_bf16.h>
#include <math.h>

// Problem constants
static constexpr int kB = 256;
static constexpr int kL = 256;
static constexpr int kD = 100;
static constexpr int kLIN = 512;
static constexpr int SZ_E = kB * kL * kD;     // 6,553,600
static constexpr int SZ_A = kB * kL * kL;     // 16,777,216
static constexpr int W_FRAG = 7 * 8 * 64 * 8; // 28672 bf16 per layer

typedef short  s8_t  __attribute__((ext_vector_type(8)));
typedef float  f4_t  __attribute__((ext_vector_type(4)));

// Fragment storage layout (both MFMA operand types share it):
//   frag(rowgroup g = row>>4, ktile kt = k>>5) at ((size_t)g*8 + kt)*512 shorts,
//   in-fragment: lane=(quad)*16 + (row&15), 8 shorts js=0..7.
//   sbf uses identity k-order (phys k = kt*32 + quad*8 + js).
//   A/At use permuted order pi: slot(q*8+a*4+r) -> phys kt*32 + a*16 + q*4 + r;
//   W fragments (wprep) bake the same pi so fgemm contracts correctly.

__device__ __forceinline__ unsigned short f2bf(float x) {
    __hip_bfloat16 h = __float2bfloat16(x);
    return *(unsigned short*)&h;
}
__device__ __forceinline__ float bf2f(unsigned short u) {
    unsigned int w = ((unsigned int)u) << 16;
    return *(float*)&w;
}
__device__ __forceinline__ float ftanh(float x) {
    float ax = fabsf(x);
    float t = __expf(-2.f * ax);
    float r = 1.f - 2.f * t / (1.f + t);
    return copysignf(r, x);
}

// ---------------------------------------------------------------- embed
__global__ __launch_bounds__(256) void embed_kernel(const int* __restrict__ q1,
                                                    const int* __restrict__ q2,
                                                    const float* __restrict__ emb,
                                                    float* __restrict__ e1,
                                                    float* __restrict__ e2) {
    int idx = blockIdx.x * 256 + threadIdx.x;
    int which = idx >= SZ_E;
    int off = which ? idx - SZ_E : idx;
    int row = off / kD;
    int d = off - row * kD;
    int q = which ? q2[row] : q1[row];
    float v = emb[q * kD + d];
    if (which) e2[off] = v; else e1[off] = v;
}

// ------------------------------------------------------------- mean over L (both sides)
__global__ __launch_bounds__(256) void mean_kernel(const float* __restrict__ e1,
                                                   const float* __restrict__ e2,
                                                   float* __restrict__ xcat) {
    int g = blockIdx.x * 256 + threadIdx.x;
    int side = blockIdx.y;
    if (g >= kB * kD) return;
    int b = g / kD, d = g - b * kD;
    const float* p = (side ? e2 : e1) + (size_t)b * kL * kD + d;
    float s = 0.f;
    for (int l = 0; l < kL; ++l) s += p[l * kD];
    xcat[b * 600 + side * 300 + d] = s * (1.0f / kL);
}

// ------------------------------------------------------------- bf16 hi/lo prep (fragment layout) + sq + zero w
__global__ __launch_bounds__(256) void bfprep_kernel(const float* __restrict__ S1,
                                                     const float* __restrict__ S2,
                                                     const int* __restrict__ q1,
                                                     const int* __restrict__ q2,
                                                     unsigned short* __restrict__ sbf1,
                                                     unsigned short* __restrict__ sbf2,
                                                     float* __restrict__ sq1,
                                                     float* __restrict__ sq2,
                                                     float* __restrict__ w1,
                                                     float* __restrict__ w2) {
    int side = blockIdx.y;
    const float* S = side ? S2 : S1;
    const int* q = side ? q2 : q1;
    unsigned short* sb = side ? sbf2 : sbf1;
    float* sq = side ? sq2 : sq1;
    float* w = side ? w2 : w1;
    int tid = threadIdx.x;
    int row = blockIdx.x * 4 + (tid >> 6);
    int l = tid & 63;
    const float* p = S + (size_t)row * kD;
    float v = q[row] != 0 ? 1.f : 0.f;
    float xa = p[l];
    float xb = (l < kD - 64) ? p[64 + l] : 0.f;
    float s = xa * xa + xb * xb;
#pragma unroll
    for (int m = 32; m >= 1; m >>= 1) s += __shfl_xor(s, m, 64);
    if (l == 0) { sq[row] = s * v; w[row] = 0.f; }

    bool is_hi = l < 25;
    bool is_lo = (l >= 32 && l < 57);
    float4 hv = {0.f, 0.f, 0.f, 0.f};
    if (is_hi) hv = *(const float4*)(p + 4 * l);
    else if (is_lo) hv = *(const float4*)(p + 4 * (l - 32));
    float arr[4] = {hv.x, hv.y, hv.z, hv.w};
    unsigned short us[4];
#pragma unroll
    for (int i = 0; i < 4; ++i) {
        float x = arr[i] * v;
        unsigned short h = f2bf(x);
        if (is_hi) us[i] = h;
        else if (is_lo) us[i] = f2bf(x - bf2f(h));
        else us[i] = 0;
    }
    // fragment store: k0 = 4*l covers all 256 k slots across the 64 lanes
    int kt = l >> 3;
    int lfr = ((l >> 1) & 3) * 16 + (row & 15);
    ushort4 st = {us[0], us[1], us[2], us[3]};
    *(ushort4*)(sb + ((size_t)(row >> 4) * 8 + kt) * 512 + lfr * 8 + 4 * (l & 1)) = st;
}

// ------------------------------------------------------------- match via MFMA (hi/lo split, fragment I/O)
template<int MODE>
__global__ __launch_bounds__(256) void match_core(const unsigned short* __restrict__ sbf1,
                                                  const unsigned short* __restrict__ sbf2,
                                                  const float* __restrict__ sq1,
                                                  const float* __restrict__ sq2,
                                                  unsigned short* __restrict__ A,
                                                  unsigned short* __restrict__ At,
                                                  float* __restrict__ w1,
                                                  float* __restrict__ w2) {
    int tid = threadIdx.x;
    int lane = tid & 63, wave = tid >> 6;
    int quad = lane >> 4, l15 = lane & 15;
    int b = blockIdx.z;
    int i0 = blockIdx.y * 128, j0 = blockIdx.x * 128;
    int iw = i0 + wave * 32;
    int lo8 = lane * 8;

    const unsigned short* s1f = sbf1 + ((size_t)(b * 16 + (iw >> 4)) * 8) * 512 + lo8;
    const unsigned short* s2f = sbf2 + ((size_t)(b * 16 + (j0 >> 4)) * 8) * 512 + lo8;
    const float* sq1p = sq1 + b * kL + iw;
    const float* sq2p = sq2 + b * kL + j0;

    float s1v[2][4];
#pragma unroll
    for (int mt = 0; mt < 2; ++mt)
#pragma unroll
        for (int r = 0; r < 4; ++r) s1v[mt][r] = sq1p[mt * 16 + quad * 4 + r];
    float s1c[2];
    if (MODE == 0) { s1c[0] = sq1p[l15]; s1c[1] = sq1p[16 + l15]; }

    float rs_acc[2][4] = {{0.f,0.f,0.f,0.f},{0.f,0.f,0.f,0.f}};

    for (int half = 0; half < 2; ++half) {
        f4_t D[2][4] = {};
        f4_t Dp[4][2] = {};
#pragma unroll
        for (int kt = 0; kt < 4; ++kt) {
            s8_t a1h[2], a1l[2], b2h[4], b2l[4];
#pragma unroll
            for (int mt = 0; mt < 2; ++mt) {
                a1h[mt] = *(const s8_t*)(s1f + (size_t)(mt * 8 + kt) * 512);
                a1l[mt] = *(const s8_t*)(s1f + (size_t)(mt * 8 + kt + 4) * 512);
            }
#pragma unroll
            for (int n = 0; n < 4; ++n) {
                int J = half * 4 + n;
                b2h[n] = *(const s8_t*)(s2f + (size_t)(J * 8 + kt) * 512);
                b2l[n] = *(const s8_t*)(s2f + (size_t)(J * 8 + kt + 4) * 512);
            }
#pragma unroll
            for (int mt = 0; mt < 2; ++mt)
#pragma unroll
                for (int n = 0; n < 4; ++n) {
                    D[mt][n] = __builtin_amdgcn_mfma_f32_16x16x32_bf16(a1h[mt], b2h[n], D[mt][n], 0, 0, 0);
                    D[mt][n] = __builtin_amdgcn_mfma_f32_16x16x32_bf16(a1h[mt], b2l[n], D[mt][n], 0, 0, 0);
                    D[mt][n] = __builtin_amdgcn_mfma_f32_16x16x32_bf16(a1l[mt], b2h[n], D[mt][n], 0, 0, 0);
                    if (MODE == 0) {
                        Dp[n][mt] = __builtin_amdgcn_mfma_f32_16x16x32_bf16(b2h[n], a1h[mt], Dp[n][mt], 0, 0, 0);
                        Dp[n][mt] = __builtin_amdgcn_mfma_f32_16x16x32_bf16(b2l[n], a1h[mt], Dp[n][mt], 0, 0, 0);
                        Dp[n][mt] = __builtin_amdgcn_mfma_f32_16x16x32_bf16(b2h[n], a1l[mt], Dp[n][mt], 0, 0, 0);
                    }
                }
        }
        // ---- D epilogue: rows=i (quad*4+r per mt), col=j (l15 per n). Feeds At (rows j, K=i).
#pragma unroll
        for (int n = 0; n < 4; ++n) {
            float s2vn = sq2p[half * 64 + n * 16 + l15];
            float cs = 0.f;
            s8_t st;
#pragma unroll
            for (int mt = 0; mt < 2; ++mt) {
#pragma unroll
                for (int r = 0; r < 4; ++r) {
                    float d2 = fmaxf(s1v[mt][r] + s2vn - 2.f * D[mt][n][r], 0.f);
                    float av = __builtin_amdgcn_rcpf(1.f + __builtin_amdgcn_sqrtf(d2));
                    if (MODE == 0) st[mt * 4 + r] = (short)f2bf(av);
                    else { rs_acc[mt][r] += av; cs += av; }
                }
            }
            if (MODE == 0) {
                int grp = b * 16 + (j0 >> 4) + half * 4 + n;
                int kt_i = iw >> 5;
                *(s8_t*)(At + ((size_t)grp * 8 + kt_i) * 512 + lo8) = st;
            } else {
                cs += __shfl_xor(cs, 16, 64);
                cs += __shfl_xor(cs, 32, 64);
                if (lane < 16) atomicAdd(&w2[b * kL + j0 + half * 64 + n * 16 + lane], cs);
            }
        }
        // ---- Dp epilogue: rows=j (quad*4+r per n), col=i (l15 per mt). Feeds A (rows i, K=j).
        if (MODE == 0) {
#pragma unroll
            for (int np = 0; np < 2; ++np) {
#pragma unroll
                for (int mt = 0; mt < 2; ++mt) {
                    s8_t st;
#pragma unroll
                    for (int h2 = 0; h2 < 2; ++h2) {
                        int n = np * 2 + h2;
#pragma unroll
                        for (int r = 0; r < 4; ++r) {
                            float s2q = sq2p[half * 64 + n * 16 + quad * 4 + r];
                            float d2 = fmaxf(s2q + s1c[mt] - 2.f * Dp[n][mt][r], 0.f);
                            float av = __builtin_amdgcn_rcpf(1.f + __builtin_amdgcn_sqrtf(d2));
                            st[h2 * 4 + r] = (short)f2bf(av);
                        }
                    }
                    int grp = b * 16 + (iw >> 4) + mt;
                    int kt_j = (j0 >> 5) + half * 2 + np;
                    *(s8_t*)(A + ((size_t)grp * 8 + kt_j) * 512 + lo8) = st;
                }
            }
        }
    }
    if (MODE == 1) {
#pragma unroll
        for (int mt = 0; mt < 2; ++mt)
#pragma unroll
            for (int r = 0; r < 4; ++r) {
                float v = rs_acc[mt][r];
                v += __shfl_xor(v, 1, 64);
                v += __shfl_xor(v, 2, 64);
                v += __shfl_xor(v, 4, 64);
                v += __shfl_xor(v, 8, 64);
                if (l15 == 0) atomicAdd(&w1[b * kL + iw + mt * 16 + quad * 4 + r], v);
            }
    }
}

// ------------------------------------------------------------- W -> B-fragment layout (bf16, pi-permuted k)
__global__ __launch_bounds__(256) void wprep_kernel(const float* __restrict__ Ws,
                                                    unsigned short* __restrict__ Wf) {
    int layer = blockIdx.x;
    const float* W = Ws + layer * kL * kD;
    unsigned short* o = Wf + layer * W_FRAG;
    for (int t = threadIdx.x; t < W_FRAG; t += 256) {
        int j = t & 7, lane = (t >> 3) & 63, kt = (t >> 9) & 7, nt = t >> 12;
        int k = kt * 32 + (j >> 2) * 16 + ((lane >> 4) & 3) * 4 + (j & 3);  // pi
        int n = nt * 16 + (lane & 15);
        float v = (n < kD) ? W[k * kD + n] : 0.f;
        o[t] = f2bf(v);
    }
}

// ------------------------------------------------------------- f = A @ W via MFMA bf16 (fragment A), bf16 out
__global__ __launch_bounds__(256) void fgemm_mfma(const unsigned short* __restrict__ Abf,
                                                  const unsigned short* __restrict__ Wf,
                                                  unsigned short* __restrict__ out) {
    int tid = threadIdx.x;
    int lane = tid & 63, wave = tid >> 6;
    int quad = lane >> 4, l15 = lane & 15;
    size_t m0 = (size_t)blockIdx.x * 128 + wave * 32;
    f4_t acc[2][7] = {};
    const unsigned short* af = Abf + (size_t)(m0 >> 4) * 8 * 512 + lane * 8;
#pragma unroll
    for (int kt = 0; kt < 8; ++kt) {
        s8_t a0 = *(const s8_t*)(af + (size_t)kt * 512);
        s8_t a1 = *(const s8_t*)(af + (size_t)(8 + kt) * 512);
        const unsigned short* bp = Wf + (size_t)(kt * 64 + lane) * 8;
#pragma unroll
        for (int nt = 0; nt < 7; ++nt) {
            s8_t b = *(const s8_t*)(bp + (size_t)nt * 8 * 64 * 8);
            acc[0][nt] = __builtin_amdgcn_mfma_f32_16x16x32_bf16(a0, b, acc[0][nt], 0, 0, 0);
            acc[1][nt] = __builtin_amdgcn_mfma_f32_16x16x32_bf16(a1, b, acc[1][nt], 0, 0, 0);
        }
    }
#pragma unroll
    for (int mt = 0; mt < 2; ++mt)
#pragma unroll
        for (int nt = 0; nt < 7; ++nt) {
            int col = nt * 16 + l15;
            if (col < kD) {
#pragma unroll
                for (int r = 0; r < 4; ++r) {
                    size_t row = m0 + mt * 16 + quad * 4 + r;
                    out[row * kD + col] = f2bf(acc[mt][nt][r]);
                }
            }
        }
}

// ------------------------------------------------------------- conv(3x3, 2ch) + tanh + fused mean(1)
__global__ __launch_bounds__(256) void conv_kernel(const float* __restrict__ e1,
                                                   const float* __restrict__ e2,
                                                   const unsigned short* __restrict__ f1,
                                                   const unsigned short* __restrict__ f2,
                                                   const float* __restrict__ ck,
                                                   const float* __restrict__ cb,
                                                   float* __restrict__ o1,
                                                   float* __restrict__ o2,
                                                   float* __restrict__ res,
                                                   int ro1, int ro2) {
    __shared__ float le[18][104];
    __shared__ float lf[18][104];
    __shared__ float pm[8][104];
    __shared__ float ksh[19];
    int tid = threadIdx.x;
    int b = blockIdx.y;
    int l0 = blockIdx.x * 16;
    int side = blockIdx.z;
    const float* e = side ? e2 : e1;
    const unsigned short* f = side ? f2 : f1;
    float* o = side ? o2 : o1;
    int res_off = side ? ro2 : ro1;
    if (tid < 19) ksh[tid] = (tid < 18) ? ck[tid] : cb[0];
    if (tid < 18) { le[tid][0] = 0.f; lf[tid][0] = 0.f; le[tid][101] = 0.f; lf[tid][101] = 0.f; }
    for (int t = tid; t < 900; t += 256) {
        int a = t >= 450;
        int tt = a ? t - 450 : t;
        int r = tt / 25, c = tt - r * 25;
        int l = l0 - 1 + r;
        bool ok = (l >= 0 && l < kL);
        size_t base = ((size_t)b * kL + (ok ? l : 0)) * kD + c * 4;
        float vx = 0.f, vy = 0.f, vz = 0.f, vw = 0.f;
        if (!a) {
            if (ok) { float4 v = *(const float4*)(e + base); vx = v.x; vy = v.y; vz = v.z; vw = v.w; }
            le[r][1 + c * 4] = vx; le[r][2 + c * 4] = vy; le[r][3 + c * 4] = vz; le[r][4 + c * 4] = vw;
        } else {
            if (ok) { ushort4 u = *(const ushort4*)(f + base); vx = bf2f(u.x); vy = bf2f(u.y); vz = bf2f(u.z); vw = bf2f(u.w); }
            lf[r][1 + c * 4] = vx; lf[r][2 + c * 4] = vy; lf[r][3 + c * 4] = vz; lf[r][4 + c * 4] = vw;
        }
    }
    __syncthreads();
    int rg = tid >> 5, c4 = tid & 31;
    bool act = c4 < 25;
    int d0 = c4 * 4;
    float m4[4] = {0.f, 0.f, 0.f, 0.f};
#pragma unroll
    for (int rr = 0; rr < 2; ++rr) {
        int r = rg * 2 + rr;
        if (act) {
            float bias = ksh[18];
            float a0 = bias, a1 = bias, a2 = bias, a3 = bias;
#pragma unroll
            for (int ch = 0; ch < 2; ++ch) {
                const float (*L)[104] = ch ? lf : le;
                const float* kp = &ksh[ch * 9];
#pragma unroll
                for (int ky = 0; ky < 3; ++ky) {
                    const float* row = L[r + ky];
                    float4 v4 = *(const float4*)&row[d0];
                    float2 v2 = *(const float2*)&row[d0 + 4];
                    float k0 = kp[ky * 3], k1 = kp[ky * 3 + 1], k2 = kp[ky * 3 + 2];
                    a0 += k0 * v4.x + k1 * v4.y + k2 * v4.z;
                    a1 += k0 * v4.y + k1 * v4.z + k2 * v4.w;
                    a2 += k0 * v4.z + k1 * v4.w + k2 * v2.x;
                    a3 += k0 * v4.w + k1 * v2.x + k2 * v2.y;
                }
            }
            a0 = ftanh(a0); a1 = ftanh(a1); a2 = ftanh(a2); a3 = ftanh(a3);
            float4 st = {a0, a1, a2, a3};
            *(float4*)&o[((size_t)(b * kL) + l0 + r) * kD + d0] = st;
            m4[0] += a0; m4[1] += a1; m4[2] += a2; m4[3] += a3;
        }
    }
    if (act) { float4 st = {m4[0], m4[1], m4[2], m4[3]}; *(float4*)&pm[rg][d0] = st; }
    __syncthreads();
    if (tid < kD) {
        float s = 0.f;
#pragma unroll
        for (int g = 0; g < 8; ++g) s += pm[g][tid];
        atomicAdd(&res[b * 600 + res_off + tid], s * (1.0f / kL));
    }
}

// ------------------------------------------------------------- fused: e += avgpool3(o*w); hi/lo fragment prep
__global__ __launch_bounds__(256) void poolprep_kernel(const float* __restrict__ o1,
                                                       const float* __restrict__ o2,
                                                       const float* __restrict__ w1,
                                                       const float* __restrict__ w2,
                                                       const int* __restrict__ q1,
                                                       const int* __restrict__ q2,
                                                       float* __restrict__ e1,
                                                       float* __restrict__ e2,
                                                       unsigned short* __restrict__ sbf1,
                                                       unsigned short* __restrict__ sbf2,
                                                       float* __restrict__ sq1,
                                                       float* __restrict__ sq2) {
    int side = blockIdx.y;
    const float* o = side ? o2 : o1;
    const float* w = side ? w2 : w1;
    const int* q = side ? q2 : q1;
    float* e = side ? e2 : e1;
    unsigned short* sb = side ? sbf2 : sbf1;
    float* sq = side ? sq2 : sq1;
    int tid = threadIdx.x;
    int row = blockIdx.x * 4 + (tid >> 6);
    int lane = tid & 63;
    int l = row & (kL - 1);
    float v = q[row] != 0 ? 1.f : 0.f;
    float wm = w[row];
    float wp = (l > 0) ? w[row - 1] : 0.f;
    float wn = (l < kL - 1) ? w[row + 1] : 0.f;
    const float* po = o + (size_t)row * kD;
    float* pe = e + (size_t)row * kD;
    bool act = lane < 25;
    float x4[4] = {0.f, 0.f, 0.f, 0.f};
    if (act) {
        int d0 = lane * 4;
        float4 cur = *(const float4*)(po + d0);
        float4 prv = {0.f,0.f,0.f,0.f}, nxt = {0.f,0.f,0.f,0.f};
        if (l > 0) prv = *(const float4*)(po - kD + d0);
        if (l < kL - 1) nxt = *(const float4*)(po + kD + d0);
        float4 e4 = *(float4*)(pe + d0);
        x4[0] = e4.x + (prv.x * wp + cur.x * wm + nxt.x * wn) * (1.f / 3.f);
        x4[1] = e4.y + (prv.y * wp + cur.y * wm + nxt.y * wn) * (1.f / 3.f);
        x4[2] = e4.z + (prv.z * wp + cur.z * wm + nxt.z * wn) * (1.f / 3.f);
        x4[3] = e4.w + (prv.w * wp + cur.w * wm + nxt.w * wn) * (1.f / 3.f);
        float4 st = {x4[0], x4[1], x4[2], x4[3]};
        *(float4*)(pe + d0) = st;
#pragma unroll
        for (int c = 0; c < 4; ++c) x4[c] *= v;
    }
    float s = x4[0] * x4[0] + x4[1] * x4[1] + x4[2] * x4[2] + x4[3] * x4[3];
#pragma unroll
    for (int m = 32; m >= 1; m >>= 1) s += __shfl_xor(s, m, 64);
    if (lane == 0) sq[row] = s;
    if (lane < 32) {
        ushort4 hi = {0, 0, 0, 0}, lo = {0, 0, 0, 0};
        if (act) {
            unsigned short h;
            h = f2bf(x4[0]); hi.x = h; lo.x = f2bf(x4[0] - bf2f(h));
            h = f2bf(x4[1]); hi.y = h; lo.y = f2bf(x4[1] - bf2f(h));
            h = f2bf(x4[2]); hi.z = h; lo.z = f2bf(x4[2] - bf2f(h));
            h = f2bf(x4[3]); hi.w = h; lo.w = f2bf(x4[3] - bf2f(h));
        }
        int kt = lane >> 3;
        int lfr = ((lane >> 1) & 3) * 16 + (row & 15);
        unsigned short* p0 = sb + ((size_t)(row >> 4) * 8 + kt) * 512 + lfr * 8 + 4 * (lane & 1);
        *(ushort4*)p0 = hi;
        *(ushort4*)(p0 + 4 * 512) = lo;
    }
}

// ------------------------------------------------------------- head
__device__ __forceinline__ float block_sum(float v, float* red, int tid) {
#pragma unroll
    for (int m = 32; m >= 1; m >>= 1) v += __shfl_xor(v, m, 64);
    __syncthreads();
    if ((tid & 63) == 0) red[tid >> 6] = v;
    __syncthreads();
    return red[0] + red[1] + red[2] + red[3];
}

__global__ __launch_bounds__(256) void head_kernel(const float* __restrict__ xcat,
                                                   const float* __restrict__ fc1w,
                                                   const float* __restrict__ fc1b,
                                                   const float* __restrict__ lng,
                                                   const float* __restrict__ lnb,
                                                   const float* __restrict__ fc2w,
                                                   const float* __restrict__ fc2b,
                                                   float* __restrict__ out) {
    __shared__ float xr[600];
    __shared__ float red[4];
    int b = blockIdx.x, tid = threadIdx.x;
    for (int t = tid; t < 600; t += 256) xr[t] = xcat[b * 600 + t];
    __syncthreads();
    float h0 = fc1b[tid], h1 = fc1b[tid + 256];
    for (int k = 0; k < 600; ++k) {
        float xv = xr[k];
        h0 = fmaf(xv, fc1w[k * kLIN + tid], h0);
        h1 = fmaf(xv, fc1w[k * kLIN + tid + 256], h1);
    }
    float mu = block_sum(h0 + h1, red, tid) * (1.0f / kLIN);
    float d0 = h0 - mu, d1 = h1 - mu;
    float var = block_sum(d0 * d0 + d1 * d1, red, tid) * (1.0f / kLIN);
    float rstd = rsqrtf(var + 1e-5f);
    float n0 = d0 * rstd * lng[tid] + lnb[tid];
    float n1 = d1 * rstd * lng[tid + 256] + lnb[tid + 256];
    float r0 = fmaxf(n0, 0.f), r1 = fmaxf(n1, 0.f);
    float p0 = r0 * fc2w[tid * 2 + 0] + r1 * fc2w[(tid + 256) * 2 + 0];
    float p1 = r0 * fc2w[tid * 2 + 1] + r1 * fc2w[(tid + 256) * 2 + 1];
    float o0 = block_sum(p0, red, tid);
    float o1 = block_sum(p1, red, tid);
    if (tid == 0) { out[b * 2 + 0] = o0 + fc2b[0]; out[b * 2 + 1] = o1 + fc2b[1]; }
}

// ----------------------------------------------------------------------------
extern "C" void kernel_launch(void* const* d_in, const int* in_sizes, int n_in,
                              void* d_out, int out_size, void* d_ws, size_t ws_size,
                              hipStream_t stream) {
    const int*   q1   = (const int*)d_in[0];
    const int*   q2   = (const int*)d_in[1];
    const float* emb  = (const float*)d_in[2];
    const float* Ws   = (const float*)d_in[3];
    const float* ck   = (const float*)d_in[4];
    const float* cb   = (const float*)d_in[5];
    const float* fc1w = (const float*)d_in[6];
    const float* fc1b = (const float*)d_in[7];
    const float* lng  = (const float*)d_in[8];
    const float* lnb  = (const float*)d_in[9];
    const float* fc2w = (const float*)d_in[10];
    const float* fc2b = (const float*)d_in[11];
    float* out = (float*)d_out;
    float* ws  = (float*)d_ws;

    float* e1  = ws;
    float* e2  = e1 + SZ_E;
    unsigned short* fb1 = (unsigned short*)(e2 + SZ_E);
    unsigned short* fb2 = fb1 + SZ_E;
    unsigned short* Abf = (unsigned short*)((float*)fb1 + SZ_E);  // A|At fragments = SZ_A floats
    unsigned short* Atb = Abf + SZ_A;
    float* o1  = (float*)Abf;             // alias: A dead once f computed; o dead once A rewritten
    float* o2  = o1 + SZ_E;
    unsigned short* sbf1 = (unsigned short*)((float*)Abf + SZ_A); // fragment sbf, 2 sides
    unsigned short* sbf2 = sbf1 + kB * kL * 256;
    float* after = (float*)sbf1 + SZ_A;
    unsigned short* Wfrag = (unsigned short*)after;
    float* sq1 = after + W_FRAG;
    float* sq2 = sq1 + kB * kL;
    float* w1  = sq2 + kB * kL;
    float* w2  = w1 + kB * kL;
    float* xcat = w2 + kB * kL;

    hipMemsetAsync(xcat, 0, kB * 600 * sizeof(float), stream);
    embed_kernel<<<2 * SZ_E / 256, 256, 0, stream>>>(q1, q2, emb, e1, e2);
    wprep_kernel<<<2, 256, 0, stream>>>(Ws, Wfrag);
    mean_kernel<<<dim3(kB * kD / 256, 2), 256, 0, stream>>>(e1, e2, xcat);

    // ---- layer 0
    bfprep_kernel<<<dim3(kB * kL / 4, 2), 256, 0, stream>>>(e1, e2, q1, q2,
                                                            sbf1, sbf2, sq1, sq2, w1, w2);
    match_core<0><<<dim3(2, 2, kB), 256, 0, stream>>>(sbf1, sbf2, sq1, sq2,
                                                      Abf, Atb, nullptr, nullptr);
    fgemm_mfma<<<2 * kB * kL / 128, 256, 0, stream>>>(Abf, Wfrag, fb1);
    conv_kernel<<<dim3(kL / 16, kB, 2), 256, 0, stream>>>(e1, e2, fb1, fb2, ck, cb,
                                                          o1, o2, xcat, 100, 400);
    bfprep_kernel<<<dim3(kB * kL / 4, 2), 256, 0, stream>>>(o1, o2, q1, q2,
                                                            sbf1, sbf2, sq1, sq2, w1, w2);
    match_core<1><<<dim3(2, 2, kB), 256, 0, stream>>>(sbf1, sbf2, sq1, sq2,
                                                      nullptr, nullptr, w1, w2);
    poolprep_kernel<<<dim3(kB * kL / 4, 2), 256, 0, stream>>>(o1, o2, w1, w2, q1, q2,
                                                              e1, e2, sbf1, sbf2, sq1, sq2);
    // ---- layer 1 (tail match1/pool dead: e unused afterwards)
    match_core<0><<<dim3(2, 2, kB), 256, 0, stream>>>(sbf1, sbf2, sq1, sq2,
                                                      Abf, Atb, nullptr, nullptr);
    fgemm_mfma<<<2 * kB * kL / 128, 256, 0, stream>>>(Abf, Wfrag + W_FRAG, fb1);
    conv_kernel<<<dim3(kL / 16, kB, 2), 256, 0, stream>>>(e1, e2, fb1, fb2, ck + 18, cb + 1,
                                                          o1, o2, xcat, 200, 500);

    head_kernel<<<kB, 256, 0, stream>>>(xcat, fc1w, fc1b, lng, lnb, fc2w, fc2b, out);
}

// Round 6
// 505.292 us; speedup vs baseline: 2.9958x; 1.1968x over previous
//
#include <hip/hip_runtime.h>
#include <hip/hip_bf16.h>
#include <math.h>

// Problem constants
static constexpr int kB = 256;
static constexpr int kL = 256;
static constexpr int kD = 100;
static constexpr int kLIN = 512;
static constexpr int SZ_E = kB * kL * kD;     // 6,553,600
static constexpr int SZ_A = kB * kL * kL;     // 16,777,216
static constexpr int W_FRAG = 7 * 8 * 64 * 8; // 28672 bf16 per layer

typedef short  s8_t  __attribute__((ext_vector_type(8)));
typedef float  f4_t  __attribute__((ext_vector_type(4)));

// Fragment storage layout: frag(rowgroup g = row>>4, kslot s) at ((size_t)g*8+s)*512 shorts,
// in-fragment: lane = quad*16 + (row&15), 8 shorts. sbf: identity k (phys k = s*32? no:
// hi k=0..99 in slots 0..3, lo in slots 4..7). A/At + W use pi: slot(q*8+a*4+r) -> a*16+q*4+r.

__device__ __forceinline__ unsigned short f2bf(float x) {
    __hip_bfloat16 h = __float2bfloat16(x);
    return *(unsigned short*)&h;
}
__device__ __forceinline__ float bf2f(unsigned short u) {
    unsigned int w = ((unsigned int)u) << 16;
    return *(float*)&w;
}
__device__ __forceinline__ float ftanh(float x) {
    float ax = fabsf(x);
    float t = __expf(-2.f * ax);
    float r = 1.f - 2.f * t / (1.f + t);
    return copysignf(r, x);
}

// ------------------------------------------------------------- embed + hi/lo prep fused
__global__ __launch_bounds__(256) void embprep_kernel(const int* __restrict__ q1,
                                                      const int* __restrict__ q2,
                                                      const float* __restrict__ emb,
                                                      float* __restrict__ e1,
                                                      float* __restrict__ e2,
                                                      unsigned short* __restrict__ sbf1,
                                                      unsigned short* __restrict__ sbf2,
                                                      float* __restrict__ sq1,
                                                      float* __restrict__ sq2,
                                                      float* __restrict__ w1,
                                                      float* __restrict__ w2) {
    __shared__ float rowbuf[4][100];
    int side = blockIdx.y;
    const int* q = side ? q2 : q1;
    float* e = side ? e2 : e1;
    unsigned short* sb = side ? sbf2 : sbf1;
    float* sq = side ? sq2 : sq1;
    float* w = side ? w2 : w1;
    int tid = threadIdx.x;
    int wrow = tid >> 6, lane = tid & 63;
    int row = blockIdx.x * 4 + wrow;
    int qv = q[row];
    float v = qv != 0 ? 1.f : 0.f;
    const float* ep = emb + (size_t)qv * kD;
    float xa = ep[lane];
    float xb = (lane < kD - 64) ? ep[64 + lane] : 0.f;
    float* eo = e + (size_t)row * kD;
    eo[lane] = xa;
    if (lane < kD - 64) eo[64 + lane] = xb;
    rowbuf[wrow][lane] = xa;
    if (lane < kD - 64) rowbuf[wrow][64 + lane] = xb;
    float s = xa * xa + xb * xb;
#pragma unroll
    for (int m = 32; m >= 1; m >>= 1) s += __shfl_xor(s, m, 64);
    if (lane == 0) { sq[row] = s * v; w[row] = 0.f; }
    __syncthreads();
    if (lane < 32) {
        ushort4 hi = {0, 0, 0, 0}, lo = {0, 0, 0, 0};
        if (lane < 25) {
            float4 hv = *(const float4*)&rowbuf[wrow][4 * lane];
            float x0 = hv.x * v, x1 = hv.y * v, x2 = hv.z * v, x3 = hv.w * v;
            unsigned short h;
            h = f2bf(x0); hi.x = h; lo.x = f2bf(x0 - bf2f(h));
            h = f2bf(x1); hi.y = h; lo.y = f2bf(x1 - bf2f(h));
            h = f2bf(x2); hi.z = h; lo.z = f2bf(x2 - bf2f(h));
            h = f2bf(x3); hi.w = h; lo.w = f2bf(x3 - bf2f(h));
        }
        int kt = lane >> 3;
        int lfr = ((lane >> 1) & 3) * 16 + (row & 15);
        unsigned short* p0 = sb + ((size_t)(row >> 4) * 8 + kt) * 512 + lfr * 8 + 4 * (lane & 1);
        *(ushort4*)p0 = hi;
        *(ushort4*)(p0 + 4 * 512) = lo;
    }
}

// ------------------------------------------------------------- mean over L (both sides)
__global__ __launch_bounds__(256) void mean_kernel(const float* __restrict__ e1,
                                                   const float* __restrict__ e2,
                                                   float* __restrict__ xcat) {
    int g = blockIdx.x * 256 + threadIdx.x;
    int side = blockIdx.y;
    if (g >= kB * kD) return;
    int b = g / kD, d = g - b * kD;
    const float* p = (side ? e2 : e1) + (size_t)b * kL * kD + d;
    float s = 0.f;
    for (int l = 0; l < kL; ++l) s += p[l * kD];
    xcat[b * 600 + side * 300 + d] = s * (1.0f / kL);
}

// ------------------------------------------------------------- match via MFMA (hi/lo split, LDS-staged B)
template<int MODE>
__global__ __launch_bounds__(256) void match_core(const unsigned short* __restrict__ sbf1,
                                                  const unsigned short* __restrict__ sbf2,
                                                  const float* __restrict__ sq1,
                                                  const float* __restrict__ sq2,
                                                  unsigned short* __restrict__ A,
                                                  unsigned short* __restrict__ At,
                                                  float* __restrict__ w1,
                                                  float* __restrict__ w2) {
    __shared__ short lb[8 * 8 * 512];   // 64KB: j-side fragments [J(8)][slot(8)][512]
    int tid = threadIdx.x;
    int lane = tid & 63, wave = tid >> 6;
    int quad = lane >> 4, l15 = lane & 15;
    int b = blockIdx.z;
    int i0 = blockIdx.y * 128, j0 = blockIdx.x * 128;
    int iw = i0 + wave * 32;
    int lo8 = lane * 8;

    // cooperative stage: 64 fragments of 1KB, 16 per wave
    const unsigned short* s2base = sbf2 + ((size_t)(b * 16 + (j0 >> 4)) * 8) * 512;
#pragma unroll
    for (int t = 0; t < 16; ++t) {
        int frag = wave * 16 + t;
        s8_t vld = *(const s8_t*)(s2base + (size_t)frag * 512 + lo8);
        *(s8_t*)(lb + frag * 512 + lo8) = vld;
    }

    const unsigned short* s1f = sbf1 + ((size_t)(b * 16 + (iw >> 4)) * 8) * 512 + lo8;
    const float* sq1p = sq1 + b * kL + iw;
    const float* sq2p = sq2 + b * kL + j0;

    float s1v[2][4];
#pragma unroll
    for (int mt = 0; mt < 2; ++mt)
#pragma unroll
        for (int r = 0; r < 4; ++r) s1v[mt][r] = sq1p[mt * 16 + quad * 4 + r];
    float s1c[2];
    if (MODE == 0) { s1c[0] = sq1p[l15]; s1c[1] = sq1p[16 + l15]; }

    float rs_acc[2][4] = {{0.f,0.f,0.f,0.f},{0.f,0.f,0.f,0.f}};
    __syncthreads();

    for (int half = 0; half < 2; ++half) {
        f4_t D[2][4] = {};
        f4_t Dp[4][2] = {};
#pragma unroll
        for (int kt = 0; kt < 4; ++kt) {
            s8_t a1h[2], a1l[2], b2h[4], b2l[4];
#pragma unroll
            for (int mt = 0; mt < 2; ++mt) {
                a1h[mt] = *(const s8_t*)(s1f + (size_t)(mt * 8 + kt) * 512);
                a1l[mt] = *(const s8_t*)(s1f + (size_t)(mt * 8 + kt + 4) * 512);
            }
#pragma unroll
            for (int n = 0; n < 4; ++n) {
                int fb = ((half * 4 + n) * 8 + kt) * 512 + lo8;
                b2h[n] = *(const s8_t*)&lb[fb];
                b2l[n] = *(const s8_t*)&lb[fb + 4 * 512];
            }
#pragma unroll
            for (int mt = 0; mt < 2; ++mt)
#pragma unroll
                for (int n = 0; n < 4; ++n) {
                    D[mt][n] = __builtin_amdgcn_mfma_f32_16x16x32_bf16(a1h[mt], b2h[n], D[mt][n], 0, 0, 0);
                    D[mt][n] = __builtin_amdgcn_mfma_f32_16x16x32_bf16(a1h[mt], b2l[n], D[mt][n], 0, 0, 0);
                    D[mt][n] = __builtin_amdgcn_mfma_f32_16x16x32_bf16(a1l[mt], b2h[n], D[mt][n], 0, 0, 0);
                    if (MODE == 0) {
                        Dp[n][mt] = __builtin_amdgcn_mfma_f32_16x16x32_bf16(b2h[n], a1h[mt], Dp[n][mt], 0, 0, 0);
                        Dp[n][mt] = __builtin_amdgcn_mfma_f32_16x16x32_bf16(b2l[n], a1h[mt], Dp[n][mt], 0, 0, 0);
                        Dp[n][mt] = __builtin_amdgcn_mfma_f32_16x16x32_bf16(b2h[n], a1l[mt], Dp[n][mt], 0, 0, 0);
                    }
                }
        }
        // ---- D epilogue: rows=i (quad*4+r per mt), col=j (l15 per n). Feeds At (rows j, K=i).
#pragma unroll
        for (int n = 0; n < 4; ++n) {
            float s2vn = sq2p[half * 64 + n * 16 + l15];
            float cs = 0.f;
            s8_t st;
#pragma unroll
            for (int mt = 0; mt < 2; ++mt) {
#pragma unroll
                for (int r = 0; r < 4; ++r) {
                    float d2 = fmaxf(s1v[mt][r] + s2vn - 2.f * D[mt][n][r], 0.f);
                    float av = __builtin_amdgcn_rcpf(1.f + __builtin_amdgcn_sqrtf(d2));
                    if (MODE == 0) st[mt * 4 + r] = (short)f2bf(av);
                    else { rs_acc[mt][r] += av; cs += av; }
                }
            }
            if (MODE == 0) {
                int grp = b * 16 + (j0 >> 4) + half * 4 + n;
                int kt_i = iw >> 5;
                *(s8_t*)(At + ((size_t)grp * 8 + kt_i) * 512 + lo8) = st;
            } else {
                cs += __shfl_xor(cs, 16, 64);
                cs += __shfl_xor(cs, 32, 64);
                if (lane < 16) atomicAdd(&w2[b * kL + j0 + half * 64 + n * 16 + lane], cs);
            }
        }
        // ---- Dp epilogue: rows=j (quad*4+r per n), col=i (l15 per mt). Feeds A (rows i, K=j).
        if (MODE == 0) {
#pragma unroll
            for (int np = 0; np < 2; ++np) {
#pragma unroll
                for (int mt = 0; mt < 2; ++mt) {
                    s8_t st;
#pragma unroll
                    for (int h2 = 0; h2 < 2; ++h2) {
                        int n = np * 2 + h2;
#pragma unroll
                        for (int r = 0; r < 4; ++r) {
                            float s2q = sq2p[half * 64 + n * 16 + quad * 4 + r];
                            float d2 = fmaxf(s2q + s1c[mt] - 2.f * Dp[n][mt][r], 0.f);
                            float av = __builtin_amdgcn_rcpf(1.f + __builtin_amdgcn_sqrtf(d2));
                            st[h2 * 4 + r] = (short)f2bf(av);
                        }
                    }
                    int grp = b * 16 + (iw >> 4) + mt;
                    int kt_j = (j0 >> 5) + half * 2 + np;
                    *(s8_t*)(A + ((size_t)grp * 8 + kt_j) * 512 + lo8) = st;
                }
            }
        }
    }
    if (MODE == 1) {
#pragma unroll
        for (int mt = 0; mt < 2; ++mt)
#pragma unroll
            for (int r = 0; r < 4; ++r) {
                float v = rs_acc[mt][r];
                v += __shfl_xor(v, 1, 64);
                v += __shfl_xor(v, 2, 64);
                v += __shfl_xor(v, 4, 64);
                v += __shfl_xor(v, 8, 64);
                if (l15 == 0) atomicAdd(&w1[b * kL + iw + mt * 16 + quad * 4 + r], v);
            }
    }
}

// ------------------------------------------------------------- W -> B-fragment layout (bf16, pi-permuted k)
__global__ __launch_bounds__(256) void wprep_kernel(const float* __restrict__ Ws,
                                                    unsigned short* __restrict__ Wf) {
    int layer = blockIdx.x;
    const float* W = Ws + layer * kL * kD;
    unsigned short* o = Wf + layer * W_FRAG;
    for (int t = threadIdx.x; t < W_FRAG; t += 256) {
        int j = t & 7, lane = (t >> 3) & 63, kt = (t >> 9) & 7, nt = t >> 12;
        int k = kt * 32 + (j >> 2) * 16 + ((lane >> 4) & 3) * 4 + (j & 3);  // pi
        int n = nt * 16 + (lane & 15);
        float v = (n < kD) ? W[k * kD + n] : 0.f;
        o[t] = f2bf(v);
    }
}

// ------------------------------------------------------------- f = A @ W via MFMA bf16 (fragment A), bf16 out
__global__ __launch_bounds__(256) void fgemm_mfma(const unsigned short* __restrict__ Abf,
                                                  const unsigned short* __restrict__ Wf,
                                                  unsigned short* __restrict__ out) {
    int tid = threadIdx.x;
    int lane = tid & 63, wave = tid >> 6;
    int quad = lane >> 4, l15 = lane & 15;
    size_t m0 = (size_t)blockIdx.x * 128 + wave * 32;
    f4_t acc[2][7] = {};
    const unsigned short* af = Abf + (size_t)(m0 >> 4) * 8 * 512 + lane * 8;
#pragma unroll
    for (int kt = 0; kt < 8; ++kt) {
        s8_t a0 = *(const s8_t*)(af + (size_t)kt * 512);
        s8_t a1 = *(const s8_t*)(af + (size_t)(8 + kt) * 512);
        const unsigned short* bp = Wf + (size_t)(kt * 64 + lane) * 8;
#pragma unroll
        for (int nt = 0; nt < 7; ++nt) {
            s8_t b = *(const s8_t*)(bp + (size_t)nt * 8 * 64 * 8);
            acc[0][nt] = __builtin_amdgcn_mfma_f32_16x16x32_bf16(a0, b, acc[0][nt], 0, 0, 0);
            acc[1][nt] = __builtin_amdgcn_mfma_f32_16x16x32_bf16(a1, b, acc[1][nt], 0, 0, 0);
        }
    }
#pragma unroll
    for (int mt = 0; mt < 2; ++mt)
#pragma unroll
        for (int nt = 0; nt < 7; ++nt) {
            int col = nt * 16 + l15;
            if (col < kD) {
#pragma unroll
                for (int r = 0; r < 4; ++r) {
                    size_t row = m0 + mt * 16 + quad * 4 + r;
                    out[row * kD + col] = f2bf(acc[mt][nt][r]);
                }
            }
        }
}

// ------------------------------------------------------------- conv(3x3, 2ch) + tanh + mean(1) [+ fused hi/lo prep]
__global__ __launch_bounds__(256) void conv_kernel(const float* __restrict__ e1,
                                                   const float* __restrict__ e2,
                                                   const unsigned short* __restrict__ f1,
                                                   const unsigned short* __restrict__ f2,
                                                   const float* __restrict__ ck,
                                                   const float* __restrict__ cb,
                                                   float* __restrict__ o1,
                                                   float* __restrict__ o2,
                                                   float* __restrict__ res,
                                                   int ro1, int ro2,
                                                   int do_prep,
                                                   const int* __restrict__ q1,
                                                   const int* __restrict__ q2,
                                                   unsigned short* __restrict__ sbf1,
                                                   unsigned short* __restrict__ sbf2,
                                                   float* __restrict__ sq1,
                                                   float* __restrict__ sq2,
                                                   float* __restrict__ w1,
                                                   float* __restrict__ w2) {
    __shared__ float le[18][104];
    __shared__ float lf[18][104];
    __shared__ float pm[8][104];
    __shared__ float ksh[19];
    int tid = threadIdx.x;
    int b = blockIdx.y;
    int l0 = blockIdx.x * 16;
    int side = blockIdx.z;
    const float* e = side ? e2 : e1;
    const unsigned short* f = side ? f2 : f1;
    float* o = side ? o2 : o1;
    const int* q = side ? q2 : q1;
    unsigned short* sb = side ? sbf2 : sbf1;
    float* sq = side ? sq2 : sq1;
    float* w = side ? w2 : w1;
    int res_off = side ? ro2 : ro1;
    if (tid < 19) ksh[tid] = (tid < 18) ? ck[tid] : cb[0];
    if (tid < 18) { le[tid][0] = 0.f; lf[tid][0] = 0.f; le[tid][101] = 0.f; lf[tid][101] = 0.f; }
    if (do_prep && tid < 16) w[b * kL + l0 + tid] = 0.f;
    for (int t = tid; t < 900; t += 256) {
        int a = t >= 450;
        int tt = a ? t - 450 : t;
        int r = tt / 25, c = tt - r * 25;
        int l = l0 - 1 + r;
        bool ok = (l >= 0 && l < kL);
        size_t base = ((size_t)b * kL + (ok ? l : 0)) * kD + c * 4;
        float vx = 0.f, vy = 0.f, vz = 0.f, vw = 0.f;
        if (!a) {
            if (ok) { float4 v = *(const float4*)(e + base); vx = v.x; vy = v.y; vz = v.z; vw = v.w; }
            le[r][1 + c * 4] = vx; le[r][2 + c * 4] = vy; le[r][3 + c * 4] = vz; le[r][4 + c * 4] = vw;
        } else {
            if (ok) { ushort4 u = *(const ushort4*)(f + base); vx = bf2f(u.x); vy = bf2f(u.y); vz = bf2f(u.z); vw = bf2f(u.w); }
            lf[r][1 + c * 4] = vx; lf[r][2 + c * 4] = vy; lf[r][3 + c * 4] = vz; lf[r][4 + c * 4] = vw;
        }
    }
    __syncthreads();
    int rg = tid >> 5, c4 = tid & 31;
    bool act = c4 < 25;
    int d0 = c4 * 4;
    float m4[4] = {0.f, 0.f, 0.f, 0.f};
#pragma unroll
    for (int rr = 0; rr < 2; ++rr) {
        int r = rg * 2 + rr;
        float a0 = 0.f, a1 = 0.f, a2 = 0.f, a3 = 0.f;
        if (act) {
            float bias = ksh[18];
            a0 = bias; a1 = bias; a2 = bias; a3 = bias;
#pragma unroll
            for (int ch = 0; ch < 2; ++ch) {
                const float (*L)[104] = ch ? lf : le;
                const float* kp = &ksh[ch * 9];
#pragma unroll
                for (int ky = 0; ky < 3; ++ky) {
                    const float* row = L[r + ky];
                    float4 v4 = *(const float4*)&row[d0];
                    float2 v2 = *(const float2*)&row[d0 + 4];
                    float k0 = kp[ky * 3], k1 = kp[ky * 3 + 1], k2 = kp[ky * 3 + 2];
                    a0 += k0 * v4.x + k1 * v4.y + k2 * v4.z;
                    a1 += k0 * v4.y + k1 * v4.z + k2 * v4.w;
                    a2 += k0 * v4.z + k1 * v4.w + k2 * v2.x;
                    a3 += k0 * v4.w + k1 * v2.x + k2 * v2.y;
                }
            }
            a0 = ftanh(a0); a1 = ftanh(a1); a2 = ftanh(a2); a3 = ftanh(a3);
            float4 st = {a0, a1, a2, a3};
            *(float4*)&o[((size_t)(b * kL) + l0 + r) * kD + d0] = st;
            m4[0] += a0; m4[1] += a1; m4[2] += a2; m4[3] += a3;
        }
        if (do_prep) {
            int row = b * kL + l0 + r;
            float v = (q[row] != 0) ? 1.f : 0.f;
            float x0 = a0 * v, x1 = a1 * v, x2 = a2 * v, x3 = a3 * v;
            float srow = x0 * x0 + x1 * x1 + x2 * x2 + x3 * x3;
#pragma unroll
            for (int m = 16; m >= 1; m >>= 1) srow += __shfl_xor(srow, m, 32);
            if (c4 == 0) sq[row] = srow;
            ushort4 hi = {0, 0, 0, 0}, lo = {0, 0, 0, 0};
            if (act) {
                unsigned short h;
                h = f2bf(x0); hi.x = h; lo.x = f2bf(x0 - bf2f(h));
                h = f2bf(x1); hi.y = h; lo.y = f2bf(x1 - bf2f(h));
                h = f2bf(x2); hi.z = h; lo.z = f2bf(x2 - bf2f(h));
                h = f2bf(x3); hi.w = h; lo.w = f2bf(x3 - bf2f(h));
            }
            int kt = c4 >> 3;
            int lfr = ((c4 >> 1) & 3) * 16 + (row & 15);
            unsigned short* p0 = sb + ((size_t)(row >> 4) * 8 + kt) * 512 + lfr * 8 + 4 * (c4 & 1);
            *(ushort4*)p0 = hi;
            *(ushort4*)(p0 + 4 * 512) = lo;
        }
    }
    if (act) { float4 st = {m4[0], m4[1], m4[2], m4[3]}; *(float4*)&pm[rg][d0] = st; }
    __syncthreads();
    if (tid < kD) {
        float s = 0.f;
#pragma unroll
        for (int g = 0; g < 8; ++g) s += pm[g][tid];
        atomicAdd(&res[b * 600 + res_off + tid], s * (1.0f / kL));
    }
}

// ------------------------------------------------------------- fused: e += avgpool3(o*w); hi/lo fragment prep
__global__ __launch_bounds__(256) void poolprep_kernel(const float* __restrict__ o1,
                                                       const float* __restrict__ o2,
                                                       const float* __restrict__ w1,
                                                       const float* __restrict__ w2,
                                                       const int* __restrict__ q1,
                                                       const int* __restrict__ q2,
                                                       float* __restrict__ e1,
                                                       float* __restrict__ e2,
                                                       unsigned short* __restrict__ sbf1,
                                                       unsigned short* __restrict__ sbf2,
                                                       float* __restrict__ sq1,
                                                       float* __restrict__ sq2) {
    int side = blockIdx.y;
    const float* o = side ? o2 : o1;
    const float* w = side ? w2 : w1;
    const int* q = side ? q2 : q1;
    float* e = side ? e2 : e1;
    unsigned short* sb = side ? sbf2 : sbf1;
    float* sq = side ? sq2 : sq1;
    int tid = threadIdx.x;
    int row = blockIdx.x * 4 + (tid >> 6);
    int lane = tid & 63;
    int l = row & (kL - 1);
    float v = q[row] != 0 ? 1.f : 0.f;
    float wm = w[row];
    float wp = (l > 0) ? w[row - 1] : 0.f;
    float wn = (l < kL - 1) ? w[row + 1] : 0.f;
    const float* po = o + (size_t)row * kD;
    float* pe = e + (size_t)row * kD;
    bool act = lane < 25;
    float x4[4] = {0.f, 0.f, 0.f, 0.f};
    if (act) {
        int d0 = lane * 4;
        float4 cur = *(const float4*)(po + d0);
        float4 prv = {0.f,0.f,0.f,0.f}, nxt = {0.f,0.f,0.f,0.f};
        if (l > 0) prv = *(const float4*)(po - kD + d0);
        if (l < kL - 1) nxt = *(const float4*)(po + kD + d0);
        float4 e4 = *(float4*)(pe + d0);
        x4[0] = e4.x + (prv.x * wp + cur.x * wm + nxt.x * wn) * (1.f / 3.f);
        x4[1] = e4.y + (prv.y * wp + cur.y * wm + nxt.y * wn) * (1.f / 3.f);
        x4[2] = e4.z + (prv.z * wp + cur.z * wm + nxt.z * wn) * (1.f / 3.f);
        x4[3] = e4.w + (prv.w * wp + cur.w * wm + nxt.w * wn) * (1.f / 3.f);
        float4 st = {x4[0], x4[1], x4[2], x4[3]};
        *(float4*)(pe + d0) = st;
#pragma unroll
        for (int c = 0; c < 4; ++c) x4[c] *= v;
    }
    float s = x4[0] * x4[0] + x4[1] * x4[1] + x4[2] * x4[2] + x4[3] * x4[3];
#pragma unroll
    for (int m = 32; m >= 1; m >>= 1) s += __shfl_xor(s, m, 64);
    if (lane == 0) sq[row] = s;
    if (lane < 32) {
        ushort4 hi = {0, 0, 0, 0}, lo = {0, 0, 0, 0};
        if (act) {
            unsigned short h;
            h = f2bf(x4[0]); hi.x = h; lo.x = f2bf(x4[0] - bf2f(h));
            h = f2bf(x4[1]); hi.y = h; lo.y = f2bf(x4[1] - bf2f(h));
            h = f2bf(x4[2]); hi.z = h; lo.z = f2bf(x4[2] - bf2f(h));
            h = f2bf(x4[3]); hi.w = h; lo.w = f2bf(x4[3] - bf2f(h));
        }
        int kt = lane >> 3;
        int lfr = ((lane >> 1) & 3) * 16 + (row & 15);
        unsigned short* p0 = sb + ((size_t)(row >> 4) * 8 + kt) * 512 + lfr * 8 + 4 * (lane & 1);
        *(ushort4*)p0 = hi;
        *(ushort4*)(p0 + 4 * 512) = lo;
    }
}

// ------------------------------------------------------------- head
__device__ __forceinline__ float block_sum(float v, float* red, int tid) {
#pragma unroll
    for (int m = 32; m >= 1; m >>= 1) v += __shfl_xor(v, m, 64);
    __syncthreads();
    if ((tid & 63) == 0) red[tid >> 6] = v;
    __syncthreads();
    return red[0] + red[1] + red[2] + red[3];
}

__global__ __launch_bounds__(256) void head_kernel(const float* __restrict__ xcat,
                                                   const float* __restrict__ fc1w,
                                                   const float* __restrict__ fc1b,
                                                   const float* __restrict__ lng,
                                                   const float* __restrict__ lnb,
                                                   const float* __restrict__ fc2w,
                                                   const float* __restrict__ fc2b,
                                                   float* __restrict__ out) {
    __shared__ float xr[600];
    __shared__ float red[4];
    int b = blockIdx.x, tid = threadIdx.x;
    for (int t = tid; t < 600; t += 256) xr[t] = xcat[b * 600 + t];
    __syncthreads();
    float h0 = fc1b[tid], h1 = fc1b[tid + 256];
    for (int k = 0; k < 600; ++k) {
        float xv = xr[k];
        h0 = fmaf(xv, fc1w[k * kLIN + tid], h0);
        h1 = fmaf(xv, fc1w[k * kLIN + tid + 256], h1);
    }
    float mu = block_sum(h0 + h1, red, tid) * (1.0f / kLIN);
    float d0 = h0 - mu, d1 = h1 - mu;
    float var = block_sum(d0 * d0 + d1 * d1, red, tid) * (1.0f / kLIN);
    float rstd = rsqrtf(var + 1e-5f);
    float n0 = d0 * rstd * lng[tid] + lnb[tid];
    float n1 = d1 * rstd * lng[tid + 256] + lnb[tid + 256];
    float r0 = fmaxf(n0, 0.f), r1 = fmaxf(n1, 0.f);
    float p0 = r0 * fc2w[tid * 2 + 0] + r1 * fc2w[(tid + 256) * 2 + 0];
    float p1 = r0 * fc2w[tid * 2 + 1] + r1 * fc2w[(tid + 256) * 2 + 1];
    float o0 = block_sum(p0, red, tid);
    float o1 = block_sum(p1, red, tid);
    if (tid == 0) { out[b * 2 + 0] = o0 + fc2b[0]; out[b * 2 + 1] = o1 + fc2b[1]; }
}

// ----------------------------------------------------------------------------
extern "C" void kernel_launch(void* const* d_in, const int* in_sizes, int n_in,
                              void* d_out, int out_size, void* d_ws, size_t ws_size,
                              hipStream_t stream) {
    const int*   q1   = (const int*)d_in[0];
    const int*   q2   = (const int*)d_in[1];
    const float* emb  = (const float*)d_in[2];
    const float* Ws   = (const float*)d_in[3];
    const float* ck   = (const float*)d_in[4];
    const float* cb   = (const float*)d_in[5];
    const float* fc1w = (const float*)d_in[6];
    const float* fc1b = (const float*)d_in[7];
    const float* lng  = (const float*)d_in[8];
    const float* lnb  = (const float*)d_in[9];
    const float* fc2w = (const float*)d_in[10];
    const float* fc2b = (const float*)d_in[11];
    float* out = (float*)d_out;
    float* ws  = (float*)d_ws;

    float* e1  = ws;
    float* e2  = e1 + SZ_E;
    unsigned short* fb1 = (unsigned short*)(e2 + SZ_E);
    unsigned short* fb2 = fb1 + SZ_E;
    unsigned short* Abf = (unsigned short*)((float*)fb1 + SZ_E);  // A|At fragments = SZ_A floats
    unsigned short* Atb = Abf + SZ_A;
    float* o1  = (float*)Abf;             // alias: A dead once f computed; o dead once A rewritten
    float* o2  = o1 + SZ_E;
    unsigned short* sbf1 = (unsigned short*)((float*)Abf + SZ_A); // fragment sbf, 2 sides
    unsigned short* sbf2 = sbf1 + kB * kL * 256;
    float* after = (float*)sbf1 + SZ_A;
    unsigned short* Wfrag = (unsigned short*)after;
    float* sq1 = after + W_FRAG;
    float* sq2 = sq1 + kB * kL;
    float* w1  = sq2 + kB * kL;
    float* w2  = w1 + kB * kL;
    float* xcat = w2 + kB * kL;

    hipMemsetAsync(xcat, 0, kB * 600 * sizeof(float), stream);
    embprep_kernel<<<dim3(kB * kL / 4, 2), 256, 0, stream>>>(q1, q2, emb, e1, e2,
                                                             sbf1, sbf2, sq1, sq2, w1, w2);
    wprep_kernel<<<2, 256, 0, stream>>>(Ws, Wfrag);
    mean_kernel<<<dim3(kB * kD / 256, 2), 256, 0, stream>>>(e1, e2, xcat);

    // ---- layer 0
    match_core<0><<<dim3(2, 2, kB), 256, 0, stream>>>(sbf1, sbf2, sq1, sq2,
                                                      Abf, Atb, nullptr, nullptr);
    fgemm_mfma<<<2 * kB * kL / 128, 256, 0, stream>>>(Abf, Wfrag, fb1);
    conv_kernel<<<dim3(kL / 16, kB, 2), 256, 0, stream>>>(e1, e2, fb1, fb2, ck, cb,
                                                          o1, o2, xcat, 100, 400,
                                                          1, q1, q2, sbf1, sbf2, sq1, sq2, w1, w2);
    match_core<1><<<dim3(2, 2, kB), 256, 0, stream>>>(sbf1, sbf2, sq1, sq2,
                                                      nullptr, nullptr, w1, w2);
    poolprep_kernel<<<dim3(kB * kL / 4, 2), 256, 0, stream>>>(o1, o2, w1, w2, q1, q2,
                                                              e1, e2, sbf1, sbf2, sq1, sq2);
    // ---- layer 1 (tail match1/pool dead: e unused afterwards)
    match_core<0><<<dim3(2, 2, kB), 256, 0, stream>>>(sbf1, sbf2, sq1, sq2,
                                                      Abf, Atb, nullptr, nullptr);
    fgemm_mfma<<<2 * kB * kL / 128, 256, 0, stream>>>(Abf, Wfrag + W_FRAG, fb1);
    conv_kernel<<<dim3(kL / 16, kB, 2), 256, 0, stream>>>(e1, e2, fb1, fb2, ck + 18, cb + 1,
                                                          o1, o2, xcat, 200, 500,
                                                          0, q1, q2, sbf1, sbf2, sq1, sq2, w1, w2);

    head_kernel<<<kB, 256, 0, stream>>>(xcat, fc1w, fc1b, lng, lnb, fc2w, fc2b, out);
}

// Round 7
// 487.542 us; speedup vs baseline: 3.1049x; 1.0364x over previous
//
#include <hip/hip_runtime.h>
#include <hip/hip_bf16.h>
#include <math.h>

// Problem constants
static constexpr int kB = 256;
static constexpr int kL = 256;
static constexpr int kD = 100;
static constexpr int kLIN = 512;
static constexpr int SZ_E = kB * kL * kD;     // 6,553,600
static constexpr int SZ_A = kB * kL * kL;     // 16,777,216
static constexpr int W_FRAG = 7 * 8 * 64 * 8; // 28672 bf16 per layer

typedef short  s8_t  __attribute__((ext_vector_type(8)));
typedef float  f4_t  __attribute__((ext_vector_type(4)));

// Fragment storage: rowgroup g = row>>4, slot s in [0,8): ((size_t)g*8+s)*512 shorts,
// lane = quad*16 + (row&15), 8 shorts/lane. sbf k-map is IDENTITY: k = s*32 + quad*8 + j
// (slots 0-3 = hi, slots 4-7 = lo of k-32*4). A/At + W use pi permutation (see wprep).

__device__ __forceinline__ unsigned short f2bf(float x) {
    __hip_bfloat16 h = __float2bfloat16(x);
    return *(unsigned short*)&h;
}
__device__ __forceinline__ float bf2f(unsigned short u) {
    unsigned int w = ((unsigned int)u) << 16;
    return *(float*)&w;
}
__device__ __forceinline__ float ftanh(float x) {
    float ax = fabsf(x);
    float t = __expf(-2.f * ax);
    float r = 1.f - 2.f * t / (1.f + t);
    return copysignf(r, x);
}

// shared helper: write one rowgroup (16 rows in rb[16][104]) as 8 coalesced fragments
__device__ __forceinline__ void frag_store(const float (*rb)[104], const float* vsh,
                                           unsigned short* sb, int g, int tid) {
    int lane = tid & 63, wave = tid >> 6;
    int qd = (lane >> 4) & 3, r15 = lane & 15;
    float v = vsh[r15];
#pragma unroll
    for (int ss = 0; ss < 2; ++ss) {
        int s = wave * 2 + ss;
        bool is_lo = s >= 4;
        int kbase = (is_lo ? s - 4 : s) * 32 + qd * 8;
        s8_t stv;
#pragma unroll
        for (int j = 0; j < 8; ++j) {
            int k = kbase + j;
            float x = (k < kD) ? rb[r15][k] * v : 0.f;
            unsigned short h = f2bf(x);
            stv[j] = (short)(is_lo ? f2bf(x - bf2f(h)) : h);
        }
        *(s8_t*)(sb + ((size_t)g * 8 + s) * 512 + lane * 8) = stv;
    }
}

// shared helper: per-row sum of squares (16 threads/row) * v -> sq
__device__ __forceinline__ void sq_store(const float (*rb)[104], const float* vsh,
                                         float* sq, int row0, int tid) {
    int r = tid >> 4, j = tid & 15;
    float s = 0.f;
    for (int d = j; d < kD; d += 16) { float x = rb[r][d]; s += x * x; }
#pragma unroll
    for (int m = 8; m >= 1; m >>= 1) s += __shfl_xor(s, m, 64);
    if (j == 0) sq[row0 + r] = s * vsh[r];
}

// ------------------------------------------------------------- embed + prep + fused mean (16-row blocks)
__global__ __launch_bounds__(256) void embprep_kernel(const int* __restrict__ q1,
                                                      const int* __restrict__ q2,
                                                      const float* __restrict__ emb,
                                                      float* __restrict__ e1,
                                                      float* __restrict__ e2,
                                                      unsigned short* __restrict__ sbf1,
                                                      unsigned short* __restrict__ sbf2,
                                                      float* __restrict__ sq1,
                                                      float* __restrict__ sq2,
                                                      float* __restrict__ xcat) {
    __shared__ float rb[16][104];
    __shared__ float vsh[16];
    int side = blockIdx.y;
    const int* q = side ? q2 : q1;
    float* e = side ? e2 : e1;
    unsigned short* sb = side ? sbf2 : sbf1;
    float* sq = side ? sq2 : sq1;
    int tid = threadIdx.x;
    int row0 = blockIdx.x * 16;
    int b = row0 >> 8;
    if (tid < 16) vsh[tid] = (q[row0 + tid] != 0) ? 1.f : 0.f;
    for (int t = tid; t < 400; t += 256) {
        int r = t / 25, c = t - r * 25;
        int qv = q[row0 + r];
        float4 v4 = *(const float4*)(emb + (size_t)qv * kD + c * 4);
        *(float4*)(e + (size_t)(row0 + r) * kD + c * 4) = v4;
        *(float4*)&rb[r][c * 4] = v4;
    }
    __syncthreads();
    sq_store(rb, vsh, sq, row0, tid);
    if (tid < kD) {
        float s = 0.f;
#pragma unroll
        for (int r = 0; r < 16; ++r) s += rb[r][tid];
        atomicAdd(&xcat[b * 600 + side * 300 + tid], s * (1.0f / kL));
    }
    frag_store(rb, vsh, sb, row0 >> 4, tid);
}

// ------------------------------------------------------------- match via MFMA (hi/lo split, LDS-staged B)
template<int MODE>
__global__ __launch_bounds__(256) void match_core(const unsigned short* __restrict__ sbf1,
                                                  const unsigned short* __restrict__ sbf2,
                                                  const float* __restrict__ sq1,
                                                  const float* __restrict__ sq2,
                                                  unsigned short* __restrict__ A,
                                                  unsigned short* __restrict__ At,
                                                  float* __restrict__ w1,
                                                  float* __restrict__ w2) {
    __shared__ short lb[8 * 8 * 512];   // 64KB: j-side fragments [J(8)][slot(8)][512]
    int tid = threadIdx.x;
    int lane = tid & 63, wave = tid >> 6;
    int quad = lane >> 4, l15 = lane & 15;
    int b = blockIdx.z;
    int i0 = blockIdx.y * 128, j0 = blockIdx.x * 128;
    int iw = i0 + wave * 32;
    int lo8 = lane * 8;

    const unsigned short* s2base = sbf2 + ((size_t)(b * 16 + (j0 >> 4)) * 8) * 512;
#pragma unroll
    for (int t = 0; t < 16; ++t) {
        int frag = wave * 16 + t;
        s8_t vld = *(const s8_t*)(s2base + (size_t)frag * 512 + lo8);
        *(s8_t*)(lb + frag * 512 + lo8) = vld;
    }

    const unsigned short* s1f = sbf1 + ((size_t)(b * 16 + (iw >> 4)) * 8) * 512 + lo8;
    const float* sq1p = sq1 + b * kL + iw;
    const float* sq2p = sq2 + b * kL + j0;

    float s1v[2][4];
#pragma unroll
    for (int mt = 0; mt < 2; ++mt)
#pragma unroll
        for (int r = 0; r < 4; ++r) s1v[mt][r] = sq1p[mt * 16 + quad * 4 + r];
    float s1c[2];
    if (MODE == 0) { s1c[0] = sq1p[l15]; s1c[1] = sq1p[16 + l15]; }

    float rs_acc[2][4] = {{0.f,0.f,0.f,0.f},{0.f,0.f,0.f,0.f}};
    __syncthreads();

    for (int half = 0; half < 2; ++half) {
        f4_t D[2][4] = {};
        f4_t Dp[4][2] = {};
#pragma unroll
        for (int kt = 0; kt < 4; ++kt) {
            s8_t a1h[2], a1l[2], b2h[4], b2l[4];
#pragma unroll
            for (int mt = 0; mt < 2; ++mt) {
                a1h[mt] = *(const s8_t*)(s1f + (size_t)(mt * 8 + kt) * 512);
                a1l[mt] = *(const s8_t*)(s1f + (size_t)(mt * 8 + kt + 4) * 512);
            }
#pragma unroll
            for (int n = 0; n < 4; ++n) {
                int fb = ((half * 4 + n) * 8 + kt) * 512 + lo8;
                b2h[n] = *(const s8_t*)&lb[fb];
                b2l[n] = *(const s8_t*)&lb[fb + 4 * 512];
            }
#pragma unroll
            for (int mt = 0; mt < 2; ++mt)
#pragma unroll
                for (int n = 0; n < 4; ++n) {
                    D[mt][n] = __builtin_amdgcn_mfma_f32_16x16x32_bf16(a1h[mt], b2h[n], D[mt][n], 0, 0, 0);
                    D[mt][n] = __builtin_amdgcn_mfma_f32_16x16x32_bf16(a1h[mt], b2l[n], D[mt][n], 0, 0, 0);
                    D[mt][n] = __builtin_amdgcn_mfma_f32_16x16x32_bf16(a1l[mt], b2h[n], D[mt][n], 0, 0, 0);
                    if (MODE == 0) {
                        Dp[n][mt] = __builtin_amdgcn_mfma_f32_16x16x32_bf16(b2h[n], a1h[mt], Dp[n][mt], 0, 0, 0);
                        Dp[n][mt] = __builtin_amdgcn_mfma_f32_16x16x32_bf16(b2l[n], a1h[mt], Dp[n][mt], 0, 0, 0);
                        Dp[n][mt] = __builtin_amdgcn_mfma_f32_16x16x32_bf16(b2h[n], a1l[mt], Dp[n][mt], 0, 0, 0);
                    }
                }
        }
        // ---- D epilogue: rows=i (quad*4+r per mt), col=j (l15 per n). Feeds At (rows j, K=i).
#pragma unroll
        for (int n = 0; n < 4; ++n) {
            float s2vn = sq2p[half * 64 + n * 16 + l15];
            float cs = 0.f;
            s8_t st;
#pragma unroll
            for (int mt = 0; mt < 2; ++mt) {
#pragma unroll
                for (int r = 0; r < 4; ++r) {
                    float d2 = fmaxf(s1v[mt][r] + s2vn - 2.f * D[mt][n][r], 0.f);
                    float av = __builtin_amdgcn_rcpf(1.f + __builtin_amdgcn_sqrtf(d2));
                    if (MODE == 0) st[mt * 4 + r] = (short)f2bf(av);
                    else { rs_acc[mt][r] += av; cs += av; }
                }
            }
            if (MODE == 0) {
                int grp = b * 16 + (j0 >> 4) + half * 4 + n;
                int kt_i = iw >> 5;
                *(s8_t*)(At + ((size_t)grp * 8 + kt_i) * 512 + lo8) = st;
            } else {
                cs += __shfl_xor(cs, 16, 64);
                cs += __shfl_xor(cs, 32, 64);
                if (lane < 16) atomicAdd(&w2[b * kL + j0 + half * 64 + n * 16 + lane], cs);
            }
        }
        // ---- Dp epilogue: rows=j (quad*4+r per n), col=i (l15 per mt). Feeds A (rows i, K=j).
        if (MODE == 0) {
#pragma unroll
            for (int np = 0; np < 2; ++np) {
#pragma unroll
                for (int mt = 0; mt < 2; ++mt) {
                    s8_t st;
#pragma unroll
                    for (int h2 = 0; h2 < 2; ++h2) {
                        int n = np * 2 + h2;
#pragma unroll
                        for (int r = 0; r < 4; ++r) {
                            float s2q = sq2p[half * 64 + n * 16 + quad * 4 + r];
                            float d2 = fmaxf(s2q + s1c[mt] - 2.f * Dp[n][mt][r], 0.f);
                            float av = __builtin_amdgcn_rcpf(1.f + __builtin_amdgcn_sqrtf(d2));
                            st[h2 * 4 + r] = (short)f2bf(av);
                        }
                    }
                    int grp = b * 16 + (iw >> 4) + mt;
                    int kt_j = (j0 >> 5) + half * 2 + np;
                    *(s8_t*)(A + ((size_t)grp * 8 + kt_j) * 512 + lo8) = st;
                }
            }
        }
    }
    if (MODE == 1) {
#pragma unroll
        for (int mt = 0; mt < 2; ++mt)
#pragma unroll
            for (int r = 0; r < 4; ++r) {
                float v = rs_acc[mt][r];
                v += __shfl_xor(v, 1, 64);
                v += __shfl_xor(v, 2, 64);
                v += __shfl_xor(v, 4, 64);
                v += __shfl_xor(v, 8, 64);
                if (l15 == 0) atomicAdd(&w1[b * kL + iw + mt * 16 + quad * 4 + r], v);
            }
    }
}

// ------------------------------------------------------------- W -> B-fragment layout (bf16, pi-permuted k)
__global__ __launch_bounds__(256) void wprep_kernel(const float* __restrict__ Ws,
                                                    unsigned short* __restrict__ Wf) {
    int layer = blockIdx.x;
    const float* W = Ws + layer * kL * kD;
    unsigned short* o = Wf + layer * W_FRAG;
    for (int t = threadIdx.x; t < W_FRAG; t += 256) {
        int j = t & 7, lane = (t >> 3) & 63, kt = (t >> 9) & 7, nt = t >> 12;
        int k = kt * 32 + (j >> 2) * 16 + ((lane >> 4) & 3) * 4 + (j & 3);  // pi
        int n = nt * 16 + (lane & 15);
        float v = (n < kD) ? W[k * kD + n] : 0.f;
        o[t] = f2bf(v);
    }
}

// ------------------------------------------------------------- f = A @ W via MFMA bf16 (fragment A), bf16 out
__global__ __launch_bounds__(256) void fgemm_mfma(const unsigned short* __restrict__ Abf,
                                                  const unsigned short* __restrict__ Wf,
                                                  unsigned short* __restrict__ out) {
    int tid = threadIdx.x;
    int lane = tid & 63, wave = tid >> 6;
    int quad = lane >> 4, l15 = lane & 15;
    size_t m0 = (size_t)blockIdx.x * 128 + wave * 32;
    f4_t acc[2][7] = {};
    const unsigned short* af = Abf + (size_t)(m0 >> 4) * 8 * 512 + lane * 8;
#pragma unroll
    for (int kt = 0; kt < 8; ++kt) {
        s8_t a0 = *(const s8_t*)(af + (size_t)kt * 512);
        s8_t a1 = *(const s8_t*)(af + (size_t)(8 + kt) * 512);
        const unsigned short* bp = Wf + (size_t)(kt * 64 + lane) * 8;
#pragma unroll
        for (int nt = 0; nt < 7; ++nt) {
            s8_t b = *(const s8_t*)(bp + (size_t)nt * 8 * 64 * 8);
            acc[0][nt] = __builtin_amdgcn_mfma_f32_16x16x32_bf16(a0, b, acc[0][nt], 0, 0, 0);
            acc[1][nt] = __builtin_amdgcn_mfma_f32_16x16x32_bf16(a1, b, acc[1][nt], 0, 0, 0);
        }
    }
#pragma unroll
    for (int mt = 0; mt < 2; ++mt)
#pragma unroll
        for (int nt = 0; nt < 7; ++nt) {
            int col = nt * 16 + l15;
            if (col < kD) {
#pragma unroll
                for (int r = 0; r < 4; ++r) {
                    size_t row = m0 + mt * 16 + quad * 4 + r;
                    out[row * kD + col] = f2bf(acc[mt][nt][r]);
                }
            }
        }
}

// ------------------------------------------------------------- conv(3x3, 2ch) + tanh + mean(1) [+ fused hi/lo prep]
__global__ __launch_bounds__(256) void conv_kernel(const float* __restrict__ e1,
                                                   const float* __restrict__ e2,
                                                   const unsigned short* __restrict__ f1,
                                                   const unsigned short* __restrict__ f2,
                                                   const float* __restrict__ ck,
                                                   const float* __restrict__ cb,
                                                   float* __restrict__ o1,
                                                   float* __restrict__ o2,
                                                   float* __restrict__ res,
                                                   int ro1, int ro2,
                                                   int do_prep,
                                                   const int* __restrict__ q1,
                                                   const int* __restrict__ q2,
                                                   unsigned short* __restrict__ sbf1,
                                                   unsigned short* __restrict__ sbf2,
                                                   float* __restrict__ sq1,
                                                   float* __restrict__ sq2,
                                                   float* __restrict__ w1,
                                                   float* __restrict__ w2) {
    __shared__ float le[18][104];
    __shared__ float lf[18][104];
    __shared__ float pm[8][104];
    __shared__ float ksh[19];
    int tid = threadIdx.x;
    int b = blockIdx.y;
    int l0 = blockIdx.x * 16;
    int side = blockIdx.z;
    const float* e = side ? e2 : e1;
    const unsigned short* f = side ? f2 : f1;
    float* o = side ? o2 : o1;
    const int* q = side ? q2 : q1;
    unsigned short* sb = side ? sbf2 : sbf1;
    float* sq = side ? sq2 : sq1;
    float* w = side ? w2 : w1;
    int res_off = side ? ro2 : ro1;
    if (tid < 19) ksh[tid] = (tid < 18) ? ck[tid] : cb[0];
    if (tid < 18) { le[tid][0] = 0.f; lf[tid][0] = 0.f; le[tid][101] = 0.f; lf[tid][101] = 0.f; }
    if (do_prep && tid < 16) w[b * kL + l0 + tid] = 0.f;
    for (int t = tid; t < 900; t += 256) {
        int a = t >= 450;
        int tt = a ? t - 450 : t;
        int r = tt / 25, c = tt - r * 25;
        int l = l0 - 1 + r;
        bool ok = (l >= 0 && l < kL);
        size_t base = ((size_t)b * kL + (ok ? l : 0)) * kD + c * 4;
        float vx = 0.f, vy = 0.f, vz = 0.f, vw = 0.f;
        if (!a) {
            if (ok) { float4 v = *(const float4*)(e + base); vx = v.x; vy = v.y; vz = v.z; vw = v.w; }
            le[r][1 + c * 4] = vx; le[r][2 + c * 4] = vy; le[r][3 + c * 4] = vz; le[r][4 + c * 4] = vw;
        } else {
            if (ok) { ushort4 u = *(const ushort4*)(f + base); vx = bf2f(u.x); vy = bf2f(u.y); vz = bf2f(u.z); vw = bf2f(u.w); }
            lf[r][1 + c * 4] = vx; lf[r][2 + c * 4] = vy; lf[r][3 + c * 4] = vz; lf[r][4 + c * 4] = vw;
        }
    }
    __syncthreads();
    int rg = tid >> 5, c4 = tid & 31;
    bool act = c4 < 25;
    int d0 = c4 * 4;
    float m4[4] = {0.f, 0.f, 0.f, 0.f};
#pragma unroll
    for (int rr = 0; rr < 2; ++rr) {
        int r = rg * 2 + rr;
        float a0 = 0.f, a1 = 0.f, a2 = 0.f, a3 = 0.f;
        if (act) {
            float bias = ksh[18];
            a0 = bias; a1 = bias; a2 = bias; a3 = bias;
#pragma unroll
            for (int ch = 0; ch < 2; ++ch) {
                const float (*L)[104] = ch ? lf : le;
                const float* kp = &ksh[ch * 9];
#pragma unroll
                for (int ky = 0; ky < 3; ++ky) {
                    const float* row = L[r + ky];
                    float4 v4 = *(const float4*)&row[d0];
                    float2 v2 = *(const float2*)&row[d0 + 4];
                    float k0 = kp[ky * 3], k1 = kp[ky * 3 + 1], k2 = kp[ky * 3 + 2];
                    a0 += k0 * v4.x + k1 * v4.y + k2 * v4.z;
                    a1 += k0 * v4.y + k1 * v4.z + k2 * v4.w;
                    a2 += k0 * v4.z + k1 * v4.w + k2 * v2.x;
                    a3 += k0 * v4.w + k1 * v2.x + k2 * v2.y;
                }
            }
            a0 = ftanh(a0); a1 = ftanh(a1); a2 = ftanh(a2); a3 = ftanh(a3);
            float4 st = {a0, a1, a2, a3};
            *(float4*)&o[((size_t)(b * kL) + l0 + r) * kD + d0] = st;
            m4[0] += a0; m4[1] += a1; m4[2] += a2; m4[3] += a3;
        }
        if (do_prep) {
            int row = b * kL + l0 + r;
            float v = (q[row] != 0) ? 1.f : 0.f;
            float x0 = a0 * v, x1 = a1 * v, x2 = a2 * v, x3 = a3 * v;
            float srow = x0 * x0 + x1 * x1 + x2 * x2 + x3 * x3;
#pragma unroll
            for (int m = 16; m >= 1; m >>= 1) srow += __shfl_xor(srow, m, 32);
            if (c4 == 0) sq[row] = srow;
            ushort4 hi = {0, 0, 0, 0}, lo = {0, 0, 0, 0};
            if (act) {
                unsigned short h;
                h = f2bf(x0); hi.x = h; lo.x = f2bf(x0 - bf2f(h));
                h = f2bf(x1); hi.y = h; lo.y = f2bf(x1 - bf2f(h));
                h = f2bf(x2); hi.z = h; lo.z = f2bf(x2 - bf2f(h));
                h = f2bf(x3); hi.w = h; lo.w = f2bf(x3 - bf2f(h));
            }
            int kt = c4 >> 3;
            int lfr = ((c4 >> 1) & 3) * 16 + (row & 15);
            unsigned short* p0 = sb + ((size_t)(row >> 4) * 8 + kt) * 512 + lfr * 8 + 4 * (c4 & 1);
            *(ushort4*)p0 = hi;
            *(ushort4*)(p0 + 4 * 512) = lo;
        }
    }
    if (act) { float4 st = {m4[0], m4[1], m4[2], m4[3]}; *(float4*)&pm[rg][d0] = st; }
    __syncthreads();
    if (tid < kD) {
        float s = 0.f;
#pragma unroll
        for (int g = 0; g < 8; ++g) s += pm[g][tid];
        atomicAdd(&res[b * 600 + res_off + tid], s * (1.0f / kL));
    }
}

// ------------------------------------------------------------- fused: e += avgpool3(o*w); hi/lo fragment prep (16-row blocks)
__global__ __launch_bounds__(256) void poolprep_kernel(const float* __restrict__ o1,
                                                       const float* __restrict__ o2,
                                                       const float* __restrict__ w1_,
                                                       const float* __restrict__ w2_,
                                                       const int* __restrict__ q1,
                                                       const int* __restrict__ q2,
                                                       float* __restrict__ e1,
                                                       float* __restrict__ e2,
                                                       unsigned short* __restrict__ sbf1,
                                                       unsigned short* __restrict__ sbf2,
                                                       float* __restrict__ sq1,
                                                       float* __restrict__ sq2) {
    __shared__ float tb[18][104];   // o*w with halo rows
    __shared__ float xb[16][104];   // updated e
    __shared__ float vsh[16];
    __shared__ float wsh[18];
    int side = blockIdx.y;
    const float* o = side ? o2 : o1;
    const float* w = side ? w2_ : w1_;
    const int* q = side ? q2 : q1;
    float* e = side ? e2 : e1;
    unsigned short* sb = side ? sbf2 : sbf1;
    float* sq = side ? sq2 : sq1;
    int tid = threadIdx.x;
    int row0 = blockIdx.x * 16;
    int l0 = row0 & (kL - 1);
    int base_b = row0 - l0;         // b * kL
    if (tid < 18) {
        int l = l0 - 1 + tid;
        wsh[tid] = (l >= 0 && l < kL) ? w[base_b + l] : 0.f;
    }
    if (tid < 16) vsh[tid] = (q[row0 + tid] != 0) ? 1.f : 0.f;
    __syncthreads();
    for (int t = tid; t < 450; t += 256) {
        int r = t / 25, c = t - r * 25;
        int l = l0 - 1 + r;
        float4 v4 = {0.f, 0.f, 0.f, 0.f};
        if (l >= 0 && l < kL) v4 = *(const float4*)(o + (size_t)(base_b + l) * kD + c * 4);
        float ww = wsh[r];
        tb[r][c * 4 + 0] = v4.x * ww;
        tb[r][c * 4 + 1] = v4.y * ww;
        tb[r][c * 4 + 2] = v4.z * ww;
        tb[r][c * 4 + 3] = v4.w * ww;
    }
    __syncthreads();
    for (int t = tid; t < 400; t += 256) {
        int r = t / 25, c = t - r * 25;
        float* ep = e + (size_t)(row0 + r) * kD + c * 4;
        float4 e4 = *(float4*)ep;
        float nx = e4.x + (tb[r][c * 4 + 0] + tb[r + 1][c * 4 + 0] + tb[r + 2][c * 4 + 0]) * (1.f / 3.f);
        float ny = e4.y + (tb[r][c * 4 + 1] + tb[r + 1][c * 4 + 1] + tb[r + 2][c * 4 + 1]) * (1.f / 3.f);
        float nz = e4.z + (tb[r][c * 4 + 2] + tb[r + 1][c * 4 + 2] + tb[r + 2][c * 4 + 2]) * (1.f / 3.f);
        float nw = e4.w + (tb[r][c * 4 + 3] + tb[r + 1][c * 4 + 3] + tb[r + 2][c * 4 + 3]) * (1.f / 3.f);
        float4 st = {nx, ny, nz, nw};
        *(float4*)ep = st;
        *(float4*)&xb[r][c * 4] = st;
    }
    __syncthreads();
    sq_store(xb, vsh, sq, row0, tid);
    frag_store(xb, vsh, sb, row0 >> 4, tid);
}

// ------------------------------------------------------------- head
__device__ __forceinline__ float block_sum(float v, float* red, int tid) {
#pragma unroll
    for (int m = 32; m >= 1; m >>= 1) v += __shfl_xor(v, m, 64);
    __syncthreads();
    if ((tid & 63) == 0) red[tid >> 6] = v;
    __syncthreads();
    return red[0] + red[1] + red[2] + red[3];
}

__global__ __launch_bounds__(256) void head_kernel(const float* __restrict__ xcat,
                                                   const float* __restrict__ fc1w,
                                                   const float* __restrict__ fc1b,
                                                   const float* __restrict__ lng,
                                                   const float* __restrict__ lnb,
                                                   const float* __restrict__ fc2w,
                                                   const float* __restrict__ fc2b,
                                                   float* __restrict__ out) {
    __shared__ float xr[600];
    __shared__ float red[4];
    int b = blockIdx.x, tid = threadIdx.x;
    for (int t = tid; t < 600; t += 256) xr[t] = xcat[b * 600 + t];
    __syncthreads();
    float h0 = fc1b[tid], h1 = fc1b[tid + 256];
    for (int k = 0; k < 600; ++k) {
        float xv = xr[k];
        h0 = fmaf(xv, fc1w[k * kLIN + tid], h0);
        h1 = fmaf(xv, fc1w[k * kLIN + tid + 256], h1);
    }
    float mu = block_sum(h0 + h1, red, tid) * (1.0f / kLIN);
    float d0 = h0 - mu, d1 = h1 - mu;
    float var = block_sum(d0 * d0 + d1 * d1, red, tid) * (1.0f / kLIN);
    float rstd = rsqrtf(var + 1e-5f);
    float n0 = d0 * rstd * lng[tid] + lnb[tid];
    float n1 = d1 * rstd * lng[tid + 256] + lnb[tid + 256];
    float r0 = fmaxf(n0, 0.f), r1 = fmaxf(n1, 0.f);
    float p0 = r0 * fc2w[tid * 2 + 0] + r1 * fc2w[(tid + 256) * 2 + 0];
    float p1 = r0 * fc2w[tid * 2 + 1] + r1 * fc2w[(tid + 256) * 2 + 1];
    float o0 = block_sum(p0, red, tid);
    float o1 = block_sum(p1, red, tid);
    if (tid == 0) { out[b * 2 + 0] = o0 + fc2b[0]; out[b * 2 + 1] = o1 + fc2b[1]; }
}

// ----------------------------------------------------------------------------
extern "C" void kernel_launch(void* const* d_in, const int* in_sizes, int n_in,
                              void* d_out, int out_size, void* d_ws, size_t ws_size,
                              hipStream_t stream) {
    const int*   q1   = (const int*)d_in[0];
    const int*   q2   = (const int*)d_in[1];
    const float* emb  = (const float*)d_in[2];
    const float* Ws   = (const float*)d_in[3];
    const float* ck   = (const float*)d_in[4];
    const float* cb   = (const float*)d_in[5];
    const float* fc1w = (const float*)d_in[6];
    const float* fc1b = (const float*)d_in[7];
    const float* lng  = (const float*)d_in[8];
    const float* lnb  = (const float*)d_in[9];
    const float* fc2w = (const float*)d_in[10];
    const float* fc2b = (const float*)d_in[11];
    float* out = (float*)d_out;
    float* ws  = (float*)d_ws;

    float* e1  = ws;
    float* e2  = e1 + SZ_E;
    unsigned short* fb1 = (unsigned short*)(e2 + SZ_E);
    unsigned short* fb2 = fb1 + SZ_E;
    unsigned short* Abf = (unsigned short*)((float*)fb1 + SZ_E);  // A|At fragments = SZ_A floats
    unsigned short* Atb = Abf + SZ_A;
    float* o1  = (float*)Abf;             // alias: A dead once f computed; o dead once A rewritten
    float* o2  = o1 + SZ_E;
    unsigned short* sbf1 = (unsigned short*)((float*)Abf + SZ_A); // fragment sbf, 2 sides
    unsigned short* sbf2 = sbf1 + kB * kL * 256;
    float* after = (float*)sbf1 + SZ_A;
    unsigned short* Wfrag = (unsigned short*)after;
    float* sq1 = after + W_FRAG;
    float* sq2 = sq1 + kB * kL;
    float* w1  = sq2 + kB * kL;
    float* w2  = w1 + kB * kL;
    float* xcat = w2 + kB * kL;

    hipMemsetAsync(xcat, 0, kB * 600 * sizeof(float), stream);
    embprep_kernel<<<dim3(kB * kL / 16, 2), 256, 0, stream>>>(q1, q2, emb, e1, e2,
                                                              sbf1, sbf2, sq1, sq2, xcat);
    wprep_kernel<<<2, 256, 0, stream>>>(Ws, Wfrag);

    // ---- layer 0
    match_core<0><<<dim3(2, 2, kB), 256, 0, stream>>>(sbf1, sbf2, sq1, sq2,
                                                      Abf, Atb, nullptr, nullptr);
    fgemm_mfma<<<2 * kB * kL / 128, 256, 0, stream>>>(Abf, Wfrag, fb1);
    conv_kernel<<<dim3(kL / 16, kB, 2), 256, 0, stream>>>(e1, e2, fb1, fb2, ck, cb,
                                                          o1, o2, xcat, 100, 400,
                                                          1, q1, q2, sbf1, sbf2, sq1, sq2, w1, w2);
    match_core<1><<<dim3(2, 2, kB), 256, 0, stream>>>(sbf1, sbf2, sq1, sq2,
                                                      nullptr, nullptr, w1, w2);
    poolprep_kernel<<<dim3(kB * kL / 16, 2), 256, 0, stream>>>(o1, o2, w1, w2, q1, q2,
                                                               e1, e2, sbf1, sbf2, sq1, sq2);
    // ---- layer 1 (tail match1/pool dead: e unused afterwards)
    match_core<0><<<dim3(2, 2, kB), 256, 0, stream>>>(sbf1, sbf2, sq1, sq2,
                                                      Abf, Atb, nullptr, nullptr);
    fgemm_mfma<<<2 * kB * kL / 128, 256, 0, stream>>>(Abf, Wfrag + W_FRAG, fb1);
    conv_kernel<<<dim3(kL / 16, kB, 2), 256, 0, stream>>>(e1, e2, fb1, fb2, ck + 18, cb + 1,
                                                          o1, o2, xcat, 200, 500,
                                                          0, q1, q2, sbf1, sbf2, sq1, sq2, w1, w2);

    head_kernel<<<kB, 256, 0, stream>>>(xcat, fc1w, fc1b, lng, lnb, fc2w, fc2b, out);
}

// Round 8
// 418.251 us; speedup vs baseline: 3.6192x; 1.1657x over previous
//
#include <hip/hip_runtime.h>
#include <hip/hip_bf16.h>
#include <math.h>

// Problem constants
static constexpr int kB = 256;
static constexpr int kL = 256;
static constexpr int kD = 100;
static constexpr int kLIN = 512;
static constexpr int SZ_E = kB * kL * kD;     // 6,553,600
static constexpr int SZ_A = kB * kL * kL;     // 16,777,216
static constexpr int W_FRAG = 7 * 8 * 64 * 8; // 28672 bf16 per layer

typedef short  s8_t  __attribute__((ext_vector_type(8)));
typedef float  f4_t  __attribute__((ext_vector_type(4)));

// sbf fragment storage (hi-only bf16): rowgroup g = row>>4, slot s in [0,4):
//   ((size_t)g*4 + s)*512 shorts, lane = quad*16 + (row&15), 8 shorts/lane,
//   k = s*32 + quad*8 + j (identity map). sq is computed from the SAME
//   bf16-rounded masked values so that identical rows give d2 ~= 0 exactly.
// A/At fragments: 8 slots (K=256), pi-permuted k (see wprep) — unchanged.

__device__ __forceinline__ unsigned short f2bf(float x) {
    __hip_bfloat16 h = __float2bfloat16(x);
    return *(unsigned short*)&h;
}
__device__ __forceinline__ float bf2f(unsigned short u) {
    unsigned int w = ((unsigned int)u) << 16;
    return *(float*)&w;
}
__device__ __forceinline__ float ftanh(float x) {
    float ax = fabsf(x);
    float t = __expf(-2.f * ax);
    float r = 1.f - 2.f * t / (1.f + t);
    return copysignf(r, x);
}

// write one rowgroup (16 rows in rb[16][104]) as 4 coalesced hi fragments (one per wave)
__device__ __forceinline__ void frag_store(const float (*rb)[104], const float* vsh,
                                           unsigned short* sb, int g, int tid) {
    int lane = tid & 63, wave = tid >> 6;   // wave = slot
    int qd = (lane >> 4) & 3, r15 = lane & 15;
    float v = vsh[r15];
    int kbase = wave * 32 + qd * 8;
    s8_t stv;
#pragma unroll
    for (int j = 0; j < 8; ++j) {
        int k = kbase + j;
        float x = (k < kD) ? rb[r15][k] * v : 0.f;
        stv[j] = (short)f2bf(x);
    }
    *(s8_t*)(sb + ((size_t)g * 4 + wave) * 512 + lane * 8) = stv;
}

// per-row sum of squares of bf16-ROUNDED masked values (16 threads/row)
__device__ __forceinline__ void sq_store(const float (*rb)[104], const float* vsh,
                                         float* sq, int row0, int tid) {
    int r = tid >> 4, j = tid & 15;
    float v = vsh[r];
    float s = 0.f;
    for (int d = j; d < kD; d += 16) { float x = bf2f(f2bf(rb[r][d] * v)); s += x * x; }
#pragma unroll
    for (int m = 8; m >= 1; m >>= 1) s += __shfl_xor(s, m, 64);
    if (j == 0) sq[row0 + r] = s;
}

// ------------------------------------------------------------- embed + prep + fused mean (16-row blocks)
__global__ __launch_bounds__(256) void embprep_kernel(const int* __restrict__ q1,
                                                      const int* __restrict__ q2,
                                                      const float* __restrict__ emb,
                                                      float* __restrict__ e1,
                                                      float* __restrict__ e2,
                                                      unsigned short* __restrict__ sbf1,
                                                      unsigned short* __restrict__ sbf2,
                                                      float* __restrict__ sq1,
                                                      float* __restrict__ sq2,
                                                      float* __restrict__ xcat) {
    __shared__ float rb[16][104];
    __shared__ float vsh[16];
    int side = blockIdx.y;
    const int* q = side ? q2 : q1;
    float* e = side ? e2 : e1;
    unsigned short* sb = side ? sbf2 : sbf1;
    float* sq = side ? sq2 : sq1;
    int tid = threadIdx.x;
    int row0 = blockIdx.x * 16;
    int b = row0 >> 8;
    if (tid < 16) vsh[tid] = (q[row0 + tid] != 0) ? 1.f : 0.f;
    for (int t = tid; t < 400; t += 256) {
        int r = t / 25, c = t - r * 25;
        int qv = q[row0 + r];
        float4 v4 = *(const float4*)(emb + (size_t)qv * kD + c * 4);
        *(float4*)(e + (size_t)(row0 + r) * kD + c * 4) = v4;
        *(float4*)&rb[r][c * 4] = v4;
    }
    __syncthreads();
    sq_store(rb, vsh, sq, row0, tid);
    if (tid < kD) {
        float s = 0.f;
#pragma unroll
        for (int r = 0; r < 16; ++r) s += rb[r][tid];
        atomicAdd(&xcat[b * 600 + side * 300 + tid], s * (1.0f / kL));
    }
    frag_store(rb, vsh, sb, row0 >> 4, tid);
}

// ------------------------------------------------------------- match via MFMA (hi-only, LDS-staged B)
template<int MODE>
__global__ __launch_bounds__(256) void match_core(const unsigned short* __restrict__ sbf1,
                                                  const unsigned short* __restrict__ sbf2,
                                                  const float* __restrict__ sq1,
                                                  const float* __restrict__ sq2,
                                                  unsigned short* __restrict__ A,
                                                  unsigned short* __restrict__ At,
                                                  float* __restrict__ w1,
                                                  float* __restrict__ w2) {
    __shared__ short lb[8 * 4 * 512];   // 32KB: j-side fragments [J(8)][slot(4)][512]
    int tid = threadIdx.x;
    int lane = tid & 63, wave = tid >> 6;
    int quad = lane >> 4, l15 = lane & 15;
    int b = blockIdx.z;
    int i0 = blockIdx.y * 128, j0 = blockIdx.x * 128;
    int iw = i0 + wave * 32;
    int lo8 = lane * 8;

    const unsigned short* s2base = sbf2 + ((size_t)(b * 16 + (j0 >> 4)) * 4) * 512;
#pragma unroll
    for (int t = 0; t < 8; ++t) {
        int frag = wave * 8 + t;
        s8_t vld = *(const s8_t*)(s2base + (size_t)frag * 512 + lo8);
        *(s8_t*)(lb + frag * 512 + lo8) = vld;
    }

    const unsigned short* s1f = sbf1 + ((size_t)(b * 16 + (iw >> 4)) * 4) * 512 + lo8;
    const float* sq1p = sq1 + b * kL + iw;
    const float* sq2p = sq2 + b * kL + j0;

    float s1v[2][4];
#pragma unroll
    for (int mt = 0; mt < 2; ++mt)
#pragma unroll
        for (int r = 0; r < 4; ++r) s1v[mt][r] = sq1p[mt * 16 + quad * 4 + r];
    float s1c[2];
    if (MODE == 0) { s1c[0] = sq1p[l15]; s1c[1] = sq1p[16 + l15]; }

    float rs_acc[2][4] = {{0.f,0.f,0.f,0.f},{0.f,0.f,0.f,0.f}};
    __syncthreads();

    for (int half = 0; half < 2; ++half) {
        f4_t D[2][4] = {};
        f4_t Dp[4][2] = {};
#pragma unroll
        for (int kt = 0; kt < 4; ++kt) {
            s8_t a1h[2], b2h[4];
#pragma unroll
            for (int mt = 0; mt < 2; ++mt)
                a1h[mt] = *(const s8_t*)(s1f + (size_t)(mt * 4 + kt) * 512);
#pragma unroll
            for (int n = 0; n < 4; ++n) {
                int fb = ((half * 4 + n) * 4 + kt) * 512 + lo8;
                b2h[n] = *(const s8_t*)&lb[fb];
            }
#pragma unroll
            for (int mt = 0; mt < 2; ++mt)
#pragma unroll
                for (int n = 0; n < 4; ++n) {
                    D[mt][n] = __builtin_amdgcn_mfma_f32_16x16x32_bf16(a1h[mt], b2h[n], D[mt][n], 0, 0, 0);
                    if (MODE == 0)
                        Dp[n][mt] = __builtin_amdgcn_mfma_f32_16x16x32_bf16(b2h[n], a1h[mt], Dp[n][mt], 0, 0, 0);
                }
        }
        // ---- D epilogue: rows=i (quad*4+r per mt), col=j (l15 per n). Feeds At (rows j, K=i).
#pragma unroll
        for (int n = 0; n < 4; ++n) {
            float s2vn = sq2p[half * 64 + n * 16 + l15];
            float cs = 0.f;
            s8_t st;
#pragma unroll
            for (int mt = 0; mt < 2; ++mt) {
#pragma unroll
                for (int r = 0; r < 4; ++r) {
                    float d2 = fmaxf(s1v[mt][r] + s2vn - 2.f * D[mt][n][r], 0.f);
                    float av = __builtin_amdgcn_rcpf(1.f + __builtin_amdgcn_sqrtf(d2));
                    if (MODE == 0) st[mt * 4 + r] = (short)f2bf(av);
                    else { rs_acc[mt][r] += av; cs += av; }
                }
            }
            if (MODE == 0) {
                int grp = b * 16 + (j0 >> 4) + half * 4 + n;
                int kt_i = iw >> 5;
                *(s8_t*)(At + ((size_t)grp * 8 + kt_i) * 512 + lo8) = st;
            } else {
                cs += __shfl_xor(cs, 16, 64);
                cs += __shfl_xor(cs, 32, 64);
                if (lane < 16) atomicAdd(&w2[b * kL + j0 + half * 64 + n * 16 + lane], cs);
            }
        }
        // ---- Dp epilogue: rows=j (quad*4+r per n), col=i (l15 per mt). Feeds A (rows i, K=j).
        if (MODE == 0) {
#pragma unroll
            for (int np = 0; np < 2; ++np) {
#pragma unroll
                for (int mt = 0; mt < 2; ++mt) {
                    s8_t st;
#pragma unroll
                    for (int h2 = 0; h2 < 2; ++h2) {
                        int n = np * 2 + h2;
#pragma unroll
                        for (int r = 0; r < 4; ++r) {
                            float s2q = sq2p[half * 64 + n * 16 + quad * 4 + r];
                            float d2 = fmaxf(s2q + s1c[mt] - 2.f * Dp[n][mt][r], 0.f);
                            float av = __builtin_amdgcn_rcpf(1.f + __builtin_amdgcn_sqrtf(d2));
                            st[h2 * 4 + r] = (short)f2bf(av);
                        }
                    }
                    int grp = b * 16 + (iw >> 4) + mt;
                    int kt_j = (j0 >> 5) + half * 2 + np;
                    *(s8_t*)(A + ((size_t)grp * 8 + kt_j) * 512 + lo8) = st;
                }
            }
        }
    }
    if (MODE == 1) {
#pragma unroll
        for (int mt = 0; mt < 2; ++mt)
#pragma unroll
            for (int r = 0; r < 4; ++r) {
                float v = rs_acc[mt][r];
                v += __shfl_xor(v, 1, 64);
                v += __shfl_xor(v, 2, 64);
                v += __shfl_xor(v, 4, 64);
                v += __shfl_xor(v, 8, 64);
                if (l15 == 0) atomicAdd(&w1[b * kL + iw + mt * 16 + quad * 4 + r], v);
            }
    }
}

// ------------------------------------------------------------- W -> B-fragment layout (bf16, pi-permuted k)
__global__ __launch_bounds__(256) void wprep_kernel(const float* __restrict__ Ws,
                                                    unsigned short* __restrict__ Wf) {
    int layer = blockIdx.x;
    const float* W = Ws + layer * kL * kD;
    unsigned short* o = Wf + layer * W_FRAG;
    for (int t = threadIdx.x; t < W_FRAG; t += 256) {
        int j = t & 7, lane = (t >> 3) & 63, kt = (t >> 9) & 7, nt = t >> 12;
        int k = kt * 32 + (j >> 2) * 16 + ((lane >> 4) & 3) * 4 + (j & 3);  // pi
        int n = nt * 16 + (lane & 15);
        float v = (n < kD) ? W[k * kD + n] : 0.f;
        o[t] = f2bf(v);
    }
}

// ------------------------------------------------------------- f = A @ W via MFMA bf16 (fragment A), bf16 out
__global__ __launch_bounds__(256) void fgemm_mfma(const unsigned short* __restrict__ Abf,
                                                  const unsigned short* __restrict__ Wf,
                                                  unsigned short* __restrict__ out) {
    int tid = threadIdx.x;
    int lane = tid & 63, wave = tid >> 6;
    int quad = lane >> 4, l15 = lane & 15;
    size_t m0 = (size_t)blockIdx.x * 128 + wave * 32;
    f4_t acc[2][7] = {};
    const unsigned short* af = Abf + (size_t)(m0 >> 4) * 8 * 512 + lane * 8;
#pragma unroll
    for (int kt = 0; kt < 8; ++kt) {
        s8_t a0 = *(const s8_t*)(af + (size_t)kt * 512);
        s8_t a1 = *(const s8_t*)(af + (size_t)(8 + kt) * 512);
        const unsigned short* bp = Wf + (size_t)(kt * 64 + lane) * 8;
#pragma unroll
        for (int nt = 0; nt < 7; ++nt) {
            s8_t b = *(const s8_t*)(bp + (size_t)nt * 8 * 64 * 8);
            acc[0][nt] = __builtin_amdgcn_mfma_f32_16x16x32_bf16(a0, b, acc[0][nt], 0, 0, 0);
            acc[1][nt] = __builtin_amdgcn_mfma_f32_16x16x32_bf16(a1, b, acc[1][nt], 0, 0, 0);
        }
    }
#pragma unroll
    for (int mt = 0; mt < 2; ++mt)
#pragma unroll
        for (int nt = 0; nt < 7; ++nt) {
            int col = nt * 16 + l15;
            if (col < kD) {
#pragma unroll
                for (int r = 0; r < 4; ++r) {
                    size_t row = m0 + mt * 16 + quad * 4 + r;
                    out[row * kD + col] = f2bf(acc[mt][nt][r]);
                }
            }
        }
}

// ------------------------------------------------------------- conv(3x3, 2ch) + tanh + mean(1) [+ fused hi prep]
__global__ __launch_bounds__(256) void conv_kernel(const float* __restrict__ e1,
                                                   const float* __restrict__ e2,
                                                   const unsigned short* __restrict__ f1,
                                                   const unsigned short* __restrict__ f2,
                                                   const float* __restrict__ ck,
                                                   const float* __restrict__ cb,
                                                   float* __restrict__ o1,
                                                   float* __restrict__ o2,
                                                   float* __restrict__ res,
                                                   int ro1, int ro2,
                                                   int do_prep,
                                                   const int* __restrict__ q1,
                                                   const int* __restrict__ q2,
                                                   unsigned short* __restrict__ sbf1,
                                                   unsigned short* __restrict__ sbf2,
                                                   float* __restrict__ sq1,
                                                   float* __restrict__ sq2,
                                                   float* __restrict__ w1,
                                                   float* __restrict__ w2) {
    __shared__ float le[18][104];
    __shared__ float lf[18][104];
    __shared__ float pm[8][104];
    __shared__ float ksh[19];
    int tid = threadIdx.x;
    int b = blockIdx.y;
    int l0 = blockIdx.x * 16;
    int side = blockIdx.z;
    const float* e = side ? e2 : e1;
    const unsigned short* f = side ? f2 : f1;
    float* o = side ? o2 : o1;
    const int* q = side ? q2 : q1;
    unsigned short* sb = side ? sbf2 : sbf1;
    float* sq = side ? sq2 : sq1;
    float* w = side ? w2 : w1;
    int res_off = side ? ro2 : ro1;
    if (tid < 19) ksh[tid] = (tid < 18) ? ck[tid] : cb[0];
    if (tid < 18) { le[tid][0] = 0.f; lf[tid][0] = 0.f; le[tid][101] = 0.f; lf[tid][101] = 0.f; }
    if (do_prep && tid < 16) w[b * kL + l0 + tid] = 0.f;
    for (int t = tid; t < 900; t += 256) {
        int a = t >= 450;
        int tt = a ? t - 450 : t;
        int r = tt / 25, c = tt - r * 25;
        int l = l0 - 1 + r;
        bool ok = (l >= 0 && l < kL);
        size_t base = ((size_t)b * kL + (ok ? l : 0)) * kD + c * 4;
        float vx = 0.f, vy = 0.f, vz = 0.f, vw = 0.f;
        if (!a) {
            if (ok) { float4 v = *(const float4*)(e + base); vx = v.x; vy = v.y; vz = v.z; vw = v.w; }
            le[r][1 + c * 4] = vx; le[r][2 + c * 4] = vy; le[r][3 + c * 4] = vz; le[r][4 + c * 4] = vw;
        } else {
            if (ok) { ushort4 u = *(const ushort4*)(f + base); vx = bf2f(u.x); vy = bf2f(u.y); vz = bf2f(u.z); vw = bf2f(u.w); }
            lf[r][1 + c * 4] = vx; lf[r][2 + c * 4] = vy; lf[r][3 + c * 4] = vz; lf[r][4 + c * 4] = vw;
        }
    }
    __syncthreads();
    int rg = tid >> 5, c4 = tid & 31;
    bool act = c4 < 25;
    int d0 = c4 * 4;
    float m4[4] = {0.f, 0.f, 0.f, 0.f};
#pragma unroll
    for (int rr = 0; rr < 2; ++rr) {
        int r = rg * 2 + rr;
        float a0 = 0.f, a1 = 0.f, a2 = 0.f, a3 = 0.f;
        if (act) {
            float bias = ksh[18];
            a0 = bias; a1 = bias; a2 = bias; a3 = bias;
#pragma unroll
            for (int ch = 0; ch < 2; ++ch) {
                const float (*L)[104] = ch ? lf : le;
                const float* kp = &ksh[ch * 9];
#pragma unroll
                for (int ky = 0; ky < 3; ++ky) {
                    const float* row = L[r + ky];
                    float4 v4 = *(const float4*)&row[d0];
                    float2 v2 = *(const float2*)&row[d0 + 4];
                    float k0 = kp[ky * 3], k1 = kp[ky * 3 + 1], k2 = kp[ky * 3 + 2];
                    a0 += k0 * v4.x + k1 * v4.y + k2 * v4.z;
                    a1 += k0 * v4.y + k1 * v4.z + k2 * v4.w;
                    a2 += k0 * v4.z + k1 * v4.w + k2 * v2.x;
                    a3 += k0 * v4.w + k1 * v2.x + k2 * v2.y;
                }
            }
            a0 = ftanh(a0); a1 = ftanh(a1); a2 = ftanh(a2); a3 = ftanh(a3);
            float4 st = {a0, a1, a2, a3};
            *(float4*)&o[((size_t)(b * kL) + l0 + r) * kD + d0] = st;
            m4[0] += a0; m4[1] += a1; m4[2] += a2; m4[3] += a3;
        }
        if (do_prep) {
            int row = b * kL + l0 + r;
            float v = (q[row] != 0) ? 1.f : 0.f;
            ushort4 hi = {0, 0, 0, 0};
            float xr0 = 0.f, xr1 = 0.f, xr2 = 0.f, xr3 = 0.f;
            if (act) {
                hi.x = f2bf(a0 * v); xr0 = bf2f(hi.x);
                hi.y = f2bf(a1 * v); xr1 = bf2f(hi.y);
                hi.z = f2bf(a2 * v); xr2 = bf2f(hi.z);
                hi.w = f2bf(a3 * v); xr3 = bf2f(hi.w);
            }
            float srow = xr0 * xr0 + xr1 * xr1 + xr2 * xr2 + xr3 * xr3;
#pragma unroll
            for (int m = 16; m >= 1; m >>= 1) srow += __shfl_xor(srow, m, 32);
            if (c4 == 0) sq[row] = srow;
            int kt = c4 >> 3;
            int lfr = ((c4 >> 1) & 3) * 16 + (row & 15);
            unsigned short* p0 = sb + ((size_t)(row >> 4) * 4 + kt) * 512 + lfr * 8 + 4 * (c4 & 1);
            *(ushort4*)p0 = hi;
        }
    }
    if (act) { float4 st = {m4[0], m4[1], m4[2], m4[3]}; *(float4*)&pm[rg][d0] = st; }
    __syncthreads();
    if (tid < kD) {
        float s = 0.f;
#pragma unroll
        for (int g = 0; g < 8; ++g) s += pm[g][tid];
        atomicAdd(&res[b * 600 + res_off + tid], s * (1.0f / kL));
    }
}

// ------------------------------------------------------------- fused: e += avgpool3(o*w); hi prep (16-row blocks)
__global__ __launch_bounds__(256) void poolprep_kernel(const float* __restrict__ o1,
                                                       const float* __restrict__ o2,
                                                       const float* __restrict__ w1_,
                                                       const float* __restrict__ w2_,
                                                       const int* __restrict__ q1,
                                                       const int* __restrict__ q2,
                                                       float* __restrict__ e1,
                                                       float* __restrict__ e2,
                                                       unsigned short* __restrict__ sbf1,
                                                       unsigned short* __restrict__ sbf2,
                                                       float* __restrict__ sq1,
                                                       float* __restrict__ sq2) {
    __shared__ float tb[18][104];   // o*w with halo rows
    __shared__ float xb[16][104];   // updated e
    __shared__ float vsh[16];
    __shared__ float wsh[18];
    int side = blockIdx.y;
    const float* o = side ? o2 : o1;
    const float* w = side ? w2_ : w1_;
    const int* q = side ? q2 : q1;
    float* e = side ? e2 : e1;
    unsigned short* sb = side ? sbf2 : sbf1;
    float* sq = side ? sq2 : sq1;
    int tid = threadIdx.x;
    int row0 = blockIdx.x * 16;
    int l0 = row0 & (kL - 1);
    int base_b = row0 - l0;         // b * kL
    if (tid < 18) {
        int l = l0 - 1 + tid;
        wsh[tid] = (l >= 0 && l < kL) ? w[base_b + l] : 0.f;
    }
    if (tid < 16) vsh[tid] = (q[row0 + tid] != 0) ? 1.f : 0.f;
    __syncthreads();
    for (int t = tid; t < 450; t += 256) {
        int r = t / 25, c = t - r * 25;
        int l = l0 - 1 + r;
        float4 v4 = {0.f, 0.f, 0.f, 0.f};
        if (l >= 0 && l < kL) v4 = *(const float4*)(o + (size_t)(base_b + l) * kD + c * 4);
        float ww = wsh[r];
        tb[r][c * 4 + 0] = v4.x * ww;
        tb[r][c * 4 + 1] = v4.y * ww;
        tb[r][c * 4 + 2] = v4.z * ww;
        tb[r][c * 4 + 3] = v4.w * ww;
    }
    __syncthreads();
    for (int t = tid; t < 400; t += 256) {
        int r = t / 25, c = t - r * 25;
        float* ep = e + (size_t)(row0 + r) * kD + c * 4;
        float4 e4 = *(float4*)ep;
        float nx = e4.x + (tb[r][c * 4 + 0] + tb[r + 1][c * 4 + 0] + tb[r + 2][c * 4 + 0]) * (1.f / 3.f);
        float ny = e4.y + (tb[r][c * 4 + 1] + tb[r + 1][c * 4 + 1] + tb[r + 2][c * 4 + 1]) * (1.f / 3.f);
        float nz = e4.z + (tb[r][c * 4 + 2] + tb[r + 1][c * 4 + 2] + tb[r + 2][c * 4 + 2]) * (1.f / 3.f);
        float nw = e4.w + (tb[r][c * 4 + 3] + tb[r + 1][c * 4 + 3] + tb[r + 2][c * 4 + 3]) * (1.f / 3.f);
        float4 st = {nx, ny, nz, nw};
        *(float4*)ep = st;
        *(float4*)&xb[r][c * 4] = st;
    }
    __syncthreads();
    sq_store(xb, vsh, sq, row0, tid);
    frag_store(xb, vsh, sb, row0 >> 4, tid);
}

// ------------------------------------------------------------- head
__device__ __forceinline__ float block_sum(float v, float* red, int tid) {
#pragma unroll
    for (int m = 32; m >= 1; m >>= 1) v += __shfl_xor(v, m, 64);
    __syncthreads();
    if ((tid & 63) == 0) red[tid >> 6] = v;
    __syncthreads();
    return red[0] + red[1] + red[2] + red[3];
}

__global__ __launch_bounds__(256) void head_kernel(const float* __restrict__ xcat,
                                                   const float* __restrict__ fc1w,
                                                   const float* __restrict__ fc1b,
                                                   const float* __restrict__ lng,
                                                   const float* __restrict__ lnb,
                                                   const float* __restrict__ fc2w,
                                                   const float* __restrict__ fc2b,
                                                   float* __restrict__ out) {
    __shared__ float xr[600];
    __shared__ float red[4];
    int b = blockIdx.x, tid = threadIdx.x;
    for (int t = tid; t < 600; t += 256) xr[t] = xcat[b * 600 + t];
    __syncthreads();
    float h0 = fc1b[tid], h1 = fc1b[tid + 256];
    for (int k = 0; k < 600; ++k) {
        float xv = xr[k];
        h0 = fmaf(xv, fc1w[k * kLIN + tid], h0);
        h1 = fmaf(xv, fc1w[k * kLIN + tid + 256], h1);
    }
    float mu = block_sum(h0 + h1, red, tid) * (1.0f / kLIN);
    float d0 = h0 - mu, d1 = h1 - mu;
    float var = block_sum(d0 * d0 + d1 * d1, red, tid) * (1.0f / kLIN);
    float rstd = rsqrtf(var + 1e-5f);
    float n0 = d0 * rstd * lng[tid] + lnb[tid];
    float n1 = d1 * rstd * lng[tid + 256] + lnb[tid + 256];
    float r0 = fmaxf(n0, 0.f), r1 = fmaxf(n1, 0.f);
    float p0 = r0 * fc2w[tid * 2 + 0] + r1 * fc2w[(tid + 256) * 2 + 0];
    float p1 = r0 * fc2w[tid * 2 + 1] + r1 * fc2w[(tid + 256) * 2 + 1];
    float o0 = block_sum(p0, red, tid);
    float o1 = block_sum(p1, red, tid);
    if (tid == 0) { out[b * 2 + 0] = o0 + fc2b[0]; out[b * 2 + 1] = o1 + fc2b[1]; }
}

// ----------------------------------------------------------------------------
extern "C" void kernel_launch(void* const* d_in, const int* in_sizes, int n_in,
                              void* d_out, int out_size, void* d_ws, size_t ws_size,
                              hipStream_t stream) {
    const int*   q1   = (const int*)d_in[0];
    const int*   q2   = (const int*)d_in[1];
    const float* emb  = (const float*)d_in[2];
    const float* Ws   = (const float*)d_in[3];
    const float* ck   = (const float*)d_in[4];
    const float* cb   = (const float*)d_in[5];
    const float* fc1w = (const float*)d_in[6];
    const float* fc1b = (const float*)d_in[7];
    const float* lng  = (const float*)d_in[8];
    const float* lnb  = (const float*)d_in[9];
    const float* fc2w = (const float*)d_in[10];
    const float* fc2b = (const float*)d_in[11];
    float* out = (float*)d_out;
    float* ws  = (float*)d_ws;

    float* e1  = ws;
    float* e2  = e1 + SZ_E;
    unsigned short* fb1 = (unsigned short*)(e2 + SZ_E);
    unsigned short* fb2 = fb1 + SZ_E;
    unsigned short* Abf = (unsigned short*)((float*)fb1 + SZ_E);  // A|At fragments = SZ_A floats
    unsigned short* Atb = Abf + SZ_A;
    float* o1  = (float*)Abf;             // alias: A dead once f computed; o dead once A rewritten
    float* o2  = o1 + SZ_E;
    unsigned short* sbf1 = (unsigned short*)((float*)Abf + SZ_A); // hi-only fragment sbf, 2 sides
    unsigned short* sbf2 = sbf1 + kB * kL * 128;
    float* after = (float*)sbf1 + SZ_A / 2;
    unsigned short* Wfrag = (unsigned short*)after;
    float* sq1 = after + W_FRAG;
    float* sq2 = sq1 + kB * kL;
    float* w1  = sq2 + kB * kL;
    float* w2  = w1 + kB * kL;
    float* xcat = w2 + kB * kL;

    hipMemsetAsync(xcat, 0, kB * 600 * sizeof(float), stream);
    embprep_kernel<<<dim3(kB * kL / 16, 2), 256, 0, stream>>>(q1, q2, emb, e1, e2,
                                                              sbf1, sbf2, sq1, sq2, xcat);
    wprep_kernel<<<2, 256, 0, stream>>>(Ws, Wfrag);

    // ---- layer 0
    match_core<0><<<dim3(2, 2, kB), 256, 0, stream>>>(sbf1, sbf2, sq1, sq2,
                                                      Abf, Atb, nullptr, nullptr);
    fgemm_mfma<<<2 * kB * kL / 128, 256, 0, stream>>>(Abf, Wfrag, fb1);
    conv_kernel<<<dim3(kL / 16, kB, 2), 256, 0, stream>>>(e1, e2, fb1, fb2, ck, cb,
                                                          o1, o2, xcat, 100, 400,
                                                          1, q1, q2, sbf1, sbf2, sq1, sq2, w1, w2);
    match_core<1><<<dim3(2, 2, kB), 256, 0, stream>>>(sbf1, sbf2, sq1, sq2,
                                                      nullptr, nullptr, w1, w2);
    poolprep_kernel<<<dim3(kB * kL / 16, 2), 256, 0, stream>>>(o1, o2, w1, w2, q1, q2,
                                                               e1, e2, sbf1, sbf2, sq1, sq2);
    // ---- layer 1 (tail match1/pool dead: e unused afterwards)
    match_core<0><<<dim3(2, 2, kB), 256, 0, stream>>>(sbf1, sbf2, sq1, sq2,
                                                      Abf, Atb, nullptr, nullptr);
    fgemm_mfma<<<2 * kB * kL / 128, 256, 0, stream>>>(Abf, Wfrag + W_FRAG, fb1);
    conv_kernel<<<dim3(kL / 16, kB, 2), 256, 0, stream>>>(e1, e2, fb1, fb2, ck + 18, cb + 1,
                                                          o1, o2, xcat, 200, 500,
                                                          0, q1, q2, sbf1, sbf2, sq1, sq2, w1, w2);

    head_kernel<<<kB, 256, 0, stream>>>(xcat, fc1w, fc1b, lng, lnb, fc2w, fc2b, out);
}

// Round 9
// 387.198 us; speedup vs baseline: 3.9095x; 1.0802x over previous
//
#include <hip/hip_runtime.h>
#include <hip/hip_bf16.h>
#include <math.h>

// Problem constants
static constexpr int kB = 256;
static constexpr int kL = 256;
static constexpr int kD = 100;
static constexpr int kLIN = 512;
static constexpr int SZ_E = kB * kL * kD;     // 6,553,600
static constexpr int W_FRAG = 7 * 8 * 64 * 8; // 28672 bf16 per layer

typedef short  s8_t  __attribute__((ext_vector_type(8)));
typedef float  f4_t  __attribute__((ext_vector_type(4)));

// sbf fragment storage (hi-only bf16): rowgroup g = row>>4, slot s in [0,4):
//   ((size_t)g*4 + s)*512 shorts, lane = quad*16 + (row&15), 8 shorts/lane,
//   k = s*32 + quad*8 + j (identity). sq from the SAME bf16-rounded values.
// W fragments pi-permuted (wprep); matchf's Dp registers are A-operand
// fragments in the same pi order, fed directly to the f-GEMM MFMA.

__device__ __forceinline__ unsigned short f2bf(float x) {
    __hip_bfloat16 h = __float2bfloat16(x);
    return *(unsigned short*)&h;
}
__device__ __forceinline__ float bf2f(unsigned short u) {
    unsigned int w = ((unsigned int)u) << 16;
    return *(float*)&w;
}
__device__ __forceinline__ float ftanh(float x) {
    float ax = fabsf(x);
    float t = __expf(-2.f * ax);
    float r = 1.f - 2.f * t / (1.f + t);
    return copysignf(r, x);
}

// write one rowgroup (16 rows in rb[16][104]) as 4 coalesced hi fragments (one per wave)
__device__ __forceinline__ void frag_store(const float (*rb)[104], const float* vsh,
                                           unsigned short* sb, int g, int tid) {
    int lane = tid & 63, wave = tid >> 6;   // wave = slot
    int qd = (lane >> 4) & 3, r15 = lane & 15;
    float v = vsh[r15];
    int kbase = wave * 32 + qd * 8;
    s8_t stv;
#pragma unroll
    for (int j = 0; j < 8; ++j) {
        int k = kbase + j;
        float x = (k < kD) ? rb[r15][k] * v : 0.f;
        stv[j] = (short)f2bf(x);
    }
    *(s8_t*)(sb + ((size_t)g * 4 + wave) * 512 + lane * 8) = stv;
}

// per-row sum of squares of bf16-ROUNDED masked values (16 threads/row)
__device__ __forceinline__ void sq_store(const float (*rb)[104], const float* vsh,
                                         float* sq, int row0, int tid) {
    int r = tid >> 4, j = tid & 15;
    float v = vsh[r];
    float s = 0.f;
    for (int d = j; d < kD; d += 16) { float x = bf2f(f2bf(rb[r][d] * v)); s += x * x; }
#pragma unroll
    for (int m = 8; m >= 1; m >>= 1) s += __shfl_xor(s, m, 64);
    if (j == 0) sq[row0 + r] = s;
}

// ------------------------------------------------------------- embed + prep + fused mean
__global__ __launch_bounds__(256) void embprep_kernel(const int* __restrict__ q1,
                                                      const int* __restrict__ q2,
                                                      const float* __restrict__ emb,
                                                      float* __restrict__ e1,
                                                      float* __restrict__ e2,
                                                      unsigned short* __restrict__ sbf1,
                                                      unsigned short* __restrict__ sbf2,
                                                      float* __restrict__ sq1,
                                                      float* __restrict__ sq2,
                                                      float* __restrict__ xcat) {
    __shared__ float rb[16][104];
    __shared__ float vsh[16];
    int side = blockIdx.y;
    const int* q = side ? q2 : q1;
    float* e = side ? e2 : e1;
    unsigned short* sb = side ? sbf2 : sbf1;
    float* sq = side ? sq2 : sq1;
    int tid = threadIdx.x;
    int row0 = blockIdx.x * 16;
    int b = row0 >> 8;
    if (tid < 16) vsh[tid] = (q[row0 + tid] != 0) ? 1.f : 0.f;
    for (int t = tid; t < 400; t += 256) {
        int r = t / 25, c = t - r * 25;
        int qv = q[row0 + r];
        float4 v4 = *(const float4*)(emb + (size_t)qv * kD + c * 4);
        *(float4*)(e + (size_t)(row0 + r) * kD + c * 4) = v4;
        *(float4*)&rb[r][c * 4] = v4;
    }
    __syncthreads();
    sq_store(rb, vsh, sq, row0, tid);
    if (tid < kD) {
        float s = 0.f;
#pragma unroll
        for (int r = 0; r < 16; ++r) s += rb[r][tid];
        atomicAdd(&xcat[b * 600 + side * 300 + tid], s * (1.0f / kL));
    }
    frag_store(rb, vsh, sb, row0 >> 4, tid);
}

// ------------------------------------------------------------- fused match + f-GEMM
// side 0: f1[i] = sum_j A[i,j] W[j];  side 1: f2[j] = sum_i A[i,j] W[i] (roles swapped).
__global__ __launch_bounds__(256) void matchf_kernel(const unsigned short* __restrict__ sbf1,
                                                     const unsigned short* __restrict__ sbf2,
                                                     const float* __restrict__ sq1,
                                                     const float* __restrict__ sq2,
                                                     const unsigned short* __restrict__ Wf,
                                                     unsigned short* __restrict__ f1,
                                                     unsigned short* __restrict__ f2) {
    __shared__ short lb[8 * 4 * 512];   // 32KB: contraction-side fragments
    int tid = threadIdx.x;
    int lane = tid & 63, wave = tid >> 6;
    int quad = lane >> 4, l15 = lane & 15;
    int side = blockIdx.y;
    int b = blockIdx.z;
    const unsigned short* sA = side ? sbf2 : sbf1;
    const unsigned short* sB = side ? sbf1 : sbf2;
    const float* sqA = side ? sq2 : sq1;
    const float* sqB = side ? sq1 : sq2;
    unsigned short* fo = side ? f2 : f1;
    int i0 = blockIdx.x * 128;
    int iw = i0 + wave * 32;
    int lo8 = lane * 8;

    // i-side fragments (8 x 16B per lane), loaded once
    const unsigned short* s1f = sA + ((size_t)(b * 16 + (iw >> 4)) * 4) * 512 + lo8;
    s8_t a1[2][4];
#pragma unroll
    for (int mt = 0; mt < 2; ++mt)
#pragma unroll
        for (int kt = 0; kt < 4; ++kt)
            a1[mt][kt] = *(const s8_t*)(s1f + (size_t)(mt * 4 + kt) * 512);

    float s1c[2] = { sqA[b * kL + iw + l15], sqA[b * kL + iw + 16 + l15] };
    const float* sq2p = sqB + b * kL;

    f4_t facc[2][7] = {};

    for (int jt = 0; jt < 2; ++jt) {
        int j0 = jt * 128;
        if (jt) __syncthreads();
        const unsigned short* s2base = sB + ((size_t)(b * 16 + (j0 >> 4)) * 4) * 512;
#pragma unroll
        for (int t = 0; t < 8; ++t) {
            int frag = wave * 8 + t;
            s8_t vld = *(const s8_t*)(s2base + (size_t)frag * 512 + lo8);
            *(s8_t*)(lb + frag * 512 + lo8) = vld;
        }
        __syncthreads();
#pragma unroll
        for (int half = 0; half < 2; ++half) {
            f4_t Dp[4][2] = {};
#pragma unroll
            for (int kt = 0; kt < 4; ++kt) {
                s8_t b2[4];
#pragma unroll
                for (int n = 0; n < 4; ++n)
                    b2[n] = *(const s8_t*)&lb[((half * 4 + n) * 4 + kt) * 512 + lo8];
#pragma unroll
                for (int n = 0; n < 4; ++n)
#pragma unroll
                    for (int mt = 0; mt < 2; ++mt)
                        Dp[n][mt] = __builtin_amdgcn_mfma_f32_16x16x32_bf16(b2[n], a1[mt][kt], Dp[n][mt], 0, 0, 0);
            }
            // epilogue: Dp rows=j (quad*4+r per n), col=i (l15 per mt).
            // Build A-operand fragments (pi k-order over j) and run the f-GEMM.
#pragma unroll
            for (int np = 0; np < 2; ++np) {
                int ktj = (j0 >> 5) + half * 2 + np;
                const unsigned short* bp = Wf + (size_t)(ktj * 64 + lane) * 8;
#pragma unroll
                for (int mt = 0; mt < 2; ++mt) {
                    s8_t af;
#pragma unroll
                    for (int h2 = 0; h2 < 2; ++h2) {
                        int n = np * 2 + h2;
#pragma unroll
                        for (int r = 0; r < 4; ++r) {
                            float s2q = sq2p[j0 + half * 64 + n * 16 + quad * 4 + r];
                            float d2 = fmaxf(s2q + s1c[mt] - 2.f * Dp[n][mt][r], 0.f);
                            float av = __builtin_amdgcn_rcpf(1.f + __builtin_amdgcn_sqrtf(d2));
                            af[h2 * 4 + r] = (short)f2bf(av);
                        }
                    }
#pragma unroll
                    for (int nt = 0; nt < 7; ++nt) {
                        s8_t wv = *(const s8_t*)(bp + (size_t)nt * 8 * 64 * 8);
                        facc[mt][nt] = __builtin_amdgcn_mfma_f32_16x16x32_bf16(af, wv, facc[mt][nt], 0, 0, 0);
                    }
                }
            }
        }
    }
#pragma unroll
    for (int mt = 0; mt < 2; ++mt)
#pragma unroll
        for (int nt = 0; nt < 7; ++nt) {
            int col = nt * 16 + l15;
            if (col < kD) {
#pragma unroll
                for (int r = 0; r < 4; ++r) {
                    size_t row = (size_t)(b * kL) + iw + mt * 16 + quad * 4 + r;
                    fo[row * kD + col] = f2bf(facc[mt][nt][r]);
                }
            }
        }
}

// ------------------------------------------------------------- match row/col sums (pooling weights)
__global__ __launch_bounds__(256) void match_sums(const unsigned short* __restrict__ sbf1,
                                                  const unsigned short* __restrict__ sbf2,
                                                  const float* __restrict__ sq1,
                                                  const float* __restrict__ sq2,
                                                  float* __restrict__ w1,
                                                  float* __restrict__ w2) {
    __shared__ short lb[8 * 4 * 512];
    int tid = threadIdx.x;
    int lane = tid & 63, wave = tid >> 6;
    int quad = lane >> 4, l15 = lane & 15;
    int b = blockIdx.z;
    int i0 = blockIdx.y * 128, j0 = blockIdx.x * 128;
    int iw = i0 + wave * 32;
    int lo8 = lane * 8;

    const unsigned short* s2base = sbf2 + ((size_t)(b * 16 + (j0 >> 4)) * 4) * 512;
#pragma unroll
    for (int t = 0; t < 8; ++t) {
        int frag = wave * 8 + t;
        s8_t vld = *(const s8_t*)(s2base + (size_t)frag * 512 + lo8);
        *(s8_t*)(lb + frag * 512 + lo8) = vld;
    }

    const unsigned short* s1f = sbf1 + ((size_t)(b * 16 + (iw >> 4)) * 4) * 512 + lo8;
    const float* sq1p = sq1 + b * kL + iw;
    const float* sq2p = sq2 + b * kL + j0;

    float s1v[2][4];
#pragma unroll
    for (int mt = 0; mt < 2; ++mt)
#pragma unroll
        for (int r = 0; r < 4; ++r) s1v[mt][r] = sq1p[mt * 16 + quad * 4 + r];

    float rs_acc[2][4] = {{0.f,0.f,0.f,0.f},{0.f,0.f,0.f,0.f}};
    __syncthreads();

    for (int half = 0; half < 2; ++half) {
        f4_t D[2][4] = {};
#pragma unroll
        for (int kt = 0; kt < 4; ++kt) {
            s8_t a1h[2], b2h[4];
#pragma unroll
            for (int mt = 0; mt < 2; ++mt)
                a1h[mt] = *(const s8_t*)(s1f + (size_t)(mt * 4 + kt) * 512);
#pragma unroll
            for (int n = 0; n < 4; ++n)
                b2h[n] = *(const s8_t*)&lb[((half * 4 + n) * 4 + kt) * 512 + lo8];
#pragma unroll
            for (int mt = 0; mt < 2; ++mt)
#pragma unroll
                for (int n = 0; n < 4; ++n)
                    D[mt][n] = __builtin_amdgcn_mfma_f32_16x16x32_bf16(a1h[mt], b2h[n], D[mt][n], 0, 0, 0);
        }
#pragma unroll
        for (int n = 0; n < 4; ++n) {
            float s2vn = sq2p[half * 64 + n * 16 + l15];
            float cs = 0.f;
#pragma unroll
            for (int mt = 0; mt < 2; ++mt) {
#pragma unroll
                for (int r = 0; r < 4; ++r) {
                    float d2 = fmaxf(s1v[mt][r] + s2vn - 2.f * D[mt][n][r], 0.f);
                    float av = __builtin_amdgcn_rcpf(1.f + __builtin_amdgcn_sqrtf(d2));
                    rs_acc[mt][r] += av; cs += av;
                }
            }
            cs += __shfl_xor(cs, 16, 64);
            cs += __shfl_xor(cs, 32, 64);
            if (lane < 16) atomicAdd(&w2[b * kL + j0 + half * 64 + n * 16 + lane], cs);
        }
    }
#pragma unroll
    for (int mt = 0; mt < 2; ++mt)
#pragma unroll
        for (int r = 0; r < 4; ++r) {
            float v = rs_acc[mt][r];
            v += __shfl_xor(v, 1, 64);
            v += __shfl_xor(v, 2, 64);
            v += __shfl_xor(v, 4, 64);
            v += __shfl_xor(v, 8, 64);
            if (l15 == 0) atomicAdd(&w1[b * kL + iw + mt * 16 + quad * 4 + r], v);
        }
}

// ------------------------------------------------------------- W -> B-fragment layout (bf16, pi-permuted k)
__global__ __launch_bounds__(256) void wprep_kernel(const float* __restrict__ Ws,
                                                    unsigned short* __restrict__ Wf) {
    int layer = blockIdx.x;
    const float* W = Ws + layer * kL * kD;
    unsigned short* o = Wf + layer * W_FRAG;
    for (int t = threadIdx.x; t < W_FRAG; t += 256) {
        int j = t & 7, lane = (t >> 3) & 63, kt = (t >> 9) & 7, nt = t >> 12;
        int k = kt * 32 + (j >> 2) * 16 + ((lane >> 4) & 3) * 4 + (j & 3);  // pi
        int n = nt * 16 + (lane & 15);
        float v = (n < kD) ? W[k * kD + n] : 0.f;
        o[t] = f2bf(v);
    }
}

// ------------------------------------------------------------- conv(3x3, 2ch) + tanh + mean(1) [+ fused hi prep]
// LDS layout le/lf[r][x] = data[x-1] (halo), staged via shfl-shifted ALIGNED b128 writes.
__global__ __launch_bounds__(256) void conv_kernel(const float* __restrict__ e1,
                                                   const float* __restrict__ e2,
                                                   const unsigned short* __restrict__ f1,
                                                   const unsigned short* __restrict__ f2,
                                                   const float* __restrict__ ck,
                                                   const float* __restrict__ cb,
                                                   float* __restrict__ o1,
                                                   float* __restrict__ o2,
                                                   float* __restrict__ res,
                                                   int ro1, int ro2,
                                                   int do_prep, int do_store,
                                                   const int* __restrict__ q1,
                                                   const int* __restrict__ q2,
                                                   unsigned short* __restrict__ sbf1,
                                                   unsigned short* __restrict__ sbf2,
                                                   float* __restrict__ sq1,
                                                   float* __restrict__ sq2,
                                                   float* __restrict__ w1,
                                                   float* __restrict__ w2) {
    __shared__ float le[18][104];
    __shared__ float lf[18][104];
    __shared__ float pm[8][104];
    __shared__ float ksh[19];
    int tid = threadIdx.x;
    int b = blockIdx.y;
    int l0 = blockIdx.x * 16;
    int side = blockIdx.z;
    const float* e = side ? e2 : e1;
    const unsigned short* f = side ? f2 : f1;
    float* o = side ? o2 : o1;
    const int* q = side ? q2 : q1;
    unsigned short* sb = side ? sbf2 : sbf1;
    float* sq = side ? sq2 : sq1;
    float* w = side ? w2 : w1;
    int res_off = side ? ro2 : ro1;
    if (tid < 19) ksh[tid] = (tid < 18) ? ck[tid] : cb[0];
    if (tid < 18) { le[tid][101] = 0.f; lf[tid][101] = 0.f; }
    if (do_prep && tid < 16) w[b * kL + l0 + tid] = 0.f;
    // staging: 18 rows x 32 slots (25 active) per channel; wave-aligned rows for shfl
    for (int t = tid; t < 1152; t += 256) {
        int a = t >= 576;
        int tt = a ? t - 576 : t;
        int r = tt >> 5, c = tt & 31;
        int l = l0 - 1 + r;
        bool ok = (l >= 0 && l < kL);
        bool actc = c < 25;
        float4 v = {0.f, 0.f, 0.f, 0.f};
        if (ok && actc) {
            size_t base = ((size_t)b * kL + l) * kD + c * 4;
            if (!a) v = *(const float4*)(e + base);
            else { ushort4 u = *(const ushort4*)(f + base);
                   v.x = bf2f(u.x); v.y = bf2f(u.y); v.z = bf2f(u.z); v.w = bf2f(u.w); }
        }
        float lw = __shfl_up(v.w, 1, 64);
        if (c == 0) lw = 0.f;
        if (actc) {
            float* rowp = a ? lf[r] : le[r];
            float4 st = {lw, v.x, v.y, v.z};
            *(float4*)&rowp[c * 4] = st;
            if (c == 24) rowp[100] = v.w;
        }
    }
    __syncthreads();
    int rg = tid >> 5, c4 = tid & 31;
    bool act = c4 < 25;
    int d0 = c4 * 4;
    float m4[4] = {0.f, 0.f, 0.f, 0.f};
#pragma unroll
    for (int rr = 0; rr < 2; ++rr) {
        int r = rg * 2 + rr;
        float a0 = 0.f, a1 = 0.f, a2 = 0.f, a3 = 0.f;
        if (act) {
            float bias = ksh[18];
            a0 = bias; a1 = bias; a2 = bias; a3 = bias;
#pragma unroll
            for (int ch = 0; ch < 2; ++ch) {
                const float (*L)[104] = ch ? lf : le;
                const float* kp = &ksh[ch * 9];
#pragma unroll
                for (int ky = 0; ky < 3; ++ky) {
                    const float* row = L[r + ky];
                    float4 v4 = *(const float4*)&row[d0];
                    float2 v2 = *(const float2*)&row[d0 + 4];
                    float k0 = kp[ky * 3], k1 = kp[ky * 3 + 1], k2 = kp[ky * 3 + 2];
                    a0 += k0 * v4.x + k1 * v4.y + k2 * v4.z;
                    a1 += k0 * v4.y + k1 * v4.z + k2 * v4.w;
                    a2 += k0 * v4.z + k1 * v4.w + k2 * v2.x;
                    a3 += k0 * v4.w + k1 * v2.x + k2 * v2.y;
                }
            }
            a0 = ftanh(a0); a1 = ftanh(a1); a2 = ftanh(a2); a3 = ftanh(a3);
            if (do_store) {
                float4 st = {a0, a1, a2, a3};
                *(float4*)&o[((size_t)(b * kL) + l0 + r) * kD + d0] = st;
            }
            m4[0] += a0; m4[1] += a1; m4[2] += a2; m4[3] += a3;
        }
        if (do_prep) {
            int row = b * kL + l0 + r;
            float v = (q[row] != 0) ? 1.f : 0.f;
            ushort4 hi = {0, 0, 0, 0};
            float xr0 = 0.f, xr1 = 0.f, xr2 = 0.f, xr3 = 0.f;
            if (act) {
                hi.x = f2bf(a0 * v); xr0 = bf2f(hi.x);
                hi.y = f2bf(a1 * v); xr1 = bf2f(hi.y);
                hi.z = f2bf(a2 * v); xr2 = bf2f(hi.z);
                hi.w = f2bf(a3 * v); xr3 = bf2f(hi.w);
            }
            float srow = xr0 * xr0 + xr1 * xr1 + xr2 * xr2 + xr3 * xr3;
#pragma unroll
            for (int m = 16; m >= 1; m >>= 1) srow += __shfl_xor(srow, m, 32);
            if (c4 == 0) sq[row] = srow;
            int kt = c4 >> 3;
            int lfr = ((c4 >> 1) & 3) * 16 + (row & 15);
            unsigned short* p0 = sb + ((size_t)(row >> 4) * 4 + kt) * 512 + lfr * 8 + 4 * (c4 & 1);
            *(ushort4*)p0 = hi;
        }
    }
    if (act) { float4 st = {m4[0], m4[1], m4[2], m4[3]}; *(float4*)&pm[rg][d0] = st; }
    __syncthreads();
    if (tid < kD) {
        float s = 0.f;
#pragma unroll
        for (int g = 0; g < 8; ++g) s += pm[g][tid];
        atomicAdd(&res[b * 600 + res_off + tid], s * (1.0f / kL));
    }
}

// ------------------------------------------------------------- fused: e += avgpool3(o*w); hi prep (16-row blocks)
__global__ __launch_bounds__(256) void poolprep_kernel(const float* __restrict__ o1,
                                                       const float* __restrict__ o2,
                                                       const float* __restrict__ w1_,
                                                       const float* __restrict__ w2_,
                                                       const int* __restrict__ q1,
                                                       const int* __restrict__ q2,
                                                       float* __restrict__ e1,
                                                       float* __restrict__ e2,
                                                       unsigned short* __restrict__ sbf1,
                                                       unsigned short* __restrict__ sbf2,
                                                       float* __restrict__ sq1,
                                                       float* __restrict__ sq2) {
    __shared__ float tb[18][104];
    __shared__ float xb[16][104];
    __shared__ float vsh[16];
    __shared__ float wsh[18];
    int side = blockIdx.y;
    const float* o = side ? o2 : o1;
    const float* w = side ? w2_ : w1_;
    const int* q = side ? q2 : q1;
    float* e = side ? e2 : e1;
    unsigned short* sb = side ? sbf2 : sbf1;
    float* sq = side ? sq2 : sq1;
    int tid = threadIdx.x;
    int row0 = blockIdx.x * 16;
    int l0 = row0 & (kL - 1);
    int base_b = row0 - l0;
    if (tid < 18) {
        int l = l0 - 1 + tid;
        wsh[tid] = (l >= 0 && l < kL) ? w[base_b + l] : 0.f;
    }
    if (tid < 16) vsh[tid] = (q[row0 + tid] != 0) ? 1.f : 0.f;
    __syncthreads();
    for (int t = tid; t < 450; t += 256) {
        int r = t / 25, c = t - r * 25;
        int l = l0 - 1 + r;
        float4 v4 = {0.f, 0.f, 0.f, 0.f};
        if (l >= 0 && l < kL) v4 = *(const float4*)(o + (size_t)(base_b + l) * kD + c * 4);
        float ww = wsh[r];
        tb[r][c * 4 + 0] = v4.x * ww;
        tb[r][c * 4 + 1] = v4.y * ww;
        tb[r][c * 4 + 2] = v4.z * ww;
        tb[r][c * 4 + 3] = v4.w * ww;
    }
    __syncthreads();
    for (int t = tid; t < 400; t += 256) {
        int r = t / 25, c = t - r * 25;
        float* ep = e + (size_t)(row0 + r) * kD + c * 4;
        float4 e4 = *(float4*)ep;
        float nx = e4.x + (tb[r][c * 4 + 0] + tb[r + 1][c * 4 + 0] + tb[r + 2][c * 4 + 0]) * (1.f / 3.f);
        float ny = e4.y + (tb[r][c * 4 + 1] + tb[r + 1][c * 4 + 1] + tb[r + 2][c * 4 + 1]) * (1.f / 3.f);
        float nz = e4.z + (tb[r][c * 4 + 2] + tb[r + 1][c * 4 + 2] + tb[r + 2][c * 4 + 2]) * (1.f / 3.f);
        float nw = e4.w + (tb[r][c * 4 + 3] + tb[r + 1][c * 4 + 3] + tb[r + 2][c * 4 + 3]) * (1.f / 3.f);
        float4 st = {nx, ny, nz, nw};
        *(float4*)ep = st;
        *(float4*)&xb[r][c * 4] = st;
    }
    __syncthreads();
    sq_store(xb, vsh, sq, row0, tid);
    frag_store(xb, vsh, sb, row0 >> 4, tid);
}

// ------------------------------------------------------------- head
__device__ __forceinline__ float block_sum(float v, float* red, int tid) {
#pragma unroll
    for (int m = 32; m >= 1; m >>= 1) v += __shfl_xor(v, m, 64);
    __syncthreads();
    if ((tid & 63) == 0) red[tid >> 6] = v;
    __syncthreads();
    return red[0] + red[1] + red[2] + red[3];
}

__global__ __launch_bounds__(256) void head_kernel(const float* __restrict__ xcat,
                                                   const float* __restrict__ fc1w,
                                                   const float* __restrict__ fc1b,
                                                   const float* __restrict__ lng,
                                                   const float* __restrict__ lnb,
                                                   const float* __restrict__ fc2w,
                                                   const float* __restrict__ fc2b,
                                                   float* __restrict__ out) {
    __shared__ float xr[600];
    __shared__ float red[4];
    int b = blockIdx.x, tid = threadIdx.x;
    for (int t = tid; t < 600; t += 256) xr[t] = xcat[b * 600 + t];
    __syncthreads();
    float h0 = fc1b[tid], h1 = fc1b[tid + 256];
    for (int k = 0; k < 600; ++k) {
        float xv = xr[k];
        h0 = fmaf(xv, fc1w[k * kLIN + tid], h0);
        h1 = fmaf(xv, fc1w[k * kLIN + tid + 256], h1);
    }
    float mu = block_sum(h0 + h1, red, tid) * (1.0f / kLIN);
    float d0 = h0 - mu, d1 = h1 - mu;
    float var = block_sum(d0 * d0 + d1 * d1, red, tid) * (1.0f / kLIN);
    float rstd = rsqrtf(var + 1e-5f);
    float n0 = d0 * rstd * lng[tid] + lnb[tid];
    float n1 = d1 * rstd * lng[tid + 256] + lnb[tid + 256];
    float r0 = fmaxf(n0, 0.f), r1 = fmaxf(n1, 0.f);
    float p0 = r0 * fc2w[tid * 2 + 0] + r1 * fc2w[(tid + 256) * 2 + 0];
    float p1 = r0 * fc2w[tid * 2 + 1] + r1 * fc2w[(tid + 256) * 2 + 1];
    float o0 = block_sum(p0, red, tid);
    float o1 = block_sum(p1, red, tid);
    if (tid == 0) { out[b * 2 + 0] = o0 + fc2b[0]; out[b * 2 + 1] = o1 + fc2b[1]; }
}

// ----------------------------------------------------------------------------
extern "C" void kernel_launch(void* const* d_in, const int* in_sizes, int n_in,
                              void* d_out, int out_size, void* d_ws, size_t ws_size,
                              hipStream_t stream) {
    const int*   q1   = (const int*)d_in[0];
    const int*   q2   = (const int*)d_in[1];
    const float* emb  = (const float*)d_in[2];
    const float* Ws   = (const float*)d_in[3];
    const float* ck   = (const float*)d_in[4];
    const float* cb   = (const float*)d_in[5];
    const float* fc1w = (const float*)d_in[6];
    const float* fc1b = (const float*)d_in[7];
    const float* lng  = (const float*)d_in[8];
    const float* lnb  = (const float*)d_in[9];
    const float* fc2w = (const float*)d_in[10];
    const float* fc2b = (const float*)d_in[11];
    float* out = (float*)d_out;
    float* ws  = (float*)d_ws;

    float* e1  = ws;
    float* e2  = e1 + SZ_E;
    unsigned short* fb1 = (unsigned short*)(e2 + SZ_E);   // f1|f2 bf16 = SZ_E floats total
    unsigned short* fb2 = fb1 + SZ_E;
    float* o1  = (float*)fb1 + SZ_E;
    float* o2  = o1 + SZ_E;
    unsigned short* sbf1 = (unsigned short*)(o2 + SZ_E);  // hi-only fragments, 2 sides
    unsigned short* sbf2 = sbf1 + kB * kL * 128;
    float* after = (float*)sbf1 + kB * kL * 128;          // 2 sides * 128 shorts = 128 floats/row
    unsigned short* Wfrag = (unsigned short*)after;
    float* sq1 = after + W_FRAG;
    float* sq2 = sq1 + kB * kL;
    float* w1  = sq2 + kB * kL;
    float* w2  = w1 + kB * kL;
    float* xcat = w2 + kB * kL;

    hipMemsetAsync(xcat, 0, kB * 600 * sizeof(float), stream);
    embprep_kernel<<<dim3(kB * kL / 16, 2), 256, 0, stream>>>(q1, q2, emb, e1, e2,
                                                              sbf1, sbf2, sq1, sq2, xcat);
    wprep_kernel<<<2, 256, 0, stream>>>(Ws, Wfrag);

    // ---- layer 0
    matchf_kernel<<<dim3(2, 2, kB), 256, 0, stream>>>(sbf1, sbf2, sq1, sq2, Wfrag, fb1, fb2);
    conv_kernel<<<dim3(kL / 16, kB, 2), 256, 0, stream>>>(e1, e2, fb1, fb2, ck, cb,
                                                          o1, o2, xcat, 100, 400,
                                                          1, 1, q1, q2, sbf1, sbf2, sq1, sq2, w1, w2);
    match_sums<<<dim3(2, 2, kB), 256, 0, stream>>>(sbf1, sbf2, sq1, sq2, w1, w2);
    poolprep_kernel<<<dim3(kB * kL / 16, 2), 256, 0, stream>>>(o1, o2, w1, w2, q1, q2,
                                                               e1, e2, sbf1, sbf2, sq1, sq2);
    // ---- layer 1 (tail match/pool dead; o-store also dead)
    matchf_kernel<<<dim3(2, 2, kB), 256, 0, stream>>>(sbf1, sbf2, sq1, sq2, Wfrag + W_FRAG, fb1, fb2);
    conv_kernel<<<dim3(kL / 16, kB, 2), 256, 0, stream>>>(e1, e2, fb1, fb2, ck + 18, cb + 1,
                                                          o1, o2, xcat, 200, 500,
                                                          0, 0, q1, q2, sbf1, sbf2, sq1, sq2, w1, w2);

    head_kernel<<<kB, 256, 0, stream>>>(xcat, fc1w, fc1b, lng, lnb, fc2w, fc2b, out);
}